// Round 1
// baseline (9125.701 us; speedup 1.0000x reference)
//
#include <hip/hip_runtime.h>
#include <hip/hip_bf16.h>
#include <cstdint>

#define N_NODES 20000
#define E_EDGES 320000
#define P_TYPES 4
#define HEADS   8
#define DHID    256
#define NCLASSES 16
#define NEG_SLOPE 0.2f

// ---------------- tiled f32 GEMM: C = A[MxK] @ B[KxN] (+bias) ----------------
// MODE 0: store C = acc + bias
// MODE 1: score epilogue: atomicAdd(score[p], sum_{n,c} q[c]*tanh(acc+bias[c]))
// RELUA : apply relu to A elements on load (outs are stored pre-relu)
template<int MODE, bool RELUA>
__global__ __launch_bounds__(256)
void gemm_f32(const float* __restrict__ A, const float* __restrict__ B,
              const float* __restrict__ bias, float* __restrict__ C,
              const float* __restrict__ q, float* __restrict__ score,
              int M, int K, int Ncol, size_t aBatchStride)
{
    __shared__ __align__(16) float As[16][68];   // [k][row], stride 68: 16B-aligned rows, 2-way banks
    __shared__ __align__(16) float Bs[16][64];   // [k][col]
    __shared__ float red[4];

    const int p    = blockIdx.z;
    A += (size_t)p * aBatchStride;
    const int row0 = blockIdx.x * 64;
    const int col0 = blockIdx.y * 64;
    const int tid  = threadIdx.x;
    const int tx   = tid & 15, ty = tid >> 4;

    float acc[4][4] = {};

    for (int k0 = 0; k0 < K; k0 += 16) {
        {   // A tile 64x16, store transposed
            int r  = tid >> 2;
            int c4 = (tid & 3) * 4;
            int gr = row0 + r;
            float4 v = make_float4(0.f, 0.f, 0.f, 0.f);
            if (gr < M) v = *(const float4*)&A[(size_t)gr * K + k0 + c4];
            if (RELUA) { v.x = fmaxf(v.x, 0.f); v.y = fmaxf(v.y, 0.f);
                         v.z = fmaxf(v.z, 0.f); v.w = fmaxf(v.w, 0.f); }
            As[c4 + 0][r] = v.x; As[c4 + 1][r] = v.y;
            As[c4 + 2][r] = v.z; As[c4 + 3][r] = v.w;
        }
        {   // B tile 16x64
            int r  = tid >> 4;
            int c4 = (tid & 15) * 4;
            *(float4*)&Bs[r][c4] = *(const float4*)&B[(size_t)(k0 + r) * Ncol + col0 + c4];
        }
        __syncthreads();
        #pragma unroll
        for (int kk = 0; kk < 16; kk++) {
            float4 a4 = *(const float4*)&As[kk][ty * 4];
            float4 b4 = *(const float4*)&Bs[kk][tx * 4];
            float av[4] = {a4.x, a4.y, a4.z, a4.w};
            float bv[4] = {b4.x, b4.y, b4.z, b4.w};
            #pragma unroll
            for (int i = 0; i < 4; i++)
                #pragma unroll
                for (int j = 0; j < 4; j++)
                    acc[i][j] = fmaf(av[i], bv[j], acc[i][j]);
        }
        __syncthreads();
    }

    if (MODE == 0) {
        #pragma unroll
        for (int i = 0; i < 4; i++) {
            int r = row0 + ty * 4 + i;
            if (r < M) {
                int c = col0 + tx * 4;
                float4 st = make_float4(acc[i][0] + bias[c + 0], acc[i][1] + bias[c + 1],
                                        acc[i][2] + bias[c + 2], acc[i][3] + bias[c + 3]);
                *(float4*)&C[(size_t)r * Ncol + c] = st;
            }
        }
    } else {
        float local = 0.f;
        #pragma unroll
        for (int i = 0; i < 4; i++) {
            int r = row0 + ty * 4 + i;
            if (r < M) {
                #pragma unroll
                for (int j = 0; j < 4; j++) {
                    int c = col0 + tx * 4 + j;
                    local += q[c] * tanhf(acc[i][j] + bias[c]);
                }
            }
        }
        #pragma unroll
        for (int off = 32; off > 0; off >>= 1) local += __shfl_down(local, off, 64);
        int lane = tid & 63, w = tid >> 6;
        if (lane == 0) red[w] = local;
        __syncthreads();
        if (tid == 0) atomicAdd(score + p, red[0] + red[1] + red[2] + red[3]);
    }
}

// ---------------- per-node attention logits ----------------
__global__ __launch_bounds__(256)
void att_kernel(const float* __restrict__ z, const float* __restrict__ att_s,
                const float* __restrict__ att_d,
                float* __restrict__ a_src, float* __restrict__ a_dst)
{
    int idx = blockIdx.x * 256 + threadIdx.x;          // n*8 + h
    if (idx >= N_NODES * HEADS) return;
    int h = idx & 7, n = idx >> 3;
    const float4* zr = (const float4*)(z + (size_t)n * DHID + h * 32);
    const float4* as = (const float4*)(att_s + h * 32);
    const float4* ad = (const float4*)(att_d + h * 32);
    float s1 = 0.f, s2 = 0.f;
    #pragma unroll
    for (int i = 0; i < 8; i++) {
        float4 v = zr[i], a = as[i], b = ad[i];
        s1 += v.x * a.x + v.y * a.y + v.z * a.z + v.w * a.w;
        s2 += v.x * b.x + v.y * b.y + v.z * b.z + v.w * b.w;
    }
    a_src[idx] = s1; a_dst[idx] = s2;
}

// ---------------- edge softmax denominator (max skipped; shift-invariant) ----------------
__global__ __launch_bounds__(256)
void edge_denom_kernel(const int* __restrict__ esrc, const int* __restrict__ edst,
                       const float* __restrict__ a_src, const float* __restrict__ a_dst,
                       float* __restrict__ denom)
{
    int idx = blockIdx.x * 256 + threadIdx.x;          // (p*E+e)*8 + h
    if (idx >= P_TYPES * E_EDGES * HEADS) return;
    int h  = idx & 7;
    int eg = idx >> 3;
    int src = esrc[eg], dst = edst[eg];
    int p = eg / E_EDGES;
    float s = a_src[src * HEADS + h] + a_dst[dst * HEADS + h];
    float e = s > 0.f ? s : NEG_SLOPE * s;
    unsafeAtomicAdd(&denom[((size_t)p * N_NODES + dst) * HEADS + h], __expf(e));
}

// ---------------- message scatter: one wave per edge, 256 floats ----------------
__global__ __launch_bounds__(256)
void edge_scatter_kernel(const int* __restrict__ esrc, const int* __restrict__ edst,
                         const float* __restrict__ a_src, const float* __restrict__ a_dst,
                         const float* __restrict__ denom, const float* __restrict__ z,
                         float* __restrict__ outs)
{
    int eg = blockIdx.x * 4 + (threadIdx.x >> 6);
    if (eg >= P_TYPES * E_EDGES) return;
    int lane = threadIdx.x & 63;
    int src = esrc[eg], dst = edst[eg];
    int p = eg / E_EDGES;
    int h = lane >> 3;                                  // cols lane*4.. are in head lane/8
    float s = a_src[src * HEADS + h] + a_dst[dst * HEADS + h];
    float e = s > 0.f ? s : NEG_SLOPE * s;
    float alpha = __expf(e) / denom[((size_t)p * N_NODES + dst) * HEADS + h];
    float4 zv = *(const float4*)(z + (size_t)src * DHID + lane * 4);
    float* o = outs + ((size_t)p * N_NODES + dst) * DHID + lane * 4;
    unsafeAtomicAdd(o + 0, zv.x * alpha);
    unsafeAtomicAdd(o + 1, zv.y * alpha);
    unsafeAtomicAdd(o + 2, zv.z * alpha);
    unsafeAtomicAdd(o + 3, zv.w * alpha);
}

// ---------------- semantic softmax over P=4 ----------------
__global__ void beta_kernel(const float* __restrict__ score, float* __restrict__ beta)
{
    if (threadIdx.x == 0 && blockIdx.x == 0) {
        float s[P_TYPES]; float m = -1e30f;
        for (int p = 0; p < P_TYPES; p++) { s[p] = score[p] * (1.0f / N_NODES); m = fmaxf(m, s[p]); }
        float d = 0.f;
        for (int p = 0; p < P_TYPES; p++) { s[p] = __expf(s[p] - m); d += s[p]; }
        for (int p = 0; p < P_TYPES; p++) beta[p] = s[p] / d;
    }
}

// ---------------- weighted sum over types (+relu on outs, optional elu) ----------------
template<bool ELU>
__global__ __launch_bounds__(256)
void wsum_kernel(const float* __restrict__ outs, const float* __restrict__ beta,
                 float* __restrict__ hout)
{
    int idx = blockIdx.x * 256 + threadIdx.x;          // float4 index into [N,256]
    if (idx >= N_NODES * DHID / 4) return;
    float b[4] = {beta[0], beta[1], beta[2], beta[3]};
    const size_t stride = (size_t)N_NODES * DHID / 4;
    const float4* o = (const float4*)outs;
    float r[4] = {0.f, 0.f, 0.f, 0.f};
    #pragma unroll
    for (int p = 0; p < 4; p++) {
        float4 v = o[idx + p * stride];
        r[0] += b[p] * fmaxf(v.x, 0.f);
        r[1] += b[p] * fmaxf(v.y, 0.f);
        r[2] += b[p] * fmaxf(v.z, 0.f);
        r[3] += b[p] * fmaxf(v.w, 0.f);
    }
    if (ELU) {
        #pragma unroll
        for (int i = 0; i < 4; i++) r[i] = r[i] > 0.f ? r[i] : expm1f(r[i]);
    }
    ((float4*)hout)[idx] = make_float4(r[0], r[1], r[2], r[3]);
}

// ---------------- final classifier [N,256]@[256,16]+bo ----------------
__global__ __launch_bounds__(256)
void final_kernel(const float* __restrict__ h, const float* __restrict__ Wo,
                  const float* __restrict__ bo, float* __restrict__ out)
{
    int idx = blockIdx.x * 256 + threadIdx.x;          // n*16 + c
    if (idx >= N_NODES * NCLASSES) return;
    int c = idx & 15, n = idx >> 4;
    const float* hr = h + (size_t)n * DHID;
    float acc = bo[c];
    #pragma unroll 8
    for (int k = 0; k < DHID; k++) acc = fmaf(hr[k], Wo[k * NCLASSES + c], acc);
    out[idx] = acc;
}

extern "C" void kernel_launch(void* const* d_in, const int* in_sizes, int n_in,
                              void* d_out, int out_size, void* d_ws, size_t ws_size,
                              hipStream_t stream)
{
    const float* x   = (const float*)d_in[0];
    const int*  esrc = (const int*)d_in[1];
    const int*  edst = (const int*)d_in[2];
    const float* Wp1 = (const float*)d_in[3];
    const float* bp1 = (const float*)d_in[4];
    const float* as1 = (const float*)d_in[5];
    const float* ad1 = (const float*)d_in[6];
    const float* Wk1 = (const float*)d_in[7];
    const float* bk1 = (const float*)d_in[8];
    const float* q1  = (const float*)d_in[9];
    const float* Wp2 = (const float*)d_in[10];
    const float* bp2 = (const float*)d_in[11];
    const float* as2 = (const float*)d_in[12];
    const float* ad2 = (const float*)d_in[13];
    const float* Wk2 = (const float*)d_in[14];
    const float* bk2 = (const float*)d_in[15];
    const float* q2  = (const float*)d_in[16];
    const float* Wo  = (const float*)d_in[17];
    const float* bo  = (const float*)d_in[18];
    float* out = (float*)d_out;

    // workspace layout (floats): total ~126.7 MB
    float* z     = (float*)d_ws;                 // 5,120,000
    float* hbuf  = z     + 5120000;              // 5,120,000
    float* a_s   = hbuf  + 5120000;              //   160,000
    float* a_d   = a_s   + 160000;               //   160,000
    float* denom = a_d   + 160000;               //   640,000
    float* outs  = denom + 640000;               // 20,480,000
    float* score = outs  + 20480000;             //         8
    float* beta  = score + 8;                    //         8

    auto run_layer = [&](const float* xin, int K, const float* Wp, const float* bp,
                         const float* atts, const float* attd, const float* Wk,
                         const float* bk, const float* q, float* hout, bool elu) {
        hipMemsetAsync(denom, 0, 640000 * sizeof(float), stream);
        hipMemsetAsync(outs, 0, (size_t)20480000 * sizeof(float), stream);
        hipMemsetAsync(score, 0, 8 * sizeof(float), stream);

        dim3 g1((N_NODES + 63) / 64, DHID / 64, 1);
        gemm_f32<0, false><<<g1, 256, 0, stream>>>(xin, Wp, bp, z, nullptr, nullptr,
                                                   N_NODES, K, DHID, 0);
        att_kernel<<<(N_NODES * HEADS + 255) / 256, 256, 0, stream>>>(z, atts, attd, a_s, a_d);
        edge_denom_kernel<<<(P_TYPES * E_EDGES * HEADS + 255) / 256, 256, 0, stream>>>(
            esrc, edst, a_s, a_d, denom);
        edge_scatter_kernel<<<(P_TYPES * E_EDGES + 3) / 4, 256, 0, stream>>>(
            esrc, edst, a_s, a_d, denom, z, outs);

        dim3 g2((N_NODES + 63) / 64, DHID / 64, P_TYPES);
        gemm_f32<1, true><<<g2, 256, 0, stream>>>(outs, Wk, bk, nullptr, q, score,
                                                  N_NODES, DHID, DHID, (size_t)N_NODES * DHID);
        beta_kernel<<<1, 64, 0, stream>>>(score, beta);
        if (elu)
            wsum_kernel<true><<<(N_NODES * 64 + 255) / 256, 256, 0, stream>>>(outs, beta, hout);
        else
            wsum_kernel<false><<<(N_NODES * 64 + 255) / 256, 256, 0, stream>>>(outs, beta, hout);
    };

    run_layer(x,    512, Wp1, bp1, as1, ad1, Wk1, bk1, q1, hbuf, true);
    run_layer(hbuf, 256, Wp2, bp2, as2, ad2, Wk2, bk2, q2, hbuf, false);

    final_kernel<<<(N_NODES * NCLASSES + 255) / 256, 256, 0, stream>>>(hbuf, Wo, bo, out);
}

// Round 2
// 1070.762 us; speedup vs baseline: 8.5226x; 8.5226x over previous
//
#include <hip/hip_runtime.h>
#include <hip/hip_bf16.h>
#include <cstdint>

#define N_NODES 20000
#define E_EDGES 320000
#define P_TYPES 4
#define HEADS   8
#define DHID    256
#define NCLASSES 16
#define NEG_SLOPE 0.2f

// ---------------- tiled f32 GEMM: C = A[MxK] @ B[KxN] (+bias) ----------------
// MODE 0: store C = acc + bias
// MODE 1: score epilogue: atomicAdd(score[p], sum_{n,c} q[c]*tanh(acc+bias[c]))
// RELUA : apply relu to A elements on load (outs are stored pre-relu)
template<int MODE, bool RELUA>
__global__ __launch_bounds__(256)
void gemm_f32(const float* __restrict__ A, const float* __restrict__ B,
              const float* __restrict__ bias, float* __restrict__ C,
              const float* __restrict__ q, float* __restrict__ score,
              int M, int K, int Ncol, size_t aBatchStride)
{
    __shared__ __align__(16) float As[16][68];
    __shared__ __align__(16) float Bs[16][64];
    __shared__ float red[4];

    const int p    = blockIdx.z;
    A += (size_t)p * aBatchStride;
    const int row0 = blockIdx.x * 64;
    const int col0 = blockIdx.y * 64;
    const int tid  = threadIdx.x;
    const int tx   = tid & 15, ty = tid >> 4;

    float acc[4][4] = {};

    for (int k0 = 0; k0 < K; k0 += 16) {
        {   // A tile 64x16, store transposed
            int r  = tid >> 2;
            int c4 = (tid & 3) * 4;
            int gr = row0 + r;
            float4 v = make_float4(0.f, 0.f, 0.f, 0.f);
            if (gr < M) v = *(const float4*)&A[(size_t)gr * K + k0 + c4];
            if (RELUA) { v.x = fmaxf(v.x, 0.f); v.y = fmaxf(v.y, 0.f);
                         v.z = fmaxf(v.z, 0.f); v.w = fmaxf(v.w, 0.f); }
            As[c4 + 0][r] = v.x; As[c4 + 1][r] = v.y;
            As[c4 + 2][r] = v.z; As[c4 + 3][r] = v.w;
        }
        {   // B tile 16x64
            int r  = tid >> 4;
            int c4 = (tid & 15) * 4;
            *(float4*)&Bs[r][c4] = *(const float4*)&B[(size_t)(k0 + r) * Ncol + col0 + c4];
        }
        __syncthreads();
        #pragma unroll
        for (int kk = 0; kk < 16; kk++) {
            float4 a4 = *(const float4*)&As[kk][ty * 4];
            float4 b4 = *(const float4*)&Bs[kk][tx * 4];
            float av[4] = {a4.x, a4.y, a4.z, a4.w};
            float bv[4] = {b4.x, b4.y, b4.z, b4.w};
            #pragma unroll
            for (int i = 0; i < 4; i++)
                #pragma unroll
                for (int j = 0; j < 4; j++)
                    acc[i][j] = fmaf(av[i], bv[j], acc[i][j]);
        }
        __syncthreads();
    }

    if (MODE == 0) {
        #pragma unroll
        for (int i = 0; i < 4; i++) {
            int r = row0 + ty * 4 + i;
            if (r < M) {
                int c = col0 + tx * 4;
                float4 st = make_float4(acc[i][0] + bias[c + 0], acc[i][1] + bias[c + 1],
                                        acc[i][2] + bias[c + 2], acc[i][3] + bias[c + 3]);
                *(float4*)&C[(size_t)r * Ncol + c] = st;
            }
        }
    } else {
        float local = 0.f;
        #pragma unroll
        for (int i = 0; i < 4; i++) {
            int r = row0 + ty * 4 + i;
            if (r < M) {
                #pragma unroll
                for (int j = 0; j < 4; j++) {
                    int c = col0 + tx * 4 + j;
                    local += q[c] * tanhf(acc[i][j] + bias[c]);
                }
            }
        }
        #pragma unroll
        for (int off = 32; off > 0; off >>= 1) local += __shfl_down(local, off, 64);
        int lane = tid & 63, w = tid >> 6;
        if (lane == 0) red[w] = local;
        __syncthreads();
        if (tid == 0) atomicAdd(score + p, red[0] + red[1] + red[2] + red[3]);
    }
}

// ---------------- per-node attention logits ----------------
__global__ __launch_bounds__(256)
void att_kernel(const float* __restrict__ z, const float* __restrict__ att_s,
                const float* __restrict__ att_d,
                float* __restrict__ a_src, float* __restrict__ a_dst)
{
    int idx = blockIdx.x * 256 + threadIdx.x;          // n*8 + h
    if (idx >= N_NODES * HEADS) return;
    int h = idx & 7, n = idx >> 3;
    const float4* zr = (const float4*)(z + (size_t)n * DHID + h * 32);
    const float4* as = (const float4*)(att_s + h * 32);
    const float4* ad = (const float4*)(att_d + h * 32);
    float s1 = 0.f, s2 = 0.f;
    #pragma unroll
    for (int i = 0; i < 8; i++) {
        float4 v = zr[i], a = as[i], b = ad[i];
        s1 += v.x * a.x + v.y * a.y + v.z * a.z + v.w * a.w;
        s2 += v.x * b.x + v.y * b.y + v.z * b.z + v.w * b.w;
    }
    a_src[idx] = s1; a_dst[idx] = s2;
}

// ================= CSR build (edge structure shared by both layers) =========
__global__ __launch_bounds__(256)
void hist_kernel(const int* __restrict__ edst, int* __restrict__ counts)
{
    int idx = blockIdx.x * 256 + threadIdx.x;          // p*E + e
    if (idx >= P_TYPES * E_EDGES) return;
    int p = idx / E_EDGES;
    atomicAdd(&counts[p * N_NODES + edst[idx]], 1);
}

// single-block exclusive scan over `total` ints (shfl-based, 16 waves)
__global__ __launch_bounds__(1024)
void scan_kernel(const int* __restrict__ counts, int* __restrict__ row_start, int total)
{
    __shared__ int wsum[16];
    __shared__ int carry_s;
    int tid = threadIdx.x, lane = tid & 63, w = tid >> 6;
    if (tid == 0) carry_s = 0;
    __syncthreads();
    for (int base = 0; base < total; base += 1024) {
        int i = base + tid;
        int v = (i < total) ? counts[i] : 0;
        int incl = v;
        #pragma unroll
        for (int off = 1; off < 64; off <<= 1) {
            int t = __shfl_up(incl, off, 64);
            if (lane >= off) incl += t;
        }
        if (lane == 63) wsum[w] = incl;
        __syncthreads();
        if (w == 0) {
            int s = (lane < 16) ? wsum[lane] : 0;
            #pragma unroll
            for (int off = 1; off < 16; off <<= 1) {
                int t = __shfl_up(s, off, 64);
                if (lane >= off) s += t;
            }
            if (lane < 16) wsum[lane] = s;
        }
        __syncthreads();
        int waveoff = (w == 0) ? 0 : wsum[w - 1];
        int carry = carry_s;
        if (i < total) row_start[i] = carry + waveoff + incl - v;  // exclusive
        __syncthreads();
        if (tid == 1023) carry_s = carry + wsum[15];
        __syncthreads();
    }
    if (tid == 0) row_start[total] = carry_s;
}

__global__ __launch_bounds__(256)
void copy_kernel(const int* __restrict__ src, int* __restrict__ dst, int total)
{
    int i = blockIdx.x * 256 + threadIdx.x;
    if (i < total) dst[i] = src[i];
}

__global__ __launch_bounds__(256)
void fill_kernel(const int* __restrict__ esrc, const int* __restrict__ edst,
                 int* __restrict__ cursor, int* __restrict__ csr_src)
{
    int idx = blockIdx.x * 256 + threadIdx.x;          // p*E + e
    if (idx >= P_TYPES * E_EDGES) return;
    int p = idx / E_EDGES;
    int pos = atomicAdd(&cursor[p * N_NODES + edst[idx]], 1);
    csr_src[pos] = esrc[idx];
}

// ---------------- CSR gather: one wave per (p,dst) segment, no atomics ------
__global__ __launch_bounds__(256)
void gather_kernel(const int* __restrict__ row_start, const int* __restrict__ csr_src,
                   const float* __restrict__ a_src, const float* __restrict__ a_dst,
                   const float* __restrict__ z, float* __restrict__ outs)
{
    int seg = blockIdx.x * 4 + (threadIdx.x >> 6);      // p*N + dst
    if (seg >= P_TYPES * N_NODES) return;
    int lane = threadIdx.x & 63;
    int h = lane >> 3;                                   // head for cols [lane*4, lane*4+4)
    int dst = seg % N_NODES;
    float ad = a_dst[dst * HEADS + h];
    int start = row_start[seg], end = row_start[seg + 1];

    float4 acc = make_float4(0.f, 0.f, 0.f, 0.f);
    float den = 0.f;
    int src = (start < end) ? csr_src[start] : 0;
    for (int i = start; i < end; i++) {
        int nxt = (i + 1 < end) ? csr_src[i + 1] : 0;    // prefetch next (uniform) index
        float s = a_src[src * HEADS + h] + ad;
        float e = s > 0.f ? s : NEG_SLOPE * s;
        float wgt = __expf(e);
        float4 zv = *(const float4*)(z + (size_t)src * DHID + lane * 4);
        acc.x += wgt * zv.x; acc.y += wgt * zv.y;
        acc.z += wgt * zv.z; acc.w += wgt * zv.w;
        den += wgt;
        src = nxt;
    }
    float inv = den > 0.f ? 1.0f / den : 0.f;            // deg==0 -> zeros (matches ref)
    *(float4*)(outs + (size_t)seg * DHID + lane * 4) =
        make_float4(acc.x * inv, acc.y * inv, acc.z * inv, acc.w * inv);
}

// ---------------- semantic softmax over P=4 ----------------
__global__ void beta_kernel(const float* __restrict__ score, float* __restrict__ beta)
{
    if (threadIdx.x == 0 && blockIdx.x == 0) {
        float s[P_TYPES]; float m = -1e30f;
        for (int p = 0; p < P_TYPES; p++) { s[p] = score[p] * (1.0f / N_NODES); m = fmaxf(m, s[p]); }
        float d = 0.f;
        for (int p = 0; p < P_TYPES; p++) { s[p] = __expf(s[p] - m); d += s[p]; }
        for (int p = 0; p < P_TYPES; p++) beta[p] = s[p] / d;
    }
}

// ---------------- weighted sum over types (+relu on outs, optional elu) -----
template<bool ELU>
__global__ __launch_bounds__(256)
void wsum_kernel(const float* __restrict__ outs, const float* __restrict__ beta,
                 float* __restrict__ hout)
{
    int idx = blockIdx.x * 256 + threadIdx.x;          // float4 index into [N,256]
    if (idx >= N_NODES * DHID / 4) return;
    float b[4] = {beta[0], beta[1], beta[2], beta[3]};
    const size_t stride = (size_t)N_NODES * DHID / 4;
    const float4* o = (const float4*)outs;
    float r[4] = {0.f, 0.f, 0.f, 0.f};
    #pragma unroll
    for (int p = 0; p < 4; p++) {
        float4 v = o[idx + p * stride];
        r[0] += b[p] * fmaxf(v.x, 0.f);
        r[1] += b[p] * fmaxf(v.y, 0.f);
        r[2] += b[p] * fmaxf(v.z, 0.f);
        r[3] += b[p] * fmaxf(v.w, 0.f);
    }
    if (ELU) {
        #pragma unroll
        for (int i = 0; i < 4; i++) r[i] = r[i] > 0.f ? r[i] : expm1f(r[i]);
    }
    ((float4*)hout)[idx] = make_float4(r[0], r[1], r[2], r[3]);
}

// ---------------- final classifier [N,256]@[256,16]+bo ----------------
__global__ __launch_bounds__(256)
void final_kernel(const float* __restrict__ h, const float* __restrict__ Wo,
                  const float* __restrict__ bo, float* __restrict__ out)
{
    int idx = blockIdx.x * 256 + threadIdx.x;          // n*16 + c
    if (idx >= N_NODES * NCLASSES) return;
    int c = idx & 15, n = idx >> 4;
    const float* hr = h + (size_t)n * DHID;
    float acc = bo[c];
    #pragma unroll 8
    for (int k = 0; k < DHID; k++) acc = fmaf(hr[k], Wo[k * NCLASSES + c], acc);
    out[idx] = acc;
}

extern "C" void kernel_launch(void* const* d_in, const int* in_sizes, int n_in,
                              void* d_out, int out_size, void* d_ws, size_t ws_size,
                              hipStream_t stream)
{
    const float* x   = (const float*)d_in[0];
    const int*  esrc = (const int*)d_in[1];
    const int*  edst = (const int*)d_in[2];
    const float* Wp1 = (const float*)d_in[3];
    const float* bp1 = (const float*)d_in[4];
    const float* as1 = (const float*)d_in[5];
    const float* ad1 = (const float*)d_in[6];
    const float* Wk1 = (const float*)d_in[7];
    const float* bk1 = (const float*)d_in[8];
    const float* q1  = (const float*)d_in[9];
    const float* Wp2 = (const float*)d_in[10];
    const float* bp2 = (const float*)d_in[11];
    const float* as2 = (const float*)d_in[12];
    const float* ad2 = (const float*)d_in[13];
    const float* Wk2 = (const float*)d_in[14];
    const float* bk2 = (const float*)d_in[15];
    const float* q2  = (const float*)d_in[16];
    const float* Wo  = (const float*)d_in[17];
    const float* bo  = (const float*)d_in[18];
    float* out = (float*)d_out;

    // workspace layout (floats/ints, ~129.9 MB total)
    float* z     = (float*)d_ws;                 // 5,120,000
    float* hbuf  = z     + 5120000;              // 5,120,000
    float* a_s   = hbuf  + 5120000;              //   160,000
    float* a_d   = a_s   + 160000;               //   160,000
    float* outs  = a_d   + 160000;               // 20,480,000
    float* score = outs  + 20480000;             //         8
    float* beta  = score + 8;                    //         8
    int* row_start = (int*)(beta + 8);           //    80,001
    int* cursor    = row_start + 80004;          //    80,000
    int* csr_src   = cursor + 80000;             // 1,280,000

    const int PN = P_TYPES * N_NODES;            // 80,000 segments
    const int PE = P_TYPES * E_EDGES;            // 1,280,000 edges

    // ---- CSR build (once; edge structure shared by both layers) ----
    hipMemsetAsync(cursor, 0, PN * sizeof(int), stream);
    hist_kernel<<<(PE + 255) / 256, 256, 0, stream>>>(edst, cursor);
    scan_kernel<<<1, 1024, 0, stream>>>(cursor, row_start, PN);
    copy_kernel<<<(PN + 255) / 256, 256, 0, stream>>>(row_start, cursor, PN);
    fill_kernel<<<(PE + 255) / 256, 256, 0, stream>>>(esrc, edst, cursor, csr_src);

    auto run_layer = [&](const float* xin, int K, const float* Wp, const float* bp,
                         const float* atts, const float* attd, const float* Wk,
                         const float* bk, const float* q, float* hout, bool elu) {
        hipMemsetAsync(score, 0, 8 * sizeof(float), stream);

        dim3 g1((N_NODES + 63) / 64, DHID / 64, 1);
        gemm_f32<0, false><<<g1, 256, 0, stream>>>(xin, Wp, bp, z, nullptr, nullptr,
                                                   N_NODES, K, DHID, 0);
        att_kernel<<<(N_NODES * HEADS + 255) / 256, 256, 0, stream>>>(z, atts, attd, a_s, a_d);
        gather_kernel<<<(PN + 3) / 4, 256, 0, stream>>>(row_start, csr_src, a_s, a_d, z, outs);

        dim3 g2((N_NODES + 63) / 64, DHID / 64, P_TYPES);
        gemm_f32<1, true><<<g2, 256, 0, stream>>>(outs, Wk, bk, nullptr, q, score,
                                                  N_NODES, DHID, DHID, (size_t)N_NODES * DHID);
        beta_kernel<<<1, 64, 0, stream>>>(score, beta);
        if (elu)
            wsum_kernel<true><<<(N_NODES * 64 + 255) / 256, 256, 0, stream>>>(outs, beta, hout);
        else
            wsum_kernel<false><<<(N_NODES * 64 + 255) / 256, 256, 0, stream>>>(outs, beta, hout);
    };

    run_layer(x,    512, Wp1, bp1, as1, ad1, Wk1, bk1, q1, hbuf, true);
    run_layer(hbuf, 256, Wp2, bp2, as2, ad2, Wk2, bk2, q2, hbuf, false);

    final_kernel<<<(N_NODES * NCLASSES + 255) / 256, 256, 0, stream>>>(hbuf, Wo, bo, out);
}

// Round 3
// 961.588 us; speedup vs baseline: 9.4902x; 1.1135x over previous
//
#include <hip/hip_runtime.h>
#include <hip/hip_bf16.h>
#include <cstdint>

#define N_NODES 20000
#define E_EDGES 320000
#define P_TYPES 4
#define HEADS   8
#define DHID    256
#define NCLASSES 16
#define NEG_SLOPE 0.2f

typedef __attribute__((ext_vector_type(8))) short bf16x8;
typedef __attribute__((ext_vector_type(4))) float f32x4;

static __device__ __forceinline__ unsigned short f2bf(float v) {
    __hip_bfloat16 h = __float2bfloat16(v);
    return *(unsigned short*)&h;
}
static __device__ __forceinline__ float bf2f(unsigned short u) {
    __hip_bfloat16 h = *(__hip_bfloat16*)&u;
    return __bfloat162float(h);
}

// ================= MFMA GEMM: C[M x 256] = A[M x K] @ B[K x 256] =============
// B supplied TRANSPOSED bf16: Bth/Btl are [256][K] (hi / lo split halves).
// SPLIT: A staged as hi+lo bf16, 3 MFMAs (fp32-grade precision, for projections)
// !SPLIT: A staged hi-only (for semantic-score GEMM; error averages out)
// MODE 0: C = acc + bias      MODE 1: atomicAdd(score[p], sum q[c]*tanh(acc+bias[c]))
// RELUA: relu(A) on load.  Block: 256 thr = 4 waves; tile BM=128, BN=256, BK=32.
// Wave w owns rows [w*32, w*32+32) = 2 m-tiles x 16 n-tiles of 16x16x32 MFMA.
// LDS rows padded to 5 int4 (80B) -> conflict-free ds_read_b128 (no swizzle).
template<bool SPLIT, bool RELUA, int MODE>
__global__ __launch_bounds__(256)
void mfma_gemm(const float* __restrict__ A, const __hip_bfloat16* __restrict__ Bth,
               const __hip_bfloat16* __restrict__ Btl, const float* __restrict__ bias,
               float* __restrict__ C, const float* __restrict__ q,
               float* __restrict__ score, int M, int K, size_t aBatch)
{
    constexpr int NB = SPLIT ? 2 : 1;
    __shared__ int4 AS[NB * 128 * 5];
    __shared__ int4 BS[NB * 256 * 5];
    __shared__ float red[4];
    const int p = blockIdx.y;
    const float* Ag = A + (size_t)p * aBatch;
    const unsigned short* BgH = (const unsigned short*)Bth;
    const unsigned short* BgL = (const unsigned short*)Btl;
    const int row0 = blockIdx.x * 128;
    const int tid = threadIdx.x, lane = tid & 63, w = tid >> 6;

    f32x4 acc[2][16];
    const f32x4 zero4 = {0.f, 0.f, 0.f, 0.f};
    #pragma unroll
    for (int i = 0; i < 2; i++)
        #pragma unroll
        for (int j = 0; j < 16; j++) acc[i][j] = zero4;

    for (int k0 = 0; k0 < K; k0 += 32) {
        // ---- stage A: 128 rows x 32 k (f32 -> bf16 hi[/lo]) ----
        #pragma unroll
        for (int it = 0; it < 4; it++) {
            int id = tid + it * 256;            // 0..1023, lane-consecutive
            int r = id >> 3, f = id & 7;        // k_local = f*4
            int row_g = row0 + r;
            float4 v = make_float4(0.f, 0.f, 0.f, 0.f);
            if (row_g < M) v = *(const float4*)&Ag[(size_t)row_g * K + k0 + f * 4];
            if (RELUA) { v.x = fmaxf(v.x, 0.f); v.y = fmaxf(v.y, 0.f);
                         v.z = fmaxf(v.z, 0.f); v.w = fmaxf(v.w, 0.f); }
            ushort4 hi;
            hi.x = f2bf(v.x); hi.y = f2bf(v.y); hi.z = f2bf(v.z); hi.w = f2bf(v.w);
            int c = f >> 1, half = f & 1;
            ((ushort4*)AS)[(r * 5 + c) * 2 + half] = hi;
            if (SPLIT) {
                ushort4 lo;
                lo.x = f2bf(v.x - bf2f(hi.x)); lo.y = f2bf(v.y - bf2f(hi.y));
                lo.z = f2bf(v.z - bf2f(hi.z)); lo.w = f2bf(v.w - bf2f(hi.w));
                ((ushort4*)(AS + 128 * 5))[(r * 5 + c) * 2 + half] = lo;
            }
        }
        // ---- stage B: 256 rows(n) x 32 k bf16 (pre-transposed in global) ----
        #pragma unroll
        for (int c = 0; c < 4; c++) {
            int4 vh = *(const int4*)&BgH[(size_t)tid * K + k0 + c * 8];
            BS[tid * 5 + c] = vh;
            if (SPLIT) {
                int4 vl = *(const int4*)&BgL[(size_t)tid * K + k0 + c * 8];
                BS[256 * 5 + tid * 5 + c] = vl;
            }
        }
        __syncthreads();

        const bf16x8* ASv = (const bf16x8*)AS;
        const bf16x8* BSv = (const bf16x8*)BS;
        const int slot = lane >> 4;             // k-slot group (same map for A & B)
        bf16x8 ah[2], al[2];
        #pragma unroll
        for (int mt = 0; mt < 2; mt++) {
            int r = w * 32 + mt * 16 + (lane & 15);
            ah[mt] = ASv[r * 5 + slot];
            if (SPLIT) al[mt] = ASv[128 * 5 + r * 5 + slot];
        }
        #pragma unroll
        for (int nt = 0; nt < 16; nt++) {
            int rb = nt * 16 + (lane & 15);
            bf16x8 bh = BSv[rb * 5 + slot];
            if (SPLIT) {
                bf16x8 bl = BSv[256 * 5 + rb * 5 + slot];
                #pragma unroll
                for (int mt = 0; mt < 2; mt++) {
                    acc[mt][nt] = __builtin_amdgcn_mfma_f32_16x16x32_bf16(ah[mt], bh, acc[mt][nt], 0, 0, 0);
                    acc[mt][nt] = __builtin_amdgcn_mfma_f32_16x16x32_bf16(ah[mt], bl, acc[mt][nt], 0, 0, 0);
                    acc[mt][nt] = __builtin_amdgcn_mfma_f32_16x16x32_bf16(al[mt], bh, acc[mt][nt], 0, 0, 0);
                }
            } else {
                #pragma unroll
                for (int mt = 0; mt < 2; mt++)
                    acc[mt][nt] = __builtin_amdgcn_mfma_f32_16x16x32_bf16(ah[mt], bh, acc[mt][nt], 0, 0, 0);
            }
        }
        __syncthreads();
    }

    // C/D layout (guide-verified): within 16x16 tile, col=lane&15, row=(lane>>4)*4+reg
    if (MODE == 0) {
        #pragma unroll
        for (int mt = 0; mt < 2; mt++)
            #pragma unroll
            for (int nt = 0; nt < 16; nt++) {
                int col = nt * 16 + (lane & 15);
                float bc = bias[col];
                #pragma unroll
                for (int rg = 0; rg < 4; rg++) {
                    int row = row0 + w * 32 + mt * 16 + (lane >> 4) * 4 + rg;
                    if (row < M) C[(size_t)row * 256 + col] = acc[mt][nt][rg] + bc;
                }
            }
    } else {
        float local = 0.f;
        #pragma unroll
        for (int nt = 0; nt < 16; nt++) {
            int col = nt * 16 + (lane & 15);
            float qc = q[col], bc = bias[col];
            #pragma unroll
            for (int mt = 0; mt < 2; mt++)
                #pragma unroll
                for (int rg = 0; rg < 4; rg++) {
                    int row = row0 + w * 32 + mt * 16 + (lane >> 4) * 4 + rg;
                    if (row < M) local += qc * tanhf(acc[mt][nt][rg] + bc);
                }
        }
        #pragma unroll
        for (int off = 32; off > 0; off >>= 1) local += __shfl_down(local, off, 64);
        if (lane == 0) red[w] = local;
        __syncthreads();
        if (tid == 0) atomicAdd(score + p, red[0] + red[1] + red[2] + red[3]);
    }
}

// ---- weight convert: W[K][256] f32 -> Wt_hi/Wt_lo [256][K] bf16 ----
__global__ __launch_bounds__(256)
void convert_w(const float* __restrict__ W, __hip_bfloat16* __restrict__ hi,
               __hip_bfloat16* __restrict__ lo, int K)
{
    int id = blockIdx.x * 256 + threadIdx.x;
    if (id >= K * 256) return;
    int n = id & 255, k = id >> 8;
    float v = W[id];                            // W[k][n], coalesced read
    unsigned short h = f2bf(v);
    hi[(size_t)n * K + k] = *(__hip_bfloat16*)&h;
    unsigned short l = f2bf(v - bf2f(h));
    lo[(size_t)n * K + k] = *(__hip_bfloat16*)&l;
}

// ---------------- per-node attention logits ----------------
__global__ __launch_bounds__(256)
void att_kernel(const float* __restrict__ z, const float* __restrict__ att_s,
                const float* __restrict__ att_d,
                float* __restrict__ a_src, float* __restrict__ a_dst)
{
    int idx = blockIdx.x * 256 + threadIdx.x;          // n*8 + h
    if (idx >= N_NODES * HEADS) return;
    int h = idx & 7, n = idx >> 3;
    const float4* zr = (const float4*)(z + (size_t)n * DHID + h * 32);
    const float4* as = (const float4*)(att_s + h * 32);
    const float4* ad = (const float4*)(att_d + h * 32);
    float s1 = 0.f, s2 = 0.f;
    #pragma unroll
    for (int i = 0; i < 8; i++) {
        float4 v = zr[i], a = as[i], b = ad[i];
        s1 += v.x * a.x + v.y * a.y + v.z * a.z + v.w * a.w;
        s2 += v.x * b.x + v.y * b.y + v.z * b.z + v.w * b.w;
    }
    a_src[idx] = s1; a_dst[idx] = s2;
}

// ================= CSR build =================
__global__ __launch_bounds__(256)
void hist_kernel(const int* __restrict__ edst, int* __restrict__ counts)
{
    int idx = blockIdx.x * 256 + threadIdx.x;
    if (idx >= P_TYPES * E_EDGES) return;
    int p = idx / E_EDGES;
    atomicAdd(&counts[p * N_NODES + edst[idx]], 1);
}

// hierarchical scan, stage 1: per-block (1024) exclusive scan + block totals
__global__ __launch_bounds__(1024)
void scan_block(const int* __restrict__ counts, int* __restrict__ out,
                int* __restrict__ blockSum, int total)
{
    __shared__ int wsum[16];
    int tid = threadIdx.x, lane = tid & 63, w = tid >> 6;
    int i = blockIdx.x * 1024 + tid;
    int v = (i < total) ? counts[i] : 0;
    int incl = v;
    #pragma unroll
    for (int off = 1; off < 64; off <<= 1) {
        int t = __shfl_up(incl, off, 64);
        if (lane >= off) incl += t;
    }
    if (lane == 63) wsum[w] = incl;
    __syncthreads();
    if (w == 0) {
        int s = (lane < 16) ? wsum[lane] : 0;
        #pragma unroll
        for (int off = 1; off < 16; off <<= 1) {
            int t = __shfl_up(s, off, 64);
            if (lane >= off) s += t;
        }
        if (lane < 16) wsum[lane] = s;
    }
    __syncthreads();
    int waveoff = w ? wsum[w - 1] : 0;
    if (i < total) out[i] = waveoff + incl - v;       // block-local exclusive
    if (tid == 1023 && blockSum) blockSum[blockIdx.x] = wsum[15];
}

// stage 3: add block offsets, write cursor copy, set sentinel
__global__ __launch_bounds__(1024)
void scan_add(int* __restrict__ row_start, int* __restrict__ cursor,
              const int* __restrict__ blockOff, int total)
{
    int i = blockIdx.x * 1024 + threadIdx.x;
    if (i == 0) row_start[total] = P_TYPES * E_EDGES;
    if (i < total) {
        int v = row_start[i] + blockOff[blockIdx.x];
        row_start[i] = v;
        cursor[i] = v;
    }
}

__global__ __launch_bounds__(256)
void fill_kernel(const int* __restrict__ esrc, const int* __restrict__ edst,
                 int* __restrict__ cursor, int* __restrict__ csr_src)
{
    int idx = blockIdx.x * 256 + threadIdx.x;
    if (idx >= P_TYPES * E_EDGES) return;
    int p = idx / E_EDGES;
    int pos = atomicAdd(&cursor[p * N_NODES + edst[idx]], 1);
    csr_src[pos] = esrc[idx];
}

// ---------------- CSR gather, head(=32-col)-tiled so z slice is L2-resident --
// blockIdx.y = head h; wave = 1 segment; 8 edges in flight (8 lanes x float4 each)
__global__ __launch_bounds__(256)
void gather_kernel(const int* __restrict__ row_start, const int* __restrict__ csr_src,
                   const float* __restrict__ a_src, const float* __restrict__ a_dst,
                   const float* __restrict__ z, float* __restrict__ outs)
{
    int seg = blockIdx.x * 4 + (threadIdx.x >> 6);      // p*N + dst  (grid exact)
    int h   = blockIdx.y;
    int lane = threadIdx.x & 63;
    int sub = lane >> 3, cl = lane & 7;                  // edge slot, col quad
    int dst = seg % N_NODES;
    float ad = a_dst[dst * HEADS + h];
    int start = row_start[seg], end = row_start[seg + 1];

    float ax = 0.f, ay = 0.f, az = 0.f, aw = 0.f, den = 0.f;
    for (int i = start + sub; i < end; i += 8) {
        int src = csr_src[i];
        float s = a_src[src * HEADS + h] + ad;
        float e = s > 0.f ? s : NEG_SLOPE * s;
        float wgt = __expf(e);
        float4 zv = *(const float4*)(z + (size_t)src * DHID + h * 32 + cl * 4);
        ax += wgt * zv.x; ay += wgt * zv.y; az += wgt * zv.z; aw += wgt * zv.w;
        den += wgt;
    }
    #pragma unroll
    for (int off = 8; off <= 32; off <<= 1) {
        ax += __shfl_xor(ax, off, 64); ay += __shfl_xor(ay, off, 64);
        az += __shfl_xor(az, off, 64); aw += __shfl_xor(aw, off, 64);
        den += __shfl_xor(den, off, 64);
    }
    if (sub == 0) {
        float inv = den > 0.f ? 1.0f / den : 0.f;
        *(float4*)(outs + (size_t)seg * DHID + h * 32 + cl * 4) =
            make_float4(ax * inv, ay * inv, az * inv, aw * inv);
    }
}

// ---------------- semantic softmax over P=4 ----------------
__global__ void beta_kernel(const float* __restrict__ score, float* __restrict__ beta)
{
    if (threadIdx.x == 0 && blockIdx.x == 0) {
        float s[P_TYPES]; float m = -1e30f;
        for (int p = 0; p < P_TYPES; p++) { s[p] = score[p] * (1.0f / N_NODES); m = fmaxf(m, s[p]); }
        float d = 0.f;
        for (int p = 0; p < P_TYPES; p++) { s[p] = __expf(s[p] - m); d += s[p]; }
        for (int p = 0; p < P_TYPES; p++) beta[p] = s[p] / d;
    }
}

// ---------------- weighted sum over types (+relu, optional elu) -------------
template<bool ELU>
__global__ __launch_bounds__(256)
void wsum_kernel(const float* __restrict__ outs, const float* __restrict__ beta,
                 float* __restrict__ hout)
{
    int idx = blockIdx.x * 256 + threadIdx.x;
    if (idx >= N_NODES * DHID / 4) return;
    float b[4] = {beta[0], beta[1], beta[2], beta[3]};
    const size_t stride = (size_t)N_NODES * DHID / 4;
    const float4* o = (const float4*)outs;
    float r[4] = {0.f, 0.f, 0.f, 0.f};
    #pragma unroll
    for (int p = 0; p < 4; p++) {
        float4 v = o[idx + p * stride];
        r[0] += b[p] * fmaxf(v.x, 0.f);
        r[1] += b[p] * fmaxf(v.y, 0.f);
        r[2] += b[p] * fmaxf(v.z, 0.f);
        r[3] += b[p] * fmaxf(v.w, 0.f);
    }
    if (ELU) {
        #pragma unroll
        for (int i = 0; i < 4; i++) r[i] = r[i] > 0.f ? r[i] : expm1f(r[i]);
    }
    ((float4*)hout)[idx] = make_float4(r[0], r[1], r[2], r[3]);
}

// ---------------- final classifier [N,256]@[256,16]+bo ----------------
__global__ __launch_bounds__(256)
void final_kernel(const float* __restrict__ h, const float* __restrict__ Wo,
                  const float* __restrict__ bo, float* __restrict__ out)
{
    int idx = blockIdx.x * 256 + threadIdx.x;
    if (idx >= N_NODES * NCLASSES) return;
    int c = idx & 15, n = idx >> 4;
    const float* hr = h + (size_t)n * DHID;
    float acc = bo[c];
    #pragma unroll 8
    for (int k = 0; k < DHID; k++) acc = fmaf(hr[k], Wo[k * NCLASSES + c], acc);
    out[idx] = acc;
}

extern "C" void kernel_launch(void* const* d_in, const int* in_sizes, int n_in,
                              void* d_out, int out_size, void* d_ws, size_t ws_size,
                              hipStream_t stream)
{
    const float* x   = (const float*)d_in[0];
    const int*  esrc = (const int*)d_in[1];
    const int*  edst = (const int*)d_in[2];
    const float* Wp1 = (const float*)d_in[3];
    const float* bp1 = (const float*)d_in[4];
    const float* as1 = (const float*)d_in[5];
    const float* ad1 = (const float*)d_in[6];
    const float* Wk1 = (const float*)d_in[7];
    const float* bk1 = (const float*)d_in[8];
    const float* q1  = (const float*)d_in[9];
    const float* Wp2 = (const float*)d_in[10];
    const float* bp2 = (const float*)d_in[11];
    const float* as2 = (const float*)d_in[12];
    const float* ad2 = (const float*)d_in[13];
    const float* Wk2 = (const float*)d_in[14];
    const float* bk2 = (const float*)d_in[15];
    const float* q2  = (const float*)d_in[16];
    const float* Wo  = (const float*)d_in[17];
    const float* bo  = (const float*)d_in[18];
    float* out = (float*)d_out;

    // workspace layout (f32 slots), ~131 MB total
    float* z     = (float*)d_ws;                 // 5,120,000
    float* hbuf  = z     + 5120000;              // 5,120,000
    float* a_s   = hbuf  + 5120000;              //   160,000
    float* a_d   = a_s   + 160000;               //   160,000
    float* outs  = a_d   + 160000;               // 20,480,000
    float* score = outs  + 20480000;             //         8
    float* beta  = score + 8;                    //         8
    __hip_bfloat16* Wpt_hi = (__hip_bfloat16*)(beta + 8);     //  65,536 slots (131072 bf16)
    __hip_bfloat16* Wpt_lo = (__hip_bfloat16*)(beta + 8 + 65536);
    __hip_bfloat16* Wkt_hi = (__hip_bfloat16*)(beta + 8 + 131072);  // 32,768 slots
    __hip_bfloat16* Wkt_lo = (__hip_bfloat16*)(beta + 8 + 163840);
    int* row_start = (int*)(beta + 8 + 196608);  //    80,004
    int* cursor    = row_start + 80004;          //    80,000
    int* blockSum  = cursor + 80000;             //       128
    int* blockOff  = blockSum + 128;             //       128
    int* csr_src   = blockOff + 128;             // 1,280,000

    const int PN = P_TYPES * N_NODES;            // 80,000
    const int PE = P_TYPES * E_EDGES;            // 1,280,000
    const int NBS = (PN + 1023) / 1024;          // 79 scan blocks

    // ---- CSR build (edge structure shared by both layers) ----
    hipMemsetAsync(cursor, 0, PN * sizeof(int), stream);
    hist_kernel<<<(PE + 255) / 256, 256, 0, stream>>>(edst, cursor);
    scan_block<<<NBS, 1024, 0, stream>>>(cursor, row_start, blockSum, PN);
    scan_block<<<1, 1024, 0, stream>>>(blockSum, blockOff, nullptr, NBS);
    scan_add<<<NBS, 1024, 0, stream>>>(row_start, cursor, blockOff, PN);
    fill_kernel<<<(PE + 255) / 256, 256, 0, stream>>>(esrc, edst, cursor, csr_src);

    auto run_layer = [&](const float* xin, int K, const float* Wp, const float* bp,
                         const float* atts, const float* attd, const float* Wk,
                         const float* bk, const float* q, float* hout, bool elu) {
        hipMemsetAsync(score, 0, 8 * sizeof(float), stream);

        convert_w<<<(K * 256 + 255) / 256, 256, 0, stream>>>(Wp, Wpt_hi, Wpt_lo, K);
        dim3 g1((N_NODES + 127) / 128, 1);
        mfma_gemm<true, false, 0><<<g1, 256, 0, stream>>>(
            xin, Wpt_hi, Wpt_lo, bp, z, nullptr, nullptr, N_NODES, K, 0);

        att_kernel<<<(N_NODES * HEADS + 255) / 256, 256, 0, stream>>>(z, atts, attd, a_s, a_d);
        dim3 gg(PN / 4, HEADS);
        gather_kernel<<<gg, 256, 0, stream>>>(row_start, csr_src, a_s, a_d, z, outs);

        convert_w<<<(256 * 256 + 255) / 256, 256, 0, stream>>>(Wk, Wkt_hi, Wkt_lo, 256);
        dim3 g2((N_NODES + 127) / 128, P_TYPES);
        mfma_gemm<false, true, 1><<<g2, 256, 0, stream>>>(
            outs, Wkt_hi, nullptr, bk, nullptr, q, score, N_NODES, 256, (size_t)N_NODES * DHID);

        beta_kernel<<<1, 64, 0, stream>>>(score, beta);
        if (elu)
            wsum_kernel<true><<<(N_NODES * 64 + 255) / 256, 256, 0, stream>>>(outs, beta, hout);
        else
            wsum_kernel<false><<<(N_NODES * 64 + 255) / 256, 256, 0, stream>>>(outs, beta, hout);
    };

    run_layer(x,    512, Wp1, bp1, as1, ad1, Wk1, bk1, q1, hbuf, true);
    run_layer(hbuf, 256, Wp2, bp2, as2, ad2, Wk2, bk2, q2, hbuf, false);

    final_kernel<<<(N_NODES * NCLASSES + 255) / 256, 256, 0, stream>>>(hbuf, Wo, bo, out);
}

// Round 4
// 743.087 us; speedup vs baseline: 12.2808x; 1.2940x over previous
//
#include <hip/hip_runtime.h>
#include <hip/hip_bf16.h>
#include <cstdint>

#define N_NODES 20000
#define E_EDGES 320000
#define P_TYPES 4
#define HEADS   8
#define DHID    256
#define NCLASSES 16
#define NEG_SLOPE 0.2f

typedef __attribute__((ext_vector_type(8))) short bf16x8;
typedef __attribute__((ext_vector_type(8))) unsigned short ushort8;
typedef __attribute__((ext_vector_type(4))) float f32x4;

static __device__ __forceinline__ unsigned short f2bf(float v) {
    __hip_bfloat16 h = __float2bfloat16(v);
    return *(unsigned short*)&h;
}
static __device__ __forceinline__ float bf2f(unsigned short u) {
    __hip_bfloat16 h = *(__hip_bfloat16*)&u;
    return __bfloat162float(h);
}

// ================= MFMA GEMM: C[M x 256] = A[M x K] @ B[K x 256] =============
// B supplied TRANSPOSED bf16: Bth/Btl are [256][K] (hi / lo split halves).
// SPLIT: A staged as hi+lo bf16, 3 MFMAs (fp32-grade precision, projections)
// !SPLIT: A staged hi-only (semantic-score GEMM; error averages out in mean)
// MODE 0: C = acc + bias      MODE 1: atomicAdd(score[p], sum q[c]*tanh(acc+bias[c]))
// RELUA: relu(A) on load.  256 thr = 4 waves; BM=128, BN=256, BK=32.
// LDS rows padded to 5 int4 (80B) -> conflict-free ds_read_b128.
template<bool SPLIT, bool RELUA, int MODE>
__global__ __launch_bounds__(256)
void mfma_gemm(const float* __restrict__ A, const __hip_bfloat16* __restrict__ Bth,
               const __hip_bfloat16* __restrict__ Btl, const float* __restrict__ bias,
               float* __restrict__ C, const float* __restrict__ q,
               float* __restrict__ score, int M, int K, size_t aBatch)
{
    constexpr int NB = SPLIT ? 2 : 1;
    __shared__ int4 AS[NB * 128 * 5];
    __shared__ int4 BS[NB * 256 * 5];
    __shared__ float red[4];
    const int p = blockIdx.y;
    const float* Ag = A + (size_t)p * aBatch;
    const unsigned short* BgH = (const unsigned short*)Bth;
    const unsigned short* BgL = (const unsigned short*)Btl;
    const int row0 = blockIdx.x * 128;
    const int tid = threadIdx.x, lane = tid & 63, w = tid >> 6;

    f32x4 acc[2][16];
    const f32x4 zero4 = {0.f, 0.f, 0.f, 0.f};
    #pragma unroll
    for (int i = 0; i < 2; i++)
        #pragma unroll
        for (int j = 0; j < 16; j++) acc[i][j] = zero4;

    for (int k0 = 0; k0 < K; k0 += 32) {
        #pragma unroll
        for (int it = 0; it < 4; it++) {
            int id = tid + it * 256;
            int r = id >> 3, f = id & 7;
            int row_g = row0 + r;
            float4 v = make_float4(0.f, 0.f, 0.f, 0.f);
            if (row_g < M) v = *(const float4*)&Ag[(size_t)row_g * K + k0 + f * 4];
            if (RELUA) { v.x = fmaxf(v.x, 0.f); v.y = fmaxf(v.y, 0.f);
                         v.z = fmaxf(v.z, 0.f); v.w = fmaxf(v.w, 0.f); }
            ushort4 hi;
            hi.x = f2bf(v.x); hi.y = f2bf(v.y); hi.z = f2bf(v.z); hi.w = f2bf(v.w);
            int c = f >> 1, half = f & 1;
            ((ushort4*)AS)[(r * 5 + c) * 2 + half] = hi;
            if (SPLIT) {
                ushort4 lo;
                lo.x = f2bf(v.x - bf2f(hi.x)); lo.y = f2bf(v.y - bf2f(hi.y));
                lo.z = f2bf(v.z - bf2f(hi.z)); lo.w = f2bf(v.w - bf2f(hi.w));
                ((ushort4*)(AS + 128 * 5))[(r * 5 + c) * 2 + half] = lo;
            }
        }
        #pragma unroll
        for (int c = 0; c < 4; c++) {
            int4 vh = *(const int4*)&BgH[(size_t)tid * K + k0 + c * 8];
            BS[tid * 5 + c] = vh;
            if (SPLIT) {
                int4 vl = *(const int4*)&BgL[(size_t)tid * K + k0 + c * 8];
                BS[256 * 5 + tid * 5 + c] = vl;
            }
        }
        __syncthreads();

        const bf16x8* ASv = (const bf16x8*)AS;
        const bf16x8* BSv = (const bf16x8*)BS;
        const int slot = lane >> 4;
        bf16x8 ah[2], al[2];
        #pragma unroll
        for (int mt = 0; mt < 2; mt++) {
            int r = w * 32 + mt * 16 + (lane & 15);
            ah[mt] = ASv[r * 5 + slot];
            if (SPLIT) al[mt] = ASv[128 * 5 + r * 5 + slot];
        }
        #pragma unroll
        for (int nt = 0; nt < 16; nt++) {
            int rb = nt * 16 + (lane & 15);
            bf16x8 bh = BSv[rb * 5 + slot];
            if (SPLIT) {
                bf16x8 bl = BSv[256 * 5 + rb * 5 + slot];
                #pragma unroll
                for (int mt = 0; mt < 2; mt++) {
                    acc[mt][nt] = __builtin_amdgcn_mfma_f32_16x16x32_bf16(ah[mt], bh, acc[mt][nt], 0, 0, 0);
                    acc[mt][nt] = __builtin_amdgcn_mfma_f32_16x16x32_bf16(ah[mt], bl, acc[mt][nt], 0, 0, 0);
                    acc[mt][nt] = __builtin_amdgcn_mfma_f32_16x16x32_bf16(al[mt], bh, acc[mt][nt], 0, 0, 0);
                }
            } else {
                #pragma unroll
                for (int mt = 0; mt < 2; mt++)
                    acc[mt][nt] = __builtin_amdgcn_mfma_f32_16x16x32_bf16(ah[mt], bh, acc[mt][nt], 0, 0, 0);
            }
        }
        __syncthreads();
    }

    if (MODE == 0) {
        #pragma unroll
        for (int mt = 0; mt < 2; mt++)
            #pragma unroll
            for (int nt = 0; nt < 16; nt++) {
                int col = nt * 16 + (lane & 15);
                float bc = bias[col];
                #pragma unroll
                for (int rg = 0; rg < 4; rg++) {
                    int row = row0 + w * 32 + mt * 16 + (lane >> 4) * 4 + rg;
                    if (row < M) C[(size_t)row * 256 + col] = acc[mt][nt][rg] + bc;
                }
            }
    } else {
        float local = 0.f;
        #pragma unroll
        for (int nt = 0; nt < 16; nt++) {
            int col = nt * 16 + (lane & 15);
            float qc = q[col], bc = bias[col];
            #pragma unroll
            for (int mt = 0; mt < 2; mt++)
                #pragma unroll
                for (int rg = 0; rg < 4; rg++) {
                    int row = row0 + w * 32 + mt * 16 + (lane >> 4) * 4 + rg;
                    if (row < M) local += qc * tanhf(acc[mt][nt][rg] + bc);
                }
        }
        #pragma unroll
        for (int off = 32; off > 0; off >>= 1) local += __shfl_down(local, off, 64);
        if (lane == 0) red[w] = local;
        __syncthreads();
        if (tid == 0) atomicAdd(score + p, red[0] + red[1] + red[2] + red[3]);
    }
}

// ---- weight convert: W[K][256] f32 -> Wt_hi[/lo] [256][K] bf16 ----
__global__ __launch_bounds__(256)
void convert_w(const float* __restrict__ W, __hip_bfloat16* __restrict__ hi,
               __hip_bfloat16* __restrict__ lo, int K)
{
    int id = blockIdx.x * 256 + threadIdx.x;
    if (id >= K * 256) return;
    int n = id & 255, k = id >> 8;
    float v = W[id];
    unsigned short h = f2bf(v);
    hi[(size_t)n * K + k] = *(__hip_bfloat16*)&h;
    if (lo) {
        unsigned short l = f2bf(v - bf2f(h));
        lo[(size_t)n * K + k] = *(__hip_bfloat16*)&l;
    }
}

// ---- z (f32) -> zb (bf16), 8 elems/thread ----
__global__ __launch_bounds__(256)
void convert_z(const float* __restrict__ z, unsigned short* __restrict__ zb)
{
    int idx = blockIdx.x * 256 + threadIdx.x;          // ushort8 index
    if (idx >= N_NODES * DHID / 8) return;
    float4 v0 = ((const float4*)z)[idx * 2];
    float4 v1 = ((const float4*)z)[idx * 2 + 1];
    ushort8 o;
    o[0] = f2bf(v0.x); o[1] = f2bf(v0.y); o[2] = f2bf(v0.z); o[3] = f2bf(v0.w);
    o[4] = f2bf(v1.x); o[5] = f2bf(v1.y); o[6] = f2bf(v1.z); o[7] = f2bf(v1.w);
    ((ushort8*)zb)[idx] = o;
}

// ---------------- per-node attention logits (f32 z for exp precision) -------
__global__ __launch_bounds__(256)
void att_kernel(const float* __restrict__ z, const float* __restrict__ att_s,
                const float* __restrict__ att_d,
                float* __restrict__ a_src, float* __restrict__ a_dst)
{
    int idx = blockIdx.x * 256 + threadIdx.x;          // n*8 + h
    if (idx >= N_NODES * HEADS) return;
    int h = idx & 7, n = idx >> 3;
    const float4* zr = (const float4*)(z + (size_t)n * DHID + h * 32);
    const float4* as = (const float4*)(att_s + h * 32);
    const float4* ad = (const float4*)(att_d + h * 32);
    float s1 = 0.f, s2 = 0.f;
    #pragma unroll
    for (int i = 0; i < 8; i++) {
        float4 v = zr[i], a = as[i], b = ad[i];
        s1 += v.x * a.x + v.y * a.y + v.z * a.z + v.w * a.w;
        s2 += v.x * b.x + v.y * b.y + v.z * b.z + v.w * b.w;
    }
    a_src[idx] = s1; a_dst[idx] = s2;
}

// ================= CSR build =================
__global__ __launch_bounds__(256)
void hist_kernel(const int* __restrict__ edst, int* __restrict__ counts)
{
    int idx = blockIdx.x * 256 + threadIdx.x;
    if (idx >= P_TYPES * E_EDGES) return;
    int p = idx / E_EDGES;
    atomicAdd(&counts[p * N_NODES + edst[idx]], 1);
}

__global__ __launch_bounds__(1024)
void scan_block(const int* __restrict__ counts, int* __restrict__ out,
                int* __restrict__ blockSum, int total)
{
    __shared__ int wsum[16];
    int tid = threadIdx.x, lane = tid & 63, w = tid >> 6;
    int i = blockIdx.x * 1024 + tid;
    int v = (i < total) ? counts[i] : 0;
    int incl = v;
    #pragma unroll
    for (int off = 1; off < 64; off <<= 1) {
        int t = __shfl_up(incl, off, 64);
        if (lane >= off) incl += t;
    }
    if (lane == 63) wsum[w] = incl;
    __syncthreads();
    if (w == 0) {
        int s = (lane < 16) ? wsum[lane] : 0;
        #pragma unroll
        for (int off = 1; off < 16; off <<= 1) {
            int t = __shfl_up(s, off, 64);
            if (lane >= off) s += t;
        }
        if (lane < 16) wsum[lane] = s;
    }
    __syncthreads();
    int waveoff = w ? wsum[w - 1] : 0;
    if (i < total) out[i] = waveoff + incl - v;
    if (tid == 1023 && blockSum) blockSum[blockIdx.x] = wsum[15];
}

__global__ __launch_bounds__(1024)
void scan_add(int* __restrict__ row_start, int* __restrict__ cursor,
              const int* __restrict__ blockOff, int total)
{
    int i = blockIdx.x * 1024 + threadIdx.x;
    if (i == 0) row_start[total] = P_TYPES * E_EDGES;
    if (i < total) {
        int v = row_start[i] + blockOff[blockIdx.x];
        row_start[i] = v;
        cursor[i] = v;
    }
}

__global__ __launch_bounds__(256)
void fill_kernel(const int* __restrict__ esrc, const int* __restrict__ edst,
                 int* __restrict__ cursor, int* __restrict__ csr_src)
{
    int idx = blockIdx.x * 256 + threadIdx.x;
    if (idx >= P_TYPES * E_EDGES) return;
    int p = idx / E_EDGES;
    int pos = atomicAdd(&cursor[p * N_NODES + edst[idx]], 1);
    csr_src[pos] = esrc[idx];
}

// ---------------- CSR gather: 1 wave/segment, all heads, bf16 z rows --------
// 2 edges in flight (sub=lane>>5); lane cl=lane&31 covers cols [cl*8,cl*8+8),
// head h=cl>>2. Per iter each 32-lane half reads one 512B bf16 row, coalesced.
__global__ __launch_bounds__(256)
void gather_kernel(const int* __restrict__ row_start, const int* __restrict__ csr_src,
                   const float* __restrict__ a_src, const float* __restrict__ a_dst,
                   const unsigned short* __restrict__ zb, float* __restrict__ outs)
{
    int seg = blockIdx.x * 4 + (threadIdx.x >> 6);      // p*N + dst (grid exact)
    int lane = threadIdx.x & 63;
    int sub = lane >> 5, cl = lane & 31;
    int h = cl >> 2;
    int dst = seg % N_NODES;
    float ad = a_dst[dst * HEADS + h];
    int start = row_start[seg], end = row_start[seg + 1];

    float acc[8] = {};
    float den = 0.f;
    for (int i = start + sub; i < end; i += 2) {
        int src = csr_src[i];
        float s = a_src[src * HEADS + h] + ad;
        float e = s > 0.f ? s : NEG_SLOPE * s;
        float wgt = __expf(e);
        ushort8 zv = *(const ushort8*)(zb + (size_t)src * DHID + cl * 8);
        #pragma unroll
        for (int j = 0; j < 8; j++) acc[j] += wgt * bf2f(zv[j]);
        den += wgt;
    }
    den += __shfl_xor(den, 32, 64);
    #pragma unroll
    for (int j = 0; j < 8; j++) acc[j] += __shfl_xor(acc[j], 32, 64);
    if (sub == 0) {
        float inv = den > 0.f ? 1.0f / den : 0.f;
        float* op = outs + (size_t)seg * DHID + cl * 8;
        *(float4*)op       = make_float4(acc[0]*inv, acc[1]*inv, acc[2]*inv, acc[3]*inv);
        *(float4*)(op + 4) = make_float4(acc[4]*inv, acc[5]*inv, acc[6]*inv, acc[7]*inv);
    }
}

// ---------------- semantic softmax over P=4 ----------------
__global__ void beta_kernel(const float* __restrict__ score, float* __restrict__ beta)
{
    if (threadIdx.x == 0 && blockIdx.x == 0) {
        float s[P_TYPES]; float m = -1e30f;
        for (int p = 0; p < P_TYPES; p++) { s[p] = score[p] * (1.0f / N_NODES); m = fmaxf(m, s[p]); }
        float d = 0.f;
        for (int p = 0; p < P_TYPES; p++) { s[p] = __expf(s[p] - m); d += s[p]; }
        for (int p = 0; p < P_TYPES; p++) beta[p] = s[p] / d;
    }
}

// ---------------- weighted sum over types (+relu, optional elu) -------------
template<bool ELU>
__global__ __launch_bounds__(256)
void wsum_kernel(const float* __restrict__ outs, const float* __restrict__ beta,
                 float* __restrict__ hout)
{
    int idx = blockIdx.x * 256 + threadIdx.x;
    if (idx >= N_NODES * DHID / 4) return;
    float b[4] = {beta[0], beta[1], beta[2], beta[3]};
    const size_t stride = (size_t)N_NODES * DHID / 4;
    const float4* o = (const float4*)outs;
    float r[4] = {0.f, 0.f, 0.f, 0.f};
    #pragma unroll
    for (int p = 0; p < 4; p++) {
        float4 v = o[idx + p * stride];
        r[0] += b[p] * fmaxf(v.x, 0.f);
        r[1] += b[p] * fmaxf(v.y, 0.f);
        r[2] += b[p] * fmaxf(v.z, 0.f);
        r[3] += b[p] * fmaxf(v.w, 0.f);
    }
    if (ELU) {
        #pragma unroll
        for (int i = 0; i < 4; i++) r[i] = r[i] > 0.f ? r[i] : expm1f(r[i]);
    }
    ((float4*)hout)[idx] = make_float4(r[0], r[1], r[2], r[3]);
}

// ---------------- final classifier [N,256]@[256,16]+bo ----------------
__global__ __launch_bounds__(256)
void final_kernel(const float* __restrict__ h, const float* __restrict__ Wo,
                  const float* __restrict__ bo, float* __restrict__ out)
{
    int idx = blockIdx.x * 256 + threadIdx.x;
    if (idx >= N_NODES * NCLASSES) return;
    int c = idx & 15, n = idx >> 4;
    const float* hr = h + (size_t)n * DHID;
    float acc = bo[c];
    #pragma unroll 8
    for (int k = 0; k < DHID; k++) acc = fmaf(hr[k], Wo[k * NCLASSES + c], acc);
    out[idx] = acc;
}

extern "C" void kernel_launch(void* const* d_in, const int* in_sizes, int n_in,
                              void* d_out, int out_size, void* d_ws, size_t ws_size,
                              hipStream_t stream)
{
    const float* x   = (const float*)d_in[0];
    const int*  esrc = (const int*)d_in[1];
    const int*  edst = (const int*)d_in[2];
    const float* Wp1 = (const float*)d_in[3];
    const float* bp1 = (const float*)d_in[4];
    const float* as1 = (const float*)d_in[5];
    const float* ad1 = (const float*)d_in[6];
    const float* Wk1 = (const float*)d_in[7];
    const float* bk1 = (const float*)d_in[8];
    const float* q1  = (const float*)d_in[9];
    const float* Wp2 = (const float*)d_in[10];
    const float* bp2 = (const float*)d_in[11];
    const float* as2 = (const float*)d_in[12];
    const float* ad2 = (const float*)d_in[13];
    const float* Wk2 = (const float*)d_in[14];
    const float* bk2 = (const float*)d_in[15];
    const float* q2  = (const float*)d_in[16];
    const float* Wo  = (const float*)d_in[17];
    const float* bo  = (const float*)d_in[18];
    float* out = (float*)d_out;

    // workspace layout (f32 slots), ~141 MB total
    float* z     = (float*)d_ws;                 //  5,120,000
    float* hbuf  = z     + 5120000;              //  5,120,000
    float* a_s   = hbuf  + 5120000;              //    160,000
    float* a_d   = a_s   + 160000;               //    160,000
    float* outs  = a_d   + 160000;               // 20,480,000
    float* score = outs  + 20480000;             //          8
    float* beta  = score + 8;                    //          8
    unsigned short* zb = (unsigned short*)(beta + 8);              // 5,120,000 bf16
    __hip_bfloat16* Wp1t_hi = (__hip_bfloat16*)(beta + 8 + 2560000);
    __hip_bfloat16* Wp1t_lo = Wp1t_hi + 131072;
    __hip_bfloat16* Wp2t_hi = Wp1t_lo + 131072;
    __hip_bfloat16* Wp2t_lo = Wp2t_hi + 65536;
    __hip_bfloat16* Wk1t_hi = Wp2t_lo + 65536;
    __hip_bfloat16* Wk2t_hi = Wk1t_hi + 65536;
    int* row_start = (int*)(Wk2t_hi + 65536);    //     80,004
    int* cursor    = row_start + 80004;          //     80,000
    int* blockSum  = cursor + 80000;             //        128
    int* blockOff  = blockSum + 128;             //        128
    int* csr_src   = blockOff + 128;             //  1,280,000

    const int PN = P_TYPES * N_NODES;            // 80,000
    const int PE = P_TYPES * E_EDGES;            // 1,280,000
    const int NBS = (PN + 1023) / 1024;          // 79

    // ---- weight conversions (once) ----
    convert_w<<<(512 * 256 + 255) / 256, 256, 0, stream>>>(Wp1, Wp1t_hi, Wp1t_lo, 512);
    convert_w<<<(256 * 256 + 255) / 256, 256, 0, stream>>>(Wp2, Wp2t_hi, Wp2t_lo, 256);
    convert_w<<<(256 * 256 + 255) / 256, 256, 0, stream>>>(Wk1, Wk1t_hi, nullptr, 256);
    convert_w<<<(256 * 256 + 255) / 256, 256, 0, stream>>>(Wk2, Wk2t_hi, nullptr, 256);

    // ---- CSR build (edge structure shared by both layers) ----
    hipMemsetAsync(cursor, 0, PN * sizeof(int), stream);
    hist_kernel<<<(PE + 255) / 256, 256, 0, stream>>>(edst, cursor);
    scan_block<<<NBS, 1024, 0, stream>>>(cursor, row_start, blockSum, PN);
    scan_block<<<1, 1024, 0, stream>>>(blockSum, blockOff, nullptr, NBS);
    scan_add<<<NBS, 1024, 0, stream>>>(row_start, cursor, blockOff, PN);
    fill_kernel<<<(PE + 255) / 256, 256, 0, stream>>>(esrc, edst, cursor, csr_src);

    auto run_layer = [&](const float* xin, int K, const __hip_bfloat16* Wpt_hi,
                         const __hip_bfloat16* Wpt_lo, const float* bp,
                         const float* atts, const float* attd,
                         const __hip_bfloat16* Wkt_hi, const float* bk,
                         const float* q, float* hout, bool elu) {
        hipMemsetAsync(score, 0, 8 * sizeof(float), stream);

        dim3 g1((N_NODES + 127) / 128, 1);
        mfma_gemm<true, false, 0><<<g1, 256, 0, stream>>>(
            xin, Wpt_hi, Wpt_lo, bp, z, nullptr, nullptr, N_NODES, K, 0);

        convert_z<<<(N_NODES * DHID / 8 + 255) / 256, 256, 0, stream>>>(z, zb);
        att_kernel<<<(N_NODES * HEADS + 255) / 256, 256, 0, stream>>>(z, atts, attd, a_s, a_d);
        gather_kernel<<<PN / 4, 256, 0, stream>>>(row_start, csr_src, a_s, a_d, zb, outs);

        dim3 g2((N_NODES + 127) / 128, P_TYPES);
        mfma_gemm<false, true, 1><<<g2, 256, 0, stream>>>(
            outs, Wkt_hi, nullptr, bk, nullptr, q, score, N_NODES, 256, (size_t)N_NODES * DHID);

        beta_kernel<<<1, 64, 0, stream>>>(score, beta);
        if (elu)
            wsum_kernel<true><<<(N_NODES * 64 + 255) / 256, 256, 0, stream>>>(outs, beta, hout);
        else
            wsum_kernel<false><<<(N_NODES * 64 + 255) / 256, 256, 0, stream>>>(outs, beta, hout);
    };

    run_layer(x,    512, Wp1t_hi, Wp1t_lo, bp1, as1, ad1, Wk1t_hi, bk1, q1, hbuf, true);
    run_layer(hbuf, 256, Wp2t_hi, Wp2t_lo, bp2, as2, ad2, Wk2t_hi, bk2, q2, hbuf, false);

    final_kernel<<<(N_NODES * NCLASSES + 255) / 256, 256, 0, stream>>>(hbuf, Wo, bo, out);
}

// Round 5
// 613.408 us; speedup vs baseline: 14.8770x; 1.2114x over previous
//
#include <hip/hip_runtime.h>
#include <hip/hip_bf16.h>
#include <cstdint>

#define N_NODES 20000
#define E_EDGES 320000
#define P_TYPES 4
#define HEADS   8
#define DHID    256
#define NCLASSES 16
#define NEG_SLOPE 0.2f

typedef __attribute__((ext_vector_type(8))) short bf16x8;
typedef __attribute__((ext_vector_type(8))) unsigned short ushort8;
typedef __attribute__((ext_vector_type(4))) float f32x4;

static __device__ __forceinline__ unsigned short f2bf(float v) {
    __hip_bfloat16 h = __float2bfloat16(v);
    return *(unsigned short*)&h;
}
static __device__ __forceinline__ float bf2f(unsigned short u) {
    __hip_bfloat16 h = *(__hip_bfloat16*)&u;
    return __bfloat162float(h);
}
static __device__ __forceinline__ float fast_tanh(float x) {
    x = fminf(fmaxf(x, -10.f), 10.f);
    float t = __expf(2.f * x);
    return (t - 1.f) / (t + 1.f);
}

// ================= MFMA GEMM: C[M x 256] = A[M x K] @ B[K x 256] =============
// B supplied bf16 in k-tiled layout [K/32][256][32] (hi / lo halves) so the
// per-k-step stage load is lane-consecutive (coalesced).
// SPLIT: A,B staged hi+lo bf16, 3 MFMAs (fp32-grade, projections)
// !SPLIT: hi only (semantic-score GEMM; bf16 error averages out in the mean)
// MODE 0: C = acc + bias
// MODE 1: atomicAdd(score[row/N_NODES], sum q[c]*tanh(acc+bias[c]))  (M merged over P)
// Block: 256 thr = 4 waves; tile BM=64 x BN=256, BK=32. Wave w owns all 64 rows
// x cols [w*64, w*64+64) = 4x4 tiles of 16x16x32 MFMA.
// LDS rows padded to 5 int4 (80B) -> conflict-free ds_read_b128.
template<bool SPLIT, bool RELUA, int MODE>
__global__ __launch_bounds__(256)
void mfma_gemm(const float* __restrict__ A, const unsigned short* __restrict__ BgH,
               const unsigned short* __restrict__ BgL, const float* __restrict__ bias,
               float* __restrict__ C, const float* __restrict__ q,
               float* __restrict__ score, int M, int K)
{
    constexpr int NB = SPLIT ? 2 : 1;
    __shared__ int4 AS[NB * 64 * 5];
    __shared__ int4 BS[NB * 256 * 5];
    __shared__ float red[4][2];
    const int row0 = blockIdx.x * 64;
    const int tid = threadIdx.x, lane = tid & 63, w = tid >> 6;

    f32x4 acc[4][4];
    const f32x4 zero4 = {0.f, 0.f, 0.f, 0.f};
    #pragma unroll
    for (int i = 0; i < 4; i++)
        #pragma unroll
        for (int j = 0; j < 4; j++) acc[i][j] = zero4;

    for (int k0 = 0; k0 < K; k0 += 32) {
        // ---- stage A: 64 rows x 32 k (f32 -> bf16 hi[/lo]) ----
        #pragma unroll
        for (int it = 0; it < 2; it++) {
            int id = tid + it * 256;            // 0..511
            int r = id >> 3, f = id & 7;
            int row_g = row0 + r;
            float4 v = make_float4(0.f, 0.f, 0.f, 0.f);
            if (row_g < M) v = *(const float4*)&A[(size_t)row_g * K + k0 + f * 4];
            if (RELUA) { v.x = fmaxf(v.x, 0.f); v.y = fmaxf(v.y, 0.f);
                         v.z = fmaxf(v.z, 0.f); v.w = fmaxf(v.w, 0.f); }
            ushort4 hi;
            hi.x = f2bf(v.x); hi.y = f2bf(v.y); hi.z = f2bf(v.z); hi.w = f2bf(v.w);
            int c = f >> 1, half = f & 1;
            ((ushort4*)AS)[(r * 5 + c) * 2 + half] = hi;
            if (SPLIT) {
                ushort4 lo;
                lo.x = f2bf(v.x - bf2f(hi.x)); lo.y = f2bf(v.y - bf2f(hi.y));
                lo.z = f2bf(v.z - bf2f(hi.z)); lo.w = f2bf(v.w - bf2f(hi.w));
                ((ushort4*)(AS + 64 * 5))[(r * 5 + c) * 2 + half] = lo;
            }
        }
        // ---- stage B: one k-tile [256][32] bf16, coalesced (k-tiled global) --
        size_t bbase = (size_t)(k0 >> 5) * (256 * 32);
        #pragma unroll
        for (int it = 0; it < 4; it++) {
            int id = tid + it * 256;            // int4 index 0..1023
            int4 vh = *(const int4*)&BgH[bbase + (size_t)id * 8];
            BS[(id >> 2) * 5 + (id & 3)] = vh;
            if (SPLIT) {
                int4 vl = *(const int4*)&BgL[bbase + (size_t)id * 8];
                BS[256 * 5 + (id >> 2) * 5 + (id & 3)] = vl;
            }
        }
        __syncthreads();

        const bf16x8* ASv = (const bf16x8*)AS;
        const bf16x8* BSv = (const bf16x8*)BS;
        const int slot = lane >> 4;             // k-slot group (same map A & B)
        bf16x8 ah[4], al[4];
        #pragma unroll
        for (int mt = 0; mt < 4; mt++) {
            int r = mt * 16 + (lane & 15);
            ah[mt] = ASv[r * 5 + slot];
            if (SPLIT) al[mt] = ASv[64 * 5 + r * 5 + slot];
        }
        #pragma unroll
        for (int nt = 0; nt < 4; nt++) {
            int rb = (w * 4 + nt) * 16 + (lane & 15);
            bf16x8 bh = BSv[rb * 5 + slot];
            if (SPLIT) {
                bf16x8 bl = BSv[256 * 5 + rb * 5 + slot];
                #pragma unroll
                for (int mt = 0; mt < 4; mt++) {
                    acc[mt][nt] = __builtin_amdgcn_mfma_f32_16x16x32_bf16(ah[mt], bh, acc[mt][nt], 0, 0, 0);
                    acc[mt][nt] = __builtin_amdgcn_mfma_f32_16x16x32_bf16(ah[mt], bl, acc[mt][nt], 0, 0, 0);
                    acc[mt][nt] = __builtin_amdgcn_mfma_f32_16x16x32_bf16(al[mt], bh, acc[mt][nt], 0, 0, 0);
                }
            } else {
                #pragma unroll
                for (int mt = 0; mt < 4; mt++)
                    acc[mt][nt] = __builtin_amdgcn_mfma_f32_16x16x32_bf16(ah[mt], bh, acc[mt][nt], 0, 0, 0);
            }
        }
        __syncthreads();
    }

    // C/D layout (guide-verified): within 16x16 tile, col=lane&15, row=(lane>>4)*4+reg
    if (MODE == 0) {
        #pragma unroll
        for (int mt = 0; mt < 4; mt++)
            #pragma unroll
            for (int nt = 0; nt < 4; nt++) {
                int col = (w * 4 + nt) * 16 + (lane & 15);
                float bc = bias[col];
                #pragma unroll
                for (int rg = 0; rg < 4; rg++) {
                    int row = row0 + mt * 16 + (lane >> 4) * 4 + rg;
                    if (row < M) C[(size_t)row * 256 + col] = acc[mt][nt][rg] + bc;
                }
            }
    } else {
        const int pbase = row0 / N_NODES;
        const int rowSplit = (pbase + 1) * N_NODES;
        float l0 = 0.f, l1 = 0.f;
        #pragma unroll
        for (int nt = 0; nt < 4; nt++) {
            int col = (w * 4 + nt) * 16 + (lane & 15);
            float qc = q[col], bc = bias[col];
            #pragma unroll
            for (int mt = 0; mt < 4; mt++)
                #pragma unroll
                for (int rg = 0; rg < 4; rg++) {
                    int row = row0 + mt * 16 + (lane >> 4) * 4 + rg;
                    if (row < M) {
                        float v = qc * fast_tanh(acc[mt][nt][rg] + bc);
                        if (row >= rowSplit) l1 += v; else l0 += v;
                    }
                }
        }
        #pragma unroll
        for (int off = 32; off > 0; off >>= 1) {
            l0 += __shfl_down(l0, off, 64);
            l1 += __shfl_down(l1, off, 64);
        }
        if (lane == 0) { red[w][0] = l0; red[w][1] = l1; }
        __syncthreads();
        if (tid == 0)
            atomicAdd(score + pbase, red[0][0] + red[1][0] + red[2][0] + red[3][0]);
        if (tid == 1 && pbase + 1 < P_TYPES)
            atomicAdd(score + pbase + 1, red[0][1] + red[1][1] + red[2][1] + red[3][1]);
    }
}

// ---- weight convert: W[K][256] f32 -> k-tiled bf16 [K/32][256][32] hi[/lo] ----
__global__ __launch_bounds__(256)
void convert_w(const float* __restrict__ W, unsigned short* __restrict__ hi,
               unsigned short* __restrict__ lo, int K)
{
    int id = blockIdx.x * 256 + threadIdx.x;
    if (id >= K * 256) return;
    int n = id & 255, k = id >> 8;
    float v = W[id];
    unsigned short h = f2bf(v);
    size_t dst = ((size_t)(k >> 5) * 256 + n) * 32 + (k & 31);
    hi[dst] = h;
    if (lo) lo[dst] = f2bf(v - bf2f(h));
}

// ---- z (f32) -> zb (bf16), 8 elems/thread ----
__global__ __launch_bounds__(256)
void convert_z(const float* __restrict__ z, unsigned short* __restrict__ zb)
{
    int idx = blockIdx.x * 256 + threadIdx.x;
    if (idx >= N_NODES * DHID / 8) return;
    float4 v0 = ((const float4*)z)[idx * 2];
    float4 v1 = ((const float4*)z)[idx * 2 + 1];
    ushort8 o;
    o[0] = f2bf(v0.x); o[1] = f2bf(v0.y); o[2] = f2bf(v0.z); o[3] = f2bf(v0.w);
    o[4] = f2bf(v1.x); o[5] = f2bf(v1.y); o[6] = f2bf(v1.z); o[7] = f2bf(v1.w);
    ((ushort8*)zb)[idx] = o;
}

// ---------------- per-node attention logits (f32 z for exp precision) -------
__global__ __launch_bounds__(256)
void att_kernel(const float* __restrict__ z, const float* __restrict__ att_s,
                const float* __restrict__ att_d,
                float* __restrict__ a_src, float* __restrict__ a_dst)
{
    int idx = blockIdx.x * 256 + threadIdx.x;          // n*8 + h
    if (idx >= N_NODES * HEADS) return;
    int h = idx & 7, n = idx >> 3;
    const float4* zr = (const float4*)(z + (size_t)n * DHID + h * 32);
    const float4* as = (const float4*)(att_s + h * 32);
    const float4* ad = (const float4*)(att_d + h * 32);
    float s1 = 0.f, s2 = 0.f;
    #pragma unroll
    for (int i = 0; i < 8; i++) {
        float4 v = zr[i], a = as[i], b = ad[i];
        s1 += v.x * a.x + v.y * a.y + v.z * a.z + v.w * a.w;
        s2 += v.x * b.x + v.y * b.y + v.z * b.z + v.w * b.w;
    }
    a_src[idx] = s1; a_dst[idx] = s2;
}

// ================= CSR build =================
__global__ __launch_bounds__(256)
void hist_kernel(const int* __restrict__ edst, int* __restrict__ counts)
{
    int idx = blockIdx.x * 256 + threadIdx.x;
    if (idx >= P_TYPES * E_EDGES) return;
    int p = idx / E_EDGES;
    atomicAdd(&counts[p * N_NODES + edst[idx]], 1);
}

__global__ __launch_bounds__(1024)
void scan_block(const int* __restrict__ counts, int* __restrict__ out,
                int* __restrict__ blockSum, int total)
{
    __shared__ int wsum[16];
    int tid = threadIdx.x, lane = tid & 63, w = tid >> 6;
    int i = blockIdx.x * 1024 + tid;
    int v = (i < total) ? counts[i] : 0;
    int incl = v;
    #pragma unroll
    for (int off = 1; off < 64; off <<= 1) {
        int t = __shfl_up(incl, off, 64);
        if (lane >= off) incl += t;
    }
    if (lane == 63) wsum[w] = incl;
    __syncthreads();
    if (w == 0) {
        int s = (lane < 16) ? wsum[lane] : 0;
        #pragma unroll
        for (int off = 1; off < 16; off <<= 1) {
            int t = __shfl_up(s, off, 64);
            if (lane >= off) s += t;
        }
        if (lane < 16) wsum[lane] = s;
    }
    __syncthreads();
    int waveoff = w ? wsum[w - 1] : 0;
    if (i < total) out[i] = waveoff + incl - v;
    if (tid == 1023 && blockSum) blockSum[blockIdx.x] = wsum[15];
}

__global__ __launch_bounds__(1024)
void scan_add(int* __restrict__ row_start, int* __restrict__ cursor,
              const int* __restrict__ blockOff, int total)
{
    int i = blockIdx.x * 1024 + threadIdx.x;
    if (i == 0) row_start[total] = P_TYPES * E_EDGES;
    if (i < total) {
        int v = row_start[i] + blockOff[blockIdx.x];
        row_start[i] = v;
        cursor[i] = v;
    }
}

__global__ __launch_bounds__(256)
void fill_kernel(const int* __restrict__ esrc, const int* __restrict__ edst,
                 int* __restrict__ cursor, int* __restrict__ csr_src)
{
    int idx = blockIdx.x * 256 + threadIdx.x;
    if (idx >= P_TYPES * E_EDGES) return;
    int p = idx / E_EDGES;
    int pos = atomicAdd(&cursor[p * N_NODES + edst[idx]], 1);
    csr_src[pos] = esrc[idx];
}

// ---------------- CSR gather: 1 wave/segment, all heads, bf16 z rows --------
__global__ __launch_bounds__(256)
void gather_kernel(const int* __restrict__ row_start, const int* __restrict__ csr_src,
                   const float* __restrict__ a_src, const float* __restrict__ a_dst,
                   const unsigned short* __restrict__ zb, float* __restrict__ outs)
{
    int seg = blockIdx.x * 4 + (threadIdx.x >> 6);      // p*N + dst (grid exact)
    int lane = threadIdx.x & 63;
    int sub = lane >> 5, cl = lane & 31;
    int h = cl >> 2;
    int dst = seg % N_NODES;
    float ad = a_dst[dst * HEADS + h];
    int start = row_start[seg], end = row_start[seg + 1];

    float acc[8] = {};
    float den = 0.f;
    for (int i = start + sub; i < end; i += 2) {
        int src = csr_src[i];
        float s = a_src[src * HEADS + h] + ad;
        float e = s > 0.f ? s : NEG_SLOPE * s;
        float wgt = __expf(e);
        ushort8 zv = *(const ushort8*)(zb + (size_t)src * DHID + cl * 8);
        #pragma unroll
        for (int j = 0; j < 8; j++) acc[j] += wgt * bf2f(zv[j]);
        den += wgt;
    }
    den += __shfl_xor(den, 32, 64);
    #pragma unroll
    for (int j = 0; j < 8; j++) acc[j] += __shfl_xor(acc[j], 32, 64);
    if (sub == 0) {
        float inv = den > 0.f ? 1.0f / den : 0.f;
        float* op = outs + (size_t)seg * DHID + cl * 8;
        *(float4*)op       = make_float4(acc[0]*inv, acc[1]*inv, acc[2]*inv, acc[3]*inv);
        *(float4*)(op + 4) = make_float4(acc[4]*inv, acc[5]*inv, acc[6]*inv, acc[7]*inv);
    }
}

// ---------------- semantic softmax over P=4 ----------------
__global__ void beta_kernel(const float* __restrict__ score, float* __restrict__ beta)
{
    if (threadIdx.x == 0 && blockIdx.x == 0) {
        float s[P_TYPES]; float m = -1e30f;
        for (int p = 0; p < P_TYPES; p++) { s[p] = score[p] * (1.0f / N_NODES); m = fmaxf(m, s[p]); }
        float d = 0.f;
        for (int p = 0; p < P_TYPES; p++) { s[p] = __expf(s[p] - m); d += s[p]; }
        for (int p = 0; p < P_TYPES; p++) beta[p] = s[p] / d;
    }
}

// ---------------- weighted sum over types (+relu, optional elu) -------------
template<bool ELU>
__global__ __launch_bounds__(256)
void wsum_kernel(const float* __restrict__ outs, const float* __restrict__ beta,
                 float* __restrict__ hout)
{
    int idx = blockIdx.x * 256 + threadIdx.x;
    if (idx >= N_NODES * DHID / 4) return;
    float b[4] = {beta[0], beta[1], beta[2], beta[3]};
    const size_t stride = (size_t)N_NODES * DHID / 4;
    const float4* o = (const float4*)outs;
    float r[4] = {0.f, 0.f, 0.f, 0.f};
    #pragma unroll
    for (int p = 0; p < 4; p++) {
        float4 v = o[idx + p * stride];
        r[0] += b[p] * fmaxf(v.x, 0.f);
        r[1] += b[p] * fmaxf(v.y, 0.f);
        r[2] += b[p] * fmaxf(v.z, 0.f);
        r[3] += b[p] * fmaxf(v.w, 0.f);
    }
    if (ELU) {
        #pragma unroll
        for (int i = 0; i < 4; i++) r[i] = r[i] > 0.f ? r[i] : expm1f(r[i]);
    }
    ((float4*)hout)[idx] = make_float4(r[0], r[1], r[2], r[3]);
}

// ---------------- final classifier [N,256]@[256,16]+bo ----------------
__global__ __launch_bounds__(256)
void final_kernel(const float* __restrict__ h, const float* __restrict__ Wo,
                  const float* __restrict__ bo, float* __restrict__ out)
{
    int idx = blockIdx.x * 256 + threadIdx.x;
    if (idx >= N_NODES * NCLASSES) return;
    int c = idx & 15, n = idx >> 4;
    const float* hr = h + (size_t)n * DHID;
    float acc = bo[c];
    #pragma unroll 8
    for (int k = 0; k < DHID; k++) acc = fmaf(hr[k], Wo[k * NCLASSES + c], acc);
    out[idx] = acc;
}

extern "C" void kernel_launch(void* const* d_in, const int* in_sizes, int n_in,
                              void* d_out, int out_size, void* d_ws, size_t ws_size,
                              hipStream_t stream)
{
    const float* x   = (const float*)d_in[0];
    const int*  esrc = (const int*)d_in[1];
    const int*  edst = (const int*)d_in[2];
    const float* Wp1 = (const float*)d_in[3];
    const float* bp1 = (const float*)d_in[4];
    const float* as1 = (const float*)d_in[5];
    const float* ad1 = (const float*)d_in[6];
    const float* Wk1 = (const float*)d_in[7];
    const float* bk1 = (const float*)d_in[8];
    const float* q1  = (const float*)d_in[9];
    const float* Wp2 = (const float*)d_in[10];
    const float* bp2 = (const float*)d_in[11];
    const float* as2 = (const float*)d_in[12];
    const float* ad2 = (const float*)d_in[13];
    const float* Wk2 = (const float*)d_in[14];
    const float* bk2 = (const float*)d_in[15];
    const float* q2  = (const float*)d_in[16];
    const float* Wo  = (const float*)d_in[17];
    const float* bo  = (const float*)d_in[18];
    float* out = (float*)d_out;

    // workspace layout (f32 slots), ~141 MB total
    float* z     = (float*)d_ws;                 //  5,120,000
    float* hbuf  = z     + 5120000;              //  5,120,000
    float* a_s   = hbuf  + 5120000;              //    160,000
    float* a_d   = a_s   + 160000;               //    160,000
    float* outs  = a_d   + 160000;               // 20,480,000
    float* score = outs  + 20480000;             //          8
    float* beta  = score + 8;                    //          8
    unsigned short* zb = (unsigned short*)(beta + 8);              // 5,120,000 bf16
    unsigned short* Wp1t_hi = (unsigned short*)(beta + 8 + 2560000);
    unsigned short* Wp1t_lo = Wp1t_hi + 131072;
    unsigned short* Wp2t_hi = Wp1t_lo + 131072;
    unsigned short* Wp2t_lo = Wp2t_hi + 65536;
    unsigned short* Wk1t_hi = Wp2t_lo + 65536;
    unsigned short* Wk2t_hi = Wk1t_hi + 65536;
    int* row_start = (int*)(Wk2t_hi + 65536);    //     80,004
    int* cursor    = row_start + 80004;          //     80,000
    int* blockSum  = cursor + 80000;             //        128
    int* blockOff  = blockSum + 128;             //        128
    int* csr_src   = blockOff + 128;             //  1,280,000

    const int PN = P_TYPES * N_NODES;            // 80,000
    const int PE = P_TYPES * E_EDGES;            // 1,280,000
    const int NBS = (PN + 1023) / 1024;          // 79

    // ---- weight conversions (once, k-tiled layout) ----
    convert_w<<<(512 * 256 + 255) / 256, 256, 0, stream>>>(Wp1, Wp1t_hi, Wp1t_lo, 512);
    convert_w<<<(256 * 256 + 255) / 256, 256, 0, stream>>>(Wp2, Wp2t_hi, Wp2t_lo, 256);
    convert_w<<<(256 * 256 + 255) / 256, 256, 0, stream>>>(Wk1, Wk1t_hi, nullptr, 256);
    convert_w<<<(256 * 256 + 255) / 256, 256, 0, stream>>>(Wk2, Wk2t_hi, nullptr, 256);

    // ---- CSR build (edge structure shared by both layers) ----
    hipMemsetAsync(cursor, 0, PN * sizeof(int), stream);
    hist_kernel<<<(PE + 255) / 256, 256, 0, stream>>>(edst, cursor);
    scan_block<<<NBS, 1024, 0, stream>>>(cursor, row_start, blockSum, PN);
    scan_block<<<1, 1024, 0, stream>>>(blockSum, blockOff, nullptr, NBS);
    scan_add<<<NBS, 1024, 0, stream>>>(row_start, cursor, blockOff, PN);
    fill_kernel<<<(PE + 255) / 256, 256, 0, stream>>>(esrc, edst, cursor, csr_src);

    auto run_layer = [&](const float* xin, int K, const unsigned short* Wpt_hi,
                         const unsigned short* Wpt_lo, const float* bp,
                         const float* atts, const float* attd,
                         const unsigned short* Wkt_hi, const float* bk,
                         const float* q, float* hout, bool elu) {
        hipMemsetAsync(score, 0, 8 * sizeof(float), stream);

        mfma_gemm<true, false, 0><<<(N_NODES + 63) / 64, 256, 0, stream>>>(
            xin, Wpt_hi, Wpt_lo, bp, z, nullptr, nullptr, N_NODES, K);

        convert_z<<<(N_NODES * DHID / 8 + 255) / 256, 256, 0, stream>>>(z, zb);
        att_kernel<<<(N_NODES * HEADS + 255) / 256, 256, 0, stream>>>(z, atts, attd, a_s, a_d);
        gather_kernel<<<PN / 4, 256, 0, stream>>>(row_start, csr_src, a_s, a_d, zb, outs);

        mfma_gemm<false, true, 1><<<(PN + 63) / 64, 256, 0, stream>>>(
            outs, Wkt_hi, nullptr, bk, nullptr, q, score, PN, 256);

        beta_kernel<<<1, 64, 0, stream>>>(score, beta);
        if (elu)
            wsum_kernel<true><<<(N_NODES * 64 + 255) / 256, 256, 0, stream>>>(outs, beta, hout);
        else
            wsum_kernel<false><<<(N_NODES * 64 + 255) / 256, 256, 0, stream>>>(outs, beta, hout);
    };

    run_layer(x,    512, Wp1t_hi, Wp1t_lo, bp1, as1, ad1, Wk1t_hi, bk1, q1, hbuf, true);
    run_layer(hbuf, 256, Wp2t_hi, Wp2t_lo, bp2, as2, ad2, Wk2t_hi, bk2, q2, hbuf, false);

    final_kernel<<<(N_NODES * NCLASSES + 255) / 256, 256, 0, stream>>>(hbuf, Wo, bo, out);
}

// Round 6
// 575.538 us; speedup vs baseline: 15.8559x; 1.0658x over previous
//
#include <hip/hip_runtime.h>
#include <hip/hip_bf16.h>
#include <cstdint>

#define N_NODES 20000
#define E_EDGES 320000
#define P_TYPES 4
#define HEADS   8
#define DHID    256
#define NCLASSES 16
#define NEG_SLOPE 0.2f

typedef __attribute__((ext_vector_type(8))) short bf16x8;
typedef __attribute__((ext_vector_type(8))) unsigned short ushort8;
typedef __attribute__((ext_vector_type(4))) float f32x4;

static __device__ __forceinline__ unsigned short f2bf(float v) {
    __hip_bfloat16 h = __float2bfloat16(v);
    return *(unsigned short*)&h;
}
static __device__ __forceinline__ float bf2f(unsigned short u) {
    __hip_bfloat16 h = *(__hip_bfloat16*)&u;
    return __bfloat162float(h);
}
static __device__ __forceinline__ float fast_tanh(float x) {
    x = fminf(fmaxf(x, -10.f), 10.f);
    float t = __expf(2.f * x);
    return (t - 1.f) / (t + 1.f);
}

// ========== proj GEMM: z = A[MxK] @ Wp[Kx256] + bp, fused epilogue ==========
// hi+lo bf16 split (3 MFMAs, fp32-grade). B k-tiled [K/32][256][32] hi/lo.
// Epilogue: write zb (bf16) only (no f32 z), and compute per-node attention
// logits a_src/a_dst = sum_head_cols(z * att) via 16-lane shfl reduction.
// Wave w owns cols [w*64,w*64+64) = heads 2w,2w+1 -> reduction is wave-local.
// BM=64, BN=256, BK=32; 4 waves. LDS rows 5 int4 (80B) -> conflict-free b128.
__global__ __launch_bounds__(256)
void proj_gemm(const float* __restrict__ A, const unsigned short* __restrict__ BgH,
               const unsigned short* __restrict__ BgL, const float* __restrict__ bias,
               const float* __restrict__ att_s, const float* __restrict__ att_d,
               unsigned short* __restrict__ zb, float* __restrict__ a_s,
               float* __restrict__ a_d, int M, int K)
{
    __shared__ int4 AS[2 * 64 * 5];
    __shared__ int4 BS[2 * 256 * 5];
    const int row0 = blockIdx.x * 64;
    const int tid = threadIdx.x, lane = tid & 63, w = tid >> 6;

    f32x4 acc[4][4];
    const f32x4 zero4 = {0.f, 0.f, 0.f, 0.f};
    #pragma unroll
    for (int i = 0; i < 4; i++)
        #pragma unroll
        for (int j = 0; j < 4; j++) acc[i][j] = zero4;

    for (int k0 = 0; k0 < K; k0 += 32) {
        {   // stage A: 64 rows x 32 k (f32 -> bf16 hi+lo)
            #pragma unroll
            for (int it = 0; it < 2; it++) {
                int id = tid + it * 256;
                int r = id >> 3, f = id & 7;
                int row_g = row0 + r;
                float4 v = make_float4(0.f, 0.f, 0.f, 0.f);
                if (row_g < M) v = *(const float4*)&A[(size_t)row_g * K + k0 + f * 4];
                ushort4 hi;
                hi.x = f2bf(v.x); hi.y = f2bf(v.y); hi.z = f2bf(v.z); hi.w = f2bf(v.w);
                int c = f >> 1, half = f & 1;
                ((ushort4*)AS)[(r * 5 + c) * 2 + half] = hi;
                ushort4 lo;
                lo.x = f2bf(v.x - bf2f(hi.x)); lo.y = f2bf(v.y - bf2f(hi.y));
                lo.z = f2bf(v.z - bf2f(hi.z)); lo.w = f2bf(v.w - bf2f(hi.w));
                ((ushort4*)(AS + 64 * 5))[(r * 5 + c) * 2 + half] = lo;
            }
        }
        {   // stage B: k-tile [256][32] hi+lo, lane-consecutive (coalesced)
            size_t bbase = (size_t)(k0 >> 5) * (256 * 32);
            #pragma unroll
            for (int it = 0; it < 4; it++) {
                int id = tid + it * 256;
                BS[(id >> 2) * 5 + (id & 3)] = *(const int4*)&BgH[bbase + (size_t)id * 8];
                BS[256 * 5 + (id >> 2) * 5 + (id & 3)] = *(const int4*)&BgL[bbase + (size_t)id * 8];
            }
        }
        __syncthreads();

        const bf16x8* ASv = (const bf16x8*)AS;
        const bf16x8* BSv = (const bf16x8*)BS;
        const int slot = lane >> 4;
        bf16x8 ah[4], al[4];
        #pragma unroll
        for (int mt = 0; mt < 4; mt++) {
            int r = mt * 16 + (lane & 15);
            ah[mt] = ASv[r * 5 + slot];
            al[mt] = ASv[64 * 5 + r * 5 + slot];
        }
        #pragma unroll
        for (int nt = 0; nt < 4; nt++) {
            int rb = (w * 4 + nt) * 16 + (lane & 15);
            bf16x8 bh = BSv[rb * 5 + slot];
            bf16x8 bl = BSv[256 * 5 + rb * 5 + slot];
            #pragma unroll
            for (int mt = 0; mt < 4; mt++) {
                acc[mt][nt] = __builtin_amdgcn_mfma_f32_16x16x32_bf16(ah[mt], bh, acc[mt][nt], 0, 0, 0);
                acc[mt][nt] = __builtin_amdgcn_mfma_f32_16x16x32_bf16(ah[mt], bl, acc[mt][nt], 0, 0, 0);
                acc[mt][nt] = __builtin_amdgcn_mfma_f32_16x16x32_bf16(al[mt], bh, acc[mt][nt], 0, 0, 0);
            }
        }
        __syncthreads();
    }

    // Epilogue. C/D layout: col=lane&15 (within 16-tile), row=(lane>>4)*4+reg.
    const int c15 = lane & 15, lhi = lane >> 4;
    float asw[4], adw[4], bw[4];
    #pragma unroll
    for (int nt = 0; nt < 4; nt++) {
        int col = (w * 4 + nt) * 16 + c15;          // flat col == att flat index
        asw[nt] = att_s[col]; adw[nt] = att_d[col]; bw[nt] = bias[col];
    }
    #pragma unroll
    for (int mt = 0; mt < 4; mt++) {
        #pragma unroll
        for (int rg = 0; rg < 4; rg++) {
            int row = row0 + mt * 16 + lhi * 4 + rg;
            bool ok = row < M;
            float v0 = acc[mt][0][rg] + bw[0], v1 = acc[mt][1][rg] + bw[1];
            float v2 = acc[mt][2][rg] + bw[2], v3 = acc[mt][3][rg] + bw[3];
            if (ok) {
                unsigned short* zp = zb + (size_t)row * DHID + w * 64 + c15;
                zp[0]  = f2bf(v0); zp[16] = f2bf(v1);
                zp[32] = f2bf(v2); zp[48] = f2bf(v3);
            }
            float h0s = v0 * asw[0] + v1 * asw[1], h0d = v0 * adw[0] + v1 * adw[1];
            float h1s = v2 * asw[2] + v3 * asw[3], h1d = v2 * adw[2] + v3 * adw[3];
            #pragma unroll
            for (int off = 1; off < 16; off <<= 1) {
                h0s += __shfl_xor(h0s, off, 64); h0d += __shfl_xor(h0d, off, 64);
                h1s += __shfl_xor(h1s, off, 64); h1d += __shfl_xor(h1d, off, 64);
            }
            if (ok && c15 == 0) {
                a_s[row * HEADS + 2 * w]     = h0s;  a_d[row * HEADS + 2 * w]     = h0d;
                a_s[row * HEADS + 2 * w + 1] = h1s;  a_d[row * HEADS + 2 * w + 1] = h1d;
            }
        }
    }
}

// ========== score GEMM: bf16 A (relu'd), K=256, MODE1 epilogue =============
__global__ __launch_bounds__(256)
void score_gemm(const unsigned short* __restrict__ Ab, const unsigned short* __restrict__ BgH,
                const float* __restrict__ bias, const float* __restrict__ q,
                float* __restrict__ score, int M)
{
    __shared__ int4 AS[64 * 5];
    __shared__ int4 BS[256 * 5];
    __shared__ float red[4][2];
    const int row0 = blockIdx.x * 64;
    const int tid = threadIdx.x, lane = tid & 63, w = tid >> 6;

    f32x4 acc[4][4];
    const f32x4 zero4 = {0.f, 0.f, 0.f, 0.f};
    #pragma unroll
    for (int i = 0; i < 4; i++)
        #pragma unroll
        for (int j = 0; j < 4; j++) acc[i][j] = zero4;

    for (int k0 = 0; k0 < 256; k0 += 32) {
        {   // stage A: 64 rows x 32 k, bf16 direct + relu bit-trick
            int r = tid >> 2, f = tid & 3;
            int row_g = row0 + r;
            union { int4 v; unsigned short u[8]; } t;
            t.v = make_int4(0, 0, 0, 0);
            if (row_g < M) t.v = *(const int4*)&Ab[(size_t)row_g * DHID + k0 + f * 8];
            #pragma unroll
            for (int j = 0; j < 8; j++) if (t.u[j] & 0x8000) t.u[j] = 0;
            AS[r * 5 + f] = t.v;
        }
        {   // stage B: k-tile [256][32] hi
            size_t bbase = (size_t)(k0 >> 5) * (256 * 32);
            #pragma unroll
            for (int it = 0; it < 4; it++) {
                int id = tid + it * 256;
                BS[(id >> 2) * 5 + (id & 3)] = *(const int4*)&BgH[bbase + (size_t)id * 8];
            }
        }
        __syncthreads();

        const bf16x8* ASv = (const bf16x8*)AS;
        const bf16x8* BSv = (const bf16x8*)BS;
        const int slot = lane >> 4;
        bf16x8 ah[4];
        #pragma unroll
        for (int mt = 0; mt < 4; mt++) ah[mt] = ASv[(mt * 16 + (lane & 15)) * 5 + slot];
        #pragma unroll
        for (int nt = 0; nt < 4; nt++) {
            bf16x8 bh = BSv[((w * 4 + nt) * 16 + (lane & 15)) * 5 + slot];
            #pragma unroll
            for (int mt = 0; mt < 4; mt++)
                acc[mt][nt] = __builtin_amdgcn_mfma_f32_16x16x32_bf16(ah[mt], bh, acc[mt][nt], 0, 0, 0);
        }
        __syncthreads();
    }

    const int pbase = row0 / N_NODES;
    const int rowSplit = (pbase + 1) * N_NODES;
    float l0 = 0.f, l1 = 0.f;
    #pragma unroll
    for (int nt = 0; nt < 4; nt++) {
        int col = (w * 4 + nt) * 16 + (lane & 15);
        float qc = q[col], bc = bias[col];
        #pragma unroll
        for (int mt = 0; mt < 4; mt++)
            #pragma unroll
            for (int rg = 0; rg < 4; rg++) {
                int row = row0 + mt * 16 + (lane >> 4) * 4 + rg;
                if (row < M) {
                    float v = qc * fast_tanh(acc[mt][nt][rg] + bc);
                    if (row >= rowSplit) l1 += v; else l0 += v;
                }
            }
    }
    #pragma unroll
    for (int off = 32; off > 0; off >>= 1) {
        l0 += __shfl_down(l0, off, 64);
        l1 += __shfl_down(l1, off, 64);
    }
    if (lane == 0) { red[w][0] = l0; red[w][1] = l1; }
    __syncthreads();
    if (tid == 0)
        atomicAdd(score + pbase, red[0][0] + red[1][0] + red[2][0] + red[3][0]);
    if (tid == 1 && pbase + 1 < P_TYPES)
        atomicAdd(score + pbase + 1, red[0][1] + red[1][1] + red[2][1] + red[3][1]);
}

// ---- weight convert: W[K][256] f32 -> k-tiled bf16 [K/32][256][32] hi[/lo] ----
__global__ __launch_bounds__(256)
void convert_w(const float* __restrict__ W, unsigned short* __restrict__ hi,
               unsigned short* __restrict__ lo, int K)
{
    int id = blockIdx.x * 256 + threadIdx.x;
    if (id >= K * 256) return;
    int n = id & 255, k = id >> 8;
    float v = W[id];
    unsigned short h = f2bf(v);
    size_t dst = ((size_t)(k >> 5) * 256 + n) * 32 + (k & 31);
    hi[dst] = h;
    if (lo) lo[dst] = f2bf(v - bf2f(h));
}

// ================= CSR build =================
__global__ __launch_bounds__(256)
void hist_kernel(const int* __restrict__ edst, int* __restrict__ counts)
{
    int idx = blockIdx.x * 256 + threadIdx.x;
    if (idx >= P_TYPES * E_EDGES) return;
    int p = idx / E_EDGES;
    atomicAdd(&counts[p * N_NODES + edst[idx]], 1);
}

__global__ __launch_bounds__(1024)
void scan_block(const int* __restrict__ counts, int* __restrict__ out,
                int* __restrict__ blockSum, int total)
{
    __shared__ int wsum[16];
    int tid = threadIdx.x, lane = tid & 63, w = tid >> 6;
    int i = blockIdx.x * 1024 + tid;
    int v = (i < total) ? counts[i] : 0;
    int incl = v;
    #pragma unroll
    for (int off = 1; off < 64; off <<= 1) {
        int t = __shfl_up(incl, off, 64);
        if (lane >= off) incl += t;
    }
    if (lane == 63) wsum[w] = incl;
    __syncthreads();
    if (w == 0) {
        int s = (lane < 16) ? wsum[lane] : 0;
        #pragma unroll
        for (int off = 1; off < 16; off <<= 1) {
            int t = __shfl_up(s, off, 64);
            if (lane >= off) s += t;
        }
        if (lane < 16) wsum[lane] = s;
    }
    __syncthreads();
    int waveoff = w ? wsum[w - 1] : 0;
    if (i < total) out[i] = waveoff + incl - v;
    if (tid == 1023 && blockSum) blockSum[blockIdx.x] = wsum[15];
}

__global__ __launch_bounds__(1024)
void scan_add(int* __restrict__ row_start, int* __restrict__ cursor,
              const int* __restrict__ blockOff, int total)
{
    int i = blockIdx.x * 1024 + threadIdx.x;
    if (i == 0) row_start[total] = P_TYPES * E_EDGES;
    if (i < total) {
        int v = row_start[i] + blockOff[blockIdx.x];
        row_start[i] = v;
        cursor[i] = v;
    }
}

__global__ __launch_bounds__(256)
void fill_kernel(const int* __restrict__ esrc, const int* __restrict__ edst,
                 int* __restrict__ cursor, int* __restrict__ csr_src)
{
    int idx = blockIdx.x * 256 + threadIdx.x;
    if (idx >= P_TYPES * E_EDGES) return;
    int p = idx / E_EDGES;
    int pos = atomicAdd(&cursor[p * N_NODES + edst[idx]], 1);
    csr_src[pos] = esrc[idx];
}

// ---------------- CSR gather: 1 wave/segment, bf16 in, bf16 out -------------
__global__ __launch_bounds__(256)
void gather_kernel(const int* __restrict__ row_start, const int* __restrict__ csr_src,
                   const float* __restrict__ a_src, const float* __restrict__ a_dst,
                   const unsigned short* __restrict__ zb, unsigned short* __restrict__ outsb)
{
    int seg = blockIdx.x * 4 + (threadIdx.x >> 6);      // p*N + dst (grid exact)
    int lane = threadIdx.x & 63;
    int sub = lane >> 5, cl = lane & 31;
    int h = cl >> 2;
    int dst = seg % N_NODES;
    float ad = a_dst[dst * HEADS + h];
    int start = row_start[seg], end = row_start[seg + 1];

    float acc[8] = {};
    float den = 0.f;
    for (int i = start + sub; i < end; i += 2) {
        int src = csr_src[i];
        float s = a_src[src * HEADS + h] + ad;
        float e = s > 0.f ? s : NEG_SLOPE * s;
        float wgt = __expf(e);
        ushort8 zv = *(const ushort8*)(zb + (size_t)src * DHID + cl * 8);
        #pragma unroll
        for (int j = 0; j < 8; j++) acc[j] += wgt * bf2f(zv[j]);
        den += wgt;
    }
    den += __shfl_xor(den, 32, 64);
    #pragma unroll
    for (int j = 0; j < 8; j++) acc[j] += __shfl_xor(acc[j], 32, 64);
    if (sub == 0) {
        float inv = den > 0.f ? 1.0f / den : 0.f;
        ushort8 o;
        #pragma unroll
        for (int j = 0; j < 8; j++) o[j] = f2bf(acc[j] * inv);
        *(ushort8*)(outsb + (size_t)seg * DHID + cl * 8) = o;
    }
}

// ---------------- semantic softmax over P=4 ----------------
__global__ void beta_kernel(const float* __restrict__ score, float* __restrict__ beta)
{
    if (threadIdx.x == 0 && blockIdx.x == 0) {
        float s[P_TYPES]; float m = -1e30f;
        for (int p = 0; p < P_TYPES; p++) { s[p] = score[p] * (1.0f / N_NODES); m = fmaxf(m, s[p]); }
        float d = 0.f;
        for (int p = 0; p < P_TYPES; p++) { s[p] = __expf(s[p] - m); d += s[p]; }
        for (int p = 0; p < P_TYPES; p++) beta[p] = s[p] / d;
    }
}

// ---------------- weighted sum over types (+relu, optional elu) -------------
template<bool ELU>
__global__ __launch_bounds__(256)
void wsum_kernel(const unsigned short* __restrict__ outsb, const float* __restrict__ beta,
                 float* __restrict__ hout)
{
    int idx = blockIdx.x * 256 + threadIdx.x;          // ushort8 index into [N,256]
    if (idx >= N_NODES * DHID / 8) return;
    float b[4] = {beta[0], beta[1], beta[2], beta[3]};
    const size_t stride = (size_t)N_NODES * DHID / 8;
    const ushort8* o = (const ushort8*)outsb;
    float r[8] = {};
    #pragma unroll
    for (int p = 0; p < 4; p++) {
        ushort8 v = o[idx + p * stride];
        #pragma unroll
        for (int j = 0; j < 8; j++) r[j] += b[p] * fmaxf(bf2f(v[j]), 0.f);
    }
    if (ELU) {
        #pragma unroll
        for (int j = 0; j < 8; j++) r[j] = r[j] > 0.f ? r[j] : expm1f(r[j]);
    }
    float4* hp = (float4*)(hout + (size_t)idx * 8);
    hp[0] = make_float4(r[0], r[1], r[2], r[3]);
    hp[1] = make_float4(r[4], r[5], r[6], r[7]);
}

// ---------------- final classifier [N,256]@[256,16]+bo ----------------
__global__ __launch_bounds__(256)
void final_kernel(const float* __restrict__ h, const float* __restrict__ Wo,
                  const float* __restrict__ bo, float* __restrict__ out)
{
    int idx = blockIdx.x * 256 + threadIdx.x;
    if (idx >= N_NODES * NCLASSES) return;
    int c = idx & 15, n = idx >> 4;
    const float* hr = h + (size_t)n * DHID;
    float acc = bo[c];
    #pragma unroll 8
    for (int k = 0; k < DHID; k++) acc = fmaf(hr[k], Wo[k * NCLASSES + c], acc);
    out[idx] = acc;
}

extern "C" void kernel_launch(void* const* d_in, const int* in_sizes, int n_in,
                              void* d_out, int out_size, void* d_ws, size_t ws_size,
                              hipStream_t stream)
{
    const float* x   = (const float*)d_in[0];
    const int*  esrc = (const int*)d_in[1];
    const int*  edst = (const int*)d_in[2];
    const float* Wp1 = (const float*)d_in[3];
    const float* bp1 = (const float*)d_in[4];
    const float* as1 = (const float*)d_in[5];
    const float* ad1 = (const float*)d_in[6];
    const float* Wk1 = (const float*)d_in[7];
    const float* bk1 = (const float*)d_in[8];
    const float* q1  = (const float*)d_in[9];
    const float* Wp2 = (const float*)d_in[10];
    const float* bp2 = (const float*)d_in[11];
    const float* as2 = (const float*)d_in[12];
    const float* ad2 = (const float*)d_in[13];
    const float* Wk2 = (const float*)d_in[14];
    const float* bk2 = (const float*)d_in[15];
    const float* q2  = (const float*)d_in[16];
    const float* Wo  = (const float*)d_in[17];
    const float* bo  = (const float*)d_in[18];
    float* out = (float*)d_out;

    // workspace layout (byte offsets, ~80 MB total, all 16B-aligned)
    char* wsb = (char*)d_ws;
    float* hbuf  = (float*)wsb;                                   // 20,480,000 B
    float* a_s   = (float*)(wsb + 20480000);                      //    640,000 B
    float* a_d   = (float*)(wsb + 21120000);                      //    640,000 B
    float* score = (float*)(wsb + 21760000);                      //         32 B
    float* beta  = (float*)(wsb + 21760032);                      //         32 B
    unsigned short* zb      = (unsigned short*)(wsb + 21760064);  // 10,240,000 B
    unsigned short* outsb   = (unsigned short*)(wsb + 32000064);  // 40,960,000 B
    unsigned short* Wp1t_hi = (unsigned short*)(wsb + 72960064);  //    262,144 B
    unsigned short* Wp1t_lo = (unsigned short*)(wsb + 73222208);
    unsigned short* Wp2t_hi = (unsigned short*)(wsb + 73484352);  //    131,072 B
    unsigned short* Wp2t_lo = (unsigned short*)(wsb + 73615424);
    unsigned short* Wk1t_hi = (unsigned short*)(wsb + 73746496);
    unsigned short* Wk2t_hi = (unsigned short*)(wsb + 73877568);
    int* row_start = (int*)(wsb + 74008640);                      //    320,016 B
    int* cursor    = (int*)(wsb + 74328656);                      //    320,000 B
    int* blockSum  = (int*)(wsb + 74648656);                      //        512 B
    int* blockOff  = (int*)(wsb + 74649168);                      //        512 B
    int* csr_src   = (int*)(wsb + 74649680);                      //  5,120,000 B

    const int PN = P_TYPES * N_NODES;            // 80,000
    const int PE = P_TYPES * E_EDGES;            // 1,280,000
    const int NBS = (PN + 1023) / 1024;          // 79

    // ---- weight conversions (once, k-tiled layout) ----
    convert_w<<<(512 * 256 + 255) / 256, 256, 0, stream>>>(Wp1, Wp1t_hi, Wp1t_lo, 512);
    convert_w<<<(256 * 256 + 255) / 256, 256, 0, stream>>>(Wp2, Wp2t_hi, Wp2t_lo, 256);
    convert_w<<<(256 * 256 + 255) / 256, 256, 0, stream>>>(Wk1, Wk1t_hi, nullptr, 256);
    convert_w<<<(256 * 256 + 255) / 256, 256, 0, stream>>>(Wk2, Wk2t_hi, nullptr, 256);

    // ---- CSR build (edge structure shared by both layers) ----
    hipMemsetAsync(cursor, 0, PN * sizeof(int), stream);
    hist_kernel<<<(PE + 255) / 256, 256, 0, stream>>>(edst, cursor);
    scan_block<<<NBS, 1024, 0, stream>>>(cursor, row_start, blockSum, PN);
    scan_block<<<1, 1024, 0, stream>>>(blockSum, blockOff, nullptr, NBS);
    scan_add<<<NBS, 1024, 0, stream>>>(row_start, cursor, blockOff, PN);
    fill_kernel<<<(PE + 255) / 256, 256, 0, stream>>>(esrc, edst, cursor, csr_src);

    auto run_layer = [&](const float* xin, int K, const unsigned short* Wpt_hi,
                         const unsigned short* Wpt_lo, const float* bp,
                         const float* atts, const float* attd,
                         const unsigned short* Wkt_hi, const float* bk,
                         const float* q, float* hout, bool elu) {
        hipMemsetAsync(score, 0, 8 * sizeof(float), stream);

        proj_gemm<<<(N_NODES + 63) / 64, 256, 0, stream>>>(
            xin, Wpt_hi, Wpt_lo, bp, atts, attd, zb, a_s, a_d, N_NODES, K);

        gather_kernel<<<PN / 4, 256, 0, stream>>>(row_start, csr_src, a_s, a_d, zb, outsb);

        score_gemm<<<(PN + 63) / 64, 256, 0, stream>>>(outsb, Wkt_hi, bk, q, score, PN);

        beta_kernel<<<1, 64, 0, stream>>>(score, beta);
        if (elu)
            wsum_kernel<true><<<(N_NODES * DHID / 8 + 255) / 256, 256, 0, stream>>>(outsb, beta, hout);
        else
            wsum_kernel<false><<<(N_NODES * DHID / 8 + 255) / 256, 256, 0, stream>>>(outsb, beta, hout);
    };

    run_layer(x,    512, Wp1t_hi, Wp1t_lo, bp1, as1, ad1, Wk1t_hi, bk1, q1, hbuf, true);
    run_layer(hbuf, 256, Wp2t_hi, Wp2t_lo, bp2, as2, ad2, Wk2t_hi, bk2, q2, hbuf, false);

    final_kernel<<<(N_NODES * NCLASSES + 255) / 256, 256, 0, stream>>>(hbuf, Wo, bo, out);
}

// Round 7
// 553.506 us; speedup vs baseline: 16.4871x; 1.0398x over previous
//
#include <hip/hip_runtime.h>
#include <hip/hip_bf16.h>
#include <cstdint>

#define N_NODES 20000
#define E_EDGES 320000
#define P_TYPES 4
#define HEADS   8
#define DHID    256
#define NCLASSES 16
#define NEG_SLOPE 0.2f

typedef __attribute__((ext_vector_type(8))) short bf16x8;
typedef __attribute__((ext_vector_type(8))) unsigned short ushort8;
typedef __attribute__((ext_vector_type(4))) float f32x4;

static __device__ __forceinline__ unsigned short f2bf(float v) {
    __hip_bfloat16 h = __float2bfloat16(v);
    return *(unsigned short*)&h;
}
static __device__ __forceinline__ float bf2f(unsigned short u) {
    __hip_bfloat16 h = *(__hip_bfloat16*)&u;
    return __bfloat162float(h);
}
static __device__ __forceinline__ float fast_tanh(float x) {
    x = fminf(fmaxf(x, -10.f), 10.f);
    float t = __expf(2.f * x);
    return (t - 1.f) / (t + 1.f);
}

// ========== proj GEMM: zb = A[Mx K](hi+lo bf16) @ Wp + bp, fused epilogue ====
// A pre-split row-major bf16 hi/lo. B k-tiled [K/32][256][32] hi/lo.
// BM=64, BN=128 (blockIdx.y in {0,1}), 4 waves; wave w = 64 rows x 32 cols
// = head (by*4 + w). 3 MFMAs (hi*hi + hi*lo + lo*hi) = fp32-grade.
// Epilogue: write zb bf16; a_src/a_dst via 16-lane shfl reduce (one head/wave).
// LDS rows 5 int4 (80B) -> conflict-free ds_read_b128.
__global__ __launch_bounds__(256)
void proj_gemm(const unsigned short* __restrict__ Ah, const unsigned short* __restrict__ Al,
               const unsigned short* __restrict__ BgH, const unsigned short* __restrict__ BgL,
               const float* __restrict__ bias, const float* __restrict__ att_s,
               const float* __restrict__ att_d, unsigned short* __restrict__ zb,
               float* __restrict__ a_s, float* __restrict__ a_d, int M, int K)
{
    __shared__ int4 AS[2 * 64 * 5];
    __shared__ int4 BS[2 * 128 * 5];
    const int row0 = blockIdx.x * 64;
    const int by = blockIdx.y;
    const int tid = threadIdx.x, lane = tid & 63, w = tid >> 6;

    f32x4 acc[4][2];
    const f32x4 zero4 = {0.f, 0.f, 0.f, 0.f};
    #pragma unroll
    for (int i = 0; i < 4; i++) { acc[i][0] = zero4; acc[i][1] = zero4; }

    for (int k0 = 0; k0 < K; k0 += 32) {
        {   // stage A: 64 rows x 32 k hi+lo (pure copies)
            int r = tid >> 2, f = tid & 3;
            int rg_ = row0 + r;
            int4 vh = make_int4(0, 0, 0, 0), vl = make_int4(0, 0, 0, 0);
            if (rg_ < M) {
                size_t a = (size_t)rg_ * K + k0 + f * 8;
                vh = *(const int4*)&Ah[a];
                vl = *(const int4*)&Al[a];
            }
            AS[r * 5 + f] = vh;
            AS[64 * 5 + r * 5 + f] = vl;
        }
        {   // stage B: 128 n-rows x 32 k hi+lo from k-tiled layout (coalesced)
            size_t bbase = (size_t)(k0 >> 5) * (256 * 32) + (size_t)(by * 128) * 32;
            #pragma unroll
            for (int it = 0; it < 2; it++) {
                int id = tid + it * 256;
                int r = id >> 2, f = id & 3;
                size_t a = bbase + (size_t)r * 32 + f * 8;
                BS[r * 5 + f] = *(const int4*)&BgH[a];
                BS[128 * 5 + r * 5 + f] = *(const int4*)&BgL[a];
            }
        }
        __syncthreads();

        const bf16x8* ASv = (const bf16x8*)AS;
        const bf16x8* BSv = (const bf16x8*)BS;
        const int slot = lane >> 4;
        bf16x8 ah[4], al[4];
        #pragma unroll
        for (int mt = 0; mt < 4; mt++) {
            int r = mt * 16 + (lane & 15);
            ah[mt] = ASv[r * 5 + slot];
            al[mt] = ASv[64 * 5 + r * 5 + slot];
        }
        #pragma unroll
        for (int nt = 0; nt < 2; nt++) {
            int rb = (w * 2 + nt) * 16 + (lane & 15);
            bf16x8 bh = BSv[rb * 5 + slot];
            bf16x8 bl = BSv[128 * 5 + rb * 5 + slot];
            #pragma unroll
            for (int mt = 0; mt < 4; mt++) {
                acc[mt][nt] = __builtin_amdgcn_mfma_f32_16x16x32_bf16(ah[mt], bh, acc[mt][nt], 0, 0, 0);
                acc[mt][nt] = __builtin_amdgcn_mfma_f32_16x16x32_bf16(ah[mt], bl, acc[mt][nt], 0, 0, 0);
                acc[mt][nt] = __builtin_amdgcn_mfma_f32_16x16x32_bf16(al[mt], bh, acc[mt][nt], 0, 0, 0);
            }
        }
        __syncthreads();
    }

    // Epilogue. C/D: col=lane&15 within 16-tile, row=(lane>>4)*4+reg.
    const int c15 = lane & 15, lhi = lane >> 4;
    const int hd = by * 4 + w;                       // this wave's head
    float asw[2], adw[2], bw[2];
    #pragma unroll
    for (int nt = 0; nt < 2; nt++) {
        int col = by * 128 + w * 32 + nt * 16 + c15;
        asw[nt] = att_s[col]; adw[nt] = att_d[col]; bw[nt] = bias[col];
    }
    #pragma unroll
    for (int mt = 0; mt < 4; mt++) {
        #pragma unroll
        for (int rg = 0; rg < 4; rg++) {
            int row = row0 + mt * 16 + lhi * 4 + rg;
            bool ok = row < M;
            float v0 = acc[mt][0][rg] + bw[0], v1 = acc[mt][1][rg] + bw[1];
            if (ok) {
                unsigned short* zp = zb + (size_t)row * DHID + by * 128 + w * 32 + c15;
                zp[0] = f2bf(v0); zp[16] = f2bf(v1);
            }
            float hs = v0 * asw[0] + v1 * asw[1];
            float hdd = v0 * adw[0] + v1 * adw[1];
            #pragma unroll
            for (int off = 1; off < 16; off <<= 1) {
                hs += __shfl_xor(hs, off, 64); hdd += __shfl_xor(hdd, off, 64);
            }
            if (ok && c15 == 0) {
                a_s[row * HEADS + hd] = hs;
                a_d[row * HEADS + hd] = hdd;
            }
        }
    }
}

// ========== score GEMM: bf16 A (relu'd), K=256, score-reduce epilogue =======
__global__ __launch_bounds__(256)
void score_gemm(const unsigned short* __restrict__ Ab, const unsigned short* __restrict__ BgH,
                const float* __restrict__ bias, const float* __restrict__ q,
                float* __restrict__ score, int M)
{
    __shared__ int4 AS[64 * 5];
    __shared__ int4 BS[256 * 5];
    __shared__ float red[4][2];
    const int row0 = blockIdx.x * 64;
    const int tid = threadIdx.x, lane = tid & 63, w = tid >> 6;

    f32x4 acc[4][4];
    const f32x4 zero4 = {0.f, 0.f, 0.f, 0.f};
    #pragma unroll
    for (int i = 0; i < 4; i++)
        #pragma unroll
        for (int j = 0; j < 4; j++) acc[i][j] = zero4;

    for (int k0 = 0; k0 < 256; k0 += 32) {
        {   // stage A: bf16 copy + relu bit-trick
            int r = tid >> 2, f = tid & 3;
            union { int4 v; unsigned short u[8]; } t;
            t.v = *(const int4*)&Ab[(size_t)(row0 + r) * DHID + k0 + f * 8];
            #pragma unroll
            for (int j = 0; j < 8; j++) if (t.u[j] & 0x8000) t.u[j] = 0;
            AS[r * 5 + f] = t.v;
        }
        {   // stage B: k-tile [256][32] hi
            size_t bbase = (size_t)(k0 >> 5) * (256 * 32);
            #pragma unroll
            for (int it = 0; it < 4; it++) {
                int id = tid + it * 256;
                BS[(id >> 2) * 5 + (id & 3)] = *(const int4*)&BgH[bbase + (size_t)id * 8];
            }
        }
        __syncthreads();

        const bf16x8* ASv = (const bf16x8*)AS;
        const bf16x8* BSv = (const bf16x8*)BS;
        const int slot = lane >> 4;
        bf16x8 ah[4];
        #pragma unroll
        for (int mt = 0; mt < 4; mt++) ah[mt] = ASv[(mt * 16 + (lane & 15)) * 5 + slot];
        #pragma unroll
        for (int nt = 0; nt < 4; nt++) {
            bf16x8 bh = BSv[((w * 4 + nt) * 16 + (lane & 15)) * 5 + slot];
            #pragma unroll
            for (int mt = 0; mt < 4; mt++)
                acc[mt][nt] = __builtin_amdgcn_mfma_f32_16x16x32_bf16(ah[mt], bh, acc[mt][nt], 0, 0, 0);
        }
        __syncthreads();
    }

    const int pbase = row0 / N_NODES;
    const int rowSplit = (pbase + 1) * N_NODES;
    float l0 = 0.f, l1 = 0.f;
    #pragma unroll
    for (int nt = 0; nt < 4; nt++) {
        int col = (w * 4 + nt) * 16 + (lane & 15);
        float qc = q[col], bc = bias[col];
        #pragma unroll
        for (int mt = 0; mt < 4; mt++)
            #pragma unroll
            for (int rg = 0; rg < 4; rg++) {
                int row = row0 + mt * 16 + (lane >> 4) * 4 + rg;
                float v = qc * fast_tanh(acc[mt][nt][rg] + bc);
                if (row >= rowSplit) l1 += v; else l0 += v;
            }
    }
    #pragma unroll
    for (int off = 32; off > 0; off >>= 1) {
        l0 += __shfl_down(l0, off, 64);
        l1 += __shfl_down(l1, off, 64);
    }
    if (lane == 0) { red[w][0] = l0; red[w][1] = l1; }
    __syncthreads();
    if (tid == 0)
        atomicAdd(score + pbase, red[0][0] + red[1][0] + red[2][0] + red[3][0]);
    if (tid == 1 && pbase + 1 < P_TYPES)
        atomicAdd(score + pbase + 1, red[0][1] + red[1][1] + red[2][1] + red[3][1]);
}

// ---- fused convert: all 4 weights -> k-tiled bf16; zero cursor + score ----
__global__ __launch_bounds__(256)
void convert_weights(const float* __restrict__ Wp1, const float* __restrict__ Wp2,
                     const float* __restrict__ Wk1, const float* __restrict__ Wk2,
                     unsigned short* __restrict__ Wp1h, unsigned short* __restrict__ Wp1l,
                     unsigned short* __restrict__ Wp2h, unsigned short* __restrict__ Wp2l,
                     unsigned short* __restrict__ Wk1h, unsigned short* __restrict__ Wk2h,
                     int* __restrict__ cursor, float* __restrict__ score)
{
    int id = blockIdx.x * 256 + threadIdx.x;
    if (id < 80000) cursor[id] = 0;
    if (id < 8) score[id] = 0.f;
    if (id < 131072) {                                  // Wp1, K=512
        int n = id & 255, k = id >> 8;
        float v = Wp1[id];
        unsigned short h = f2bf(v);
        size_t dst = ((size_t)(k >> 5) * 256 + n) * 32 + (k & 31);
        Wp1h[dst] = h; Wp1l[dst] = f2bf(v - bf2f(h));
    } else if (id < 196608) {                           // Wp2, K=256
        int i2 = id - 131072;
        int n = i2 & 255, k = i2 >> 8;
        float v = Wp2[i2];
        unsigned short h = f2bf(v);
        size_t dst = ((size_t)(k >> 5) * 256 + n) * 32 + (k & 31);
        Wp2h[dst] = h; Wp2l[dst] = f2bf(v - bf2f(h));
    } else if (id < 262144) {                           // Wk1 hi
        int i2 = id - 196608;
        int n = i2 & 255, k = i2 >> 8;
        size_t dst = ((size_t)(k >> 5) * 256 + n) * 32 + (k & 31);
        Wk1h[dst] = f2bf(Wk1[i2]);
    } else if (id < 327680) {                           // Wk2 hi
        int i2 = id - 262144;
        int n = i2 & 255, k = i2 >> 8;
        size_t dst = ((size_t)(k >> 5) * 256 + n) * 32 + (k & 31);
        Wk2h[dst] = f2bf(Wk2[i2]);
    }
}

// ---- x f32 -> x_hi/x_lo bf16 (row-major), float4/thread ----
__global__ __launch_bounds__(256)
void convert_x(const float* __restrict__ x, unsigned short* __restrict__ xh,
               unsigned short* __restrict__ xl)
{
    int idx = blockIdx.x * 256 + threadIdx.x;
    if (idx >= N_NODES * 512 / 4) return;
    float4 v = ((const float4*)x)[idx];
    ushort4 h, l;
    h.x = f2bf(v.x); h.y = f2bf(v.y); h.z = f2bf(v.z); h.w = f2bf(v.w);
    l.x = f2bf(v.x - bf2f(h.x)); l.y = f2bf(v.y - bf2f(h.y));
    l.z = f2bf(v.z - bf2f(h.z)); l.w = f2bf(v.w - bf2f(h.w));
    ((ushort4*)xh)[idx] = h;
    ((ushort4*)xl)[idx] = l;
}

// ================= CSR build =================
__global__ __launch_bounds__(256)
void hist_kernel(const int* __restrict__ edst, int* __restrict__ counts)
{
    int idx = blockIdx.x * 256 + threadIdx.x;
    if (idx >= P_TYPES * E_EDGES) return;
    int p = idx / E_EDGES;
    atomicAdd(&counts[p * N_NODES + edst[idx]], 1);
}

__global__ __launch_bounds__(1024)
void scan_block(const int* __restrict__ counts, int* __restrict__ out,
                int* __restrict__ blockSum, int total)
{
    __shared__ int wsum[16];
    int tid = threadIdx.x, lane = tid & 63, w = tid >> 6;
    int i = blockIdx.x * 1024 + tid;
    int v = (i < total) ? counts[i] : 0;
    int incl = v;
    #pragma unroll
    for (int off = 1; off < 64; off <<= 1) {
        int t = __shfl_up(incl, off, 64);
        if (lane >= off) incl += t;
    }
    if (lane == 63) wsum[w] = incl;
    __syncthreads();
    if (w == 0) {
        int s = (lane < 16) ? wsum[lane] : 0;
        #pragma unroll
        for (int off = 1; off < 16; off <<= 1) {
            int t = __shfl_up(s, off, 64);
            if (lane >= off) s += t;
        }
        if (lane < 16) wsum[lane] = s;
    }
    __syncthreads();
    int waveoff = w ? wsum[w - 1] : 0;
    if (i < total) out[i] = waveoff + incl - v;
    if (tid == 1023 && blockSum) blockSum[blockIdx.x] = wsum[15];
}

__global__ __launch_bounds__(1024)
void scan_add(int* __restrict__ row_start, int* __restrict__ cursor,
              const int* __restrict__ blockOff, int total)
{
    int i = blockIdx.x * 1024 + threadIdx.x;
    if (i == 0) row_start[total] = P_TYPES * E_EDGES;
    if (i < total) {
        int v = row_start[i] + blockOff[blockIdx.x];
        row_start[i] = v;
        cursor[i] = v;
    }
}

__global__ __launch_bounds__(256)
void fill_kernel(const int* __restrict__ esrc, const int* __restrict__ edst,
                 int* __restrict__ cursor, int* __restrict__ csr_src)
{
    int idx = blockIdx.x * 256 + threadIdx.x;
    if (idx >= P_TYPES * E_EDGES) return;
    int p = idx / E_EDGES;
    int pos = atomicAdd(&cursor[p * N_NODES + edst[idx]], 1);
    csr_src[pos] = esrc[idx];
}

// ---------------- CSR gather: 1 wave/segment, bf16 in, bf16 out -------------
__global__ __launch_bounds__(256)
void gather_kernel(const int* __restrict__ row_start, const int* __restrict__ csr_src,
                   const float* __restrict__ a_src, const float* __restrict__ a_dst,
                   const unsigned short* __restrict__ zb, unsigned short* __restrict__ outsb)
{
    int seg = blockIdx.x * 4 + (threadIdx.x >> 6);      // p*N + dst (grid exact)
    int lane = threadIdx.x & 63;
    int sub = lane >> 5, cl = lane & 31;
    int h = cl >> 2;
    int dst = seg % N_NODES;
    float ad = a_dst[dst * HEADS + h];
    int start = row_start[seg], end = row_start[seg + 1];

    float acc[8] = {};
    float den = 0.f;
    for (int i = start + sub; i < end; i += 2) {
        int src = csr_src[i];
        float s = a_src[src * HEADS + h] + ad;
        float e = s > 0.f ? s : NEG_SLOPE * s;
        float wgt = __expf(e);
        ushort8 zv = *(const ushort8*)(zb + (size_t)src * DHID + cl * 8);
        #pragma unroll
        for (int j = 0; j < 8; j++) acc[j] += wgt * bf2f(zv[j]);
        den += wgt;
    }
    den += __shfl_xor(den, 32, 64);
    #pragma unroll
    for (int j = 0; j < 8; j++) acc[j] += __shfl_xor(acc[j], 32, 64);
    if (sub == 0) {
        float inv = den > 0.f ? 1.0f / den : 0.f;
        ushort8 o;
        #pragma unroll
        for (int j = 0; j < 8; j++) o[j] = f2bf(acc[j] * inv);
        *(ushort8*)(outsb + (size_t)seg * DHID + cl * 8) = o;
    }
}

// -------- weighted sum over types, fused beta softmax (+relu, opt elu) ------
// OUTMODE 0: write f32 hout (for final). OUTMODE 1: write bf16 hi/lo (for proj2).
template<int OUTMODE, bool ELU>
__global__ __launch_bounds__(256)
void wsum_kernel(const unsigned short* __restrict__ outsb, const float* __restrict__ score,
                 float* __restrict__ hout, unsigned short* __restrict__ hh,
                 unsigned short* __restrict__ hl)
{
    int idx = blockIdx.x * 256 + threadIdx.x;          // ushort8 index into [N,256]
    if (idx >= N_NODES * DHID / 8) return;
    float s0 = score[0], s1 = score[1], s2 = score[2], s3 = score[3];
    float m = fmaxf(fmaxf(s0, s1), fmaxf(s2, s3));
    float b[4];
    b[0] = __expf((s0 - m) * (1.f / N_NODES));
    b[1] = __expf((s1 - m) * (1.f / N_NODES));
    b[2] = __expf((s2 - m) * (1.f / N_NODES));
    b[3] = __expf((s3 - m) * (1.f / N_NODES));
    // NOTE: softmax argument is score/N; subtract m/N consistently:
    // recompute properly below to match reference exactly.
    float t0 = (s0 - m) * (1.f / N_NODES), t1 = (s1 - m) * (1.f / N_NODES);
    float t2 = (s2 - m) * (1.f / N_NODES), t3 = (s3 - m) * (1.f / N_NODES);
    float mm = fmaxf(fmaxf(t0, t1), fmaxf(t2, t3));
    b[0] = __expf(t0 - mm); b[1] = __expf(t1 - mm);
    b[2] = __expf(t2 - mm); b[3] = __expf(t3 - mm);
    float dinv = 1.f / (b[0] + b[1] + b[2] + b[3]);
    b[0] *= dinv; b[1] *= dinv; b[2] *= dinv; b[3] *= dinv;

    const size_t stride = (size_t)N_NODES * DHID / 8;
    const ushort8* o = (const ushort8*)outsb;
    float r[8] = {};
    #pragma unroll
    for (int p = 0; p < 4; p++) {
        ushort8 v = o[idx + p * stride];
        #pragma unroll
        for (int j = 0; j < 8; j++) r[j] += b[p] * fmaxf(bf2f(v[j]), 0.f);
    }
    if (ELU) {
        #pragma unroll
        for (int j = 0; j < 8; j++) r[j] = r[j] > 0.f ? r[j] : expm1f(r[j]);
    }
    if (OUTMODE == 0) {
        float4* hp = (float4*)(hout + (size_t)idx * 8);
        hp[0] = make_float4(r[0], r[1], r[2], r[3]);
        hp[1] = make_float4(r[4], r[5], r[6], r[7]);
    } else {
        ushort8 vh, vl;
        #pragma unroll
        for (int j = 0; j < 8; j++) {
            vh[j] = f2bf(r[j]);
            vl[j] = f2bf(r[j] - bf2f(vh[j]));
        }
        ((ushort8*)hh)[idx] = vh;
        ((ushort8*)hl)[idx] = vl;
    }
}

// ---------------- final classifier [N,256]@[256,16]+bo ----------------
__global__ __launch_bounds__(256)
void final_kernel(const float* __restrict__ h, const float* __restrict__ Wo,
                  const float* __restrict__ bo, float* __restrict__ out)
{
    int idx = blockIdx.x * 256 + threadIdx.x;
    if (idx >= N_NODES * NCLASSES) return;
    int c = idx & 15, n = idx >> 4;
    const float* hr = h + (size_t)n * DHID;
    float acc = bo[c];
    #pragma unroll 8
    for (int k = 0; k < DHID; k++) acc = fmaf(hr[k], Wo[k * NCLASSES + c], acc);
    out[idx] = acc;
}

extern "C" void kernel_launch(void* const* d_in, const int* in_sizes, int n_in,
                              void* d_out, int out_size, void* d_ws, size_t ws_size,
                              hipStream_t stream)
{
    const float* x   = (const float*)d_in[0];
    const int*  esrc = (const int*)d_in[1];
    const int*  edst = (const int*)d_in[2];
    const float* Wp1 = (const float*)d_in[3];
    const float* bp1 = (const float*)d_in[4];
    const float* as1 = (const float*)d_in[5];
    const float* ad1 = (const float*)d_in[6];
    const float* Wk1 = (const float*)d_in[7];
    const float* bk1 = (const float*)d_in[8];
    const float* q1  = (const float*)d_in[9];
    const float* Wp2 = (const float*)d_in[10];
    const float* bp2 = (const float*)d_in[11];
    const float* as2 = (const float*)d_in[12];
    const float* ad2 = (const float*)d_in[13];
    const float* Wk2 = (const float*)d_in[14];
    const float* bk2 = (const float*)d_in[15];
    const float* q2  = (const float*)d_in[16];
    const float* Wo  = (const float*)d_in[17];
    const float* bo  = (const float*)d_in[18];
    float* out = (float*)d_out;

    // workspace layout (byte offsets, ~141 MB, all 16B-aligned)
    char* wsb = (char*)d_ws;
    float* hbuf  = (float*)wsb;                                   // 20,480,000
    float* a_s   = (float*)(wsb + 20480000);                      //    640,000
    float* a_d   = (float*)(wsb + 21120000);                      //    640,000
    float* score = (float*)(wsb + 21760000);                      //         32
    unsigned short* zb      = (unsigned short*)(wsb + 21760032);  // 10,240,000
    unsigned short* outsb   = (unsigned short*)(wsb + 32000032);  // 40,960,000
    unsigned short* x_hi    = (unsigned short*)(wsb + 72960032);  // 20,480,000
    unsigned short* x_lo    = (unsigned short*)(wsb + 93440032);  // 20,480,000
    unsigned short* h_hi    = (unsigned short*)(wsb + 113920032); // 10,240,000
    unsigned short* h_lo    = (unsigned short*)(wsb + 124160032); // 10,240,000
    unsigned short* Wp1t_hi = (unsigned short*)(wsb + 134400032); //    262,144
    unsigned short* Wp1t_lo = (unsigned short*)(wsb + 134662176);
    unsigned short* Wp2t_hi = (unsigned short*)(wsb + 134924320); //    131,072
    unsigned short* Wp2t_lo = (unsigned short*)(wsb + 135055392);
    unsigned short* Wk1t_hi = (unsigned short*)(wsb + 135186464);
    unsigned short* Wk2t_hi = (unsigned short*)(wsb + 135317536);
    int* row_start = (int*)(wsb + 135448608);                     //    320,016
    int* cursor    = (int*)(wsb + 135768624);                     //    320,000
    int* blockSum  = (int*)(wsb + 136088624);                     //        512
    int* blockOff  = (int*)(wsb + 136089136);                     //        512
    int* csr_src   = (int*)(wsb + 136089648);                     //  5,120,000

    const int PN = P_TYPES * N_NODES;            // 80,000
    const int PE = P_TYPES * E_EDGES;            // 1,280,000
    const int NBS = (PN + 1023) / 1024;          // 79

    // ---- converts + zeroing (1 dispatch) + x split (1 dispatch) ----
    convert_weights<<<1280, 256, 0, stream>>>(Wp1, Wp2, Wk1, Wk2,
        Wp1t_hi, Wp1t_lo, Wp2t_hi, Wp2t_lo, Wk1t_hi, Wk2t_hi, cursor, score);
    convert_x<<<(N_NODES * 512 / 4 + 255) / 256, 256, 0, stream>>>(x, x_hi, x_lo);

    // ---- CSR build (edge structure shared by both layers) ----
    hist_kernel<<<(PE + 255) / 256, 256, 0, stream>>>(edst, cursor);
    scan_block<<<NBS, 1024, 0, stream>>>(cursor, row_start, blockSum, PN);
    scan_block<<<1, 1024, 0, stream>>>(blockSum, blockOff, nullptr, NBS);
    scan_add<<<NBS, 1024, 0, stream>>>(row_start, cursor, blockOff, PN);
    fill_kernel<<<(PE + 255) / 256, 256, 0, stream>>>(esrc, edst, cursor, csr_src);

    dim3 gp((N_NODES + 63) / 64, 2);
    const int gw = (N_NODES * DHID / 8 + 255) / 256;

    // ---- layer 1 ----
    proj_gemm<<<gp, 256, 0, stream>>>(x_hi, x_lo, Wp1t_hi, Wp1t_lo, bp1, as1, ad1,
                                      zb, a_s, a_d, N_NODES, 512);
    gather_kernel<<<PN / 4, 256, 0, stream>>>(row_start, csr_src, a_s, a_d, zb, outsb);
    score_gemm<<<PN / 64, 256, 0, stream>>>(outsb, Wk1t_hi, bk1, q1, score, PN);
    wsum_kernel<1, true><<<gw, 256, 0, stream>>>(outsb, score, nullptr, h_hi, h_lo);

    // ---- layer 2 ----
    proj_gemm<<<gp, 256, 0, stream>>>(h_hi, h_lo, Wp2t_hi, Wp2t_lo, bp2, as2, ad2,
                                      zb, a_s, a_d, N_NODES, 256);
    gather_kernel<<<PN / 4, 256, 0, stream>>>(row_start, csr_src, a_s, a_d, zb, outsb);
    score_gemm<<<PN / 64, 256, 0, stream>>>(outsb, Wk2t_hi, bk2, q2, score + 4, PN);
    wsum_kernel<0, false><<<gw, 256, 0, stream>>>(outsb, score + 4, hbuf, nullptr, nullptr);

    final_kernel<<<(N_NODES * NCLASSES + 255) / 256, 256, 0, stream>>>(hbuf, Wo, bo, out);
}

// Round 8
// 502.465 us; speedup vs baseline: 18.1619x; 1.1016x over previous
//
#include <hip/hip_runtime.h>
#include <hip/hip_bf16.h>
#include <cstdint>

#define N_NODES 20000
#define E_EDGES 320000
#define P_TYPES 4
#define HEADS   8
#define DHID    256
#define NCLASSES 16
#define NEG_SLOPE 0.2f

typedef __attribute__((ext_vector_type(8))) short bf16x8;
typedef __attribute__((ext_vector_type(8))) unsigned short ushort8;
typedef __attribute__((ext_vector_type(4))) float f32x4;

static __device__ __forceinline__ unsigned short f2bf(float v) {
    __hip_bfloat16 h = __float2bfloat16(v);
    return *(unsigned short*)&h;
}
static __device__ __forceinline__ float bf2f(unsigned short u) {
    __hip_bfloat16 h = *(__hip_bfloat16*)&u;
    return __bfloat162float(h);
}
static __device__ __forceinline__ float fast_tanh(float x) {
    x = fminf(fmaxf(x, -10.f), 10.f);
    float t = __expf(2.f * x);
    return (t - 1.f) * __builtin_amdgcn_rcpf(t + 1.f);   // ~1e-6 rel, plenty
}

// ========== proj GEMM: zb = A[MxK](hi+lo bf16) @ Wp + bp, fused epilogue ====
// A pre-split row-major bf16 hi/lo. B k-tiled [K/32][256][32] hi/lo.
// BM=64, BN=128 (blockIdx.y in {0,1}), 4 waves; wave w = 64 rows x 32 cols
// = head (by*4 + w). 3 MFMAs (hi*hi + hi*lo + lo*hi) = fp32-grade.
// Epilogue: write zb bf16; a_src/a_dst via 16-lane shfl reduce (one head/wave).
// LDS rows 5 int4 (80B) -> conflict-free ds_read_b128.
__global__ __launch_bounds__(256)
void proj_gemm(const unsigned short* __restrict__ Ah, const unsigned short* __restrict__ Al,
               const unsigned short* __restrict__ BgH, const unsigned short* __restrict__ BgL,
               const float* __restrict__ bias, const float* __restrict__ att_s,
               const float* __restrict__ att_d, unsigned short* __restrict__ zb,
               float* __restrict__ a_s, float* __restrict__ a_d, int M, int K)
{
    __shared__ int4 AS[2 * 64 * 5];
    __shared__ int4 BS[2 * 128 * 5];
    const int row0 = blockIdx.x * 64;
    const int by = blockIdx.y;
    const int tid = threadIdx.x, lane = tid & 63, w = tid >> 6;

    f32x4 acc[4][2];
    const f32x4 zero4 = {0.f, 0.f, 0.f, 0.f};
    #pragma unroll
    for (int i = 0; i < 4; i++) { acc[i][0] = zero4; acc[i][1] = zero4; }

    for (int k0 = 0; k0 < K; k0 += 32) {
        {   // stage A: 64 rows x 32 k hi+lo (pure copies)
            int r = tid >> 2, f = tid & 3;
            int rg_ = row0 + r;
            int4 vh = make_int4(0, 0, 0, 0), vl = make_int4(0, 0, 0, 0);
            if (rg_ < M) {
                size_t a = (size_t)rg_ * K + k0 + f * 8;
                vh = *(const int4*)&Ah[a];
                vl = *(const int4*)&Al[a];
            }
            AS[r * 5 + f] = vh;
            AS[64 * 5 + r * 5 + f] = vl;
        }
        {   // stage B: 128 n-rows x 32 k hi+lo from k-tiled layout (coalesced)
            size_t bbase = (size_t)(k0 >> 5) * (256 * 32) + (size_t)(by * 128) * 32;
            #pragma unroll
            for (int it = 0; it < 2; it++) {
                int id = tid + it * 256;
                int r = id >> 2, f = id & 3;
                size_t a = bbase + (size_t)r * 32 + f * 8;
                BS[r * 5 + f] = *(const int4*)&BgH[a];
                BS[128 * 5 + r * 5 + f] = *(const int4*)&BgL[a];
            }
        }
        __syncthreads();

        const bf16x8* ASv = (const bf16x8*)AS;
        const bf16x8* BSv = (const bf16x8*)BS;
        const int slot = lane >> 4;
        bf16x8 ah[4], al[4];
        #pragma unroll
        for (int mt = 0; mt < 4; mt++) {
            int r = mt * 16 + (lane & 15);
            ah[mt] = ASv[r * 5 + slot];
            al[mt] = ASv[64 * 5 + r * 5 + slot];
        }
        #pragma unroll
        for (int nt = 0; nt < 2; nt++) {
            int rb = (w * 2 + nt) * 16 + (lane & 15);
            bf16x8 bh = BSv[rb * 5 + slot];
            bf16x8 bl = BSv[128 * 5 + rb * 5 + slot];
            #pragma unroll
            for (int mt = 0; mt < 4; mt++) {
                acc[mt][nt] = __builtin_amdgcn_mfma_f32_16x16x32_bf16(ah[mt], bh, acc[mt][nt], 0, 0, 0);
                acc[mt][nt] = __builtin_amdgcn_mfma_f32_16x16x32_bf16(ah[mt], bl, acc[mt][nt], 0, 0, 0);
                acc[mt][nt] = __builtin_amdgcn_mfma_f32_16x16x32_bf16(al[mt], bh, acc[mt][nt], 0, 0, 0);
            }
        }
        __syncthreads();
    }

    // Epilogue. C/D: col=lane&15 within 16-tile, row=(lane>>4)*4+reg.
    const int c15 = lane & 15, lhi = lane >> 4;
    const int hd = by * 4 + w;                       // this wave's head
    float asw[2], adw[2], bw[2];
    #pragma unroll
    for (int nt = 0; nt < 2; nt++) {
        int col = by * 128 + w * 32 + nt * 16 + c15;
        asw[nt] = att_s[col]; adw[nt] = att_d[col]; bw[nt] = bias[col];
    }
    #pragma unroll
    for (int mt = 0; mt < 4; mt++) {
        #pragma unroll
        for (int rg = 0; rg < 4; rg++) {
            int row = row0 + mt * 16 + lhi * 4 + rg;
            bool ok = row < M;
            float v0 = acc[mt][0][rg] + bw[0], v1 = acc[mt][1][rg] + bw[1];
            if (ok) {
                unsigned short* zp = zb + (size_t)row * DHID + by * 128 + w * 32 + c15;
                zp[0] = f2bf(v0); zp[16] = f2bf(v1);
            }
            float hs = v0 * asw[0] + v1 * asw[1];
            float hdd = v0 * adw[0] + v1 * adw[1];
            #pragma unroll
            for (int off = 1; off < 16; off <<= 1) {
                hs += __shfl_xor(hs, off, 64); hdd += __shfl_xor(hdd, off, 64);
            }
            if (ok && c15 == 0) {
                a_s[row * HEADS + hd] = hs;
                a_d[row * HEADS + hd] = hdd;
            }
        }
    }
}

// ========== score GEMM: bf16 A (relu'd), K=256, score-reduce epilogue =======
__global__ __launch_bounds__(256)
void score_gemm(const unsigned short* __restrict__ Ab, const unsigned short* __restrict__ BgH,
                const float* __restrict__ bias, const float* __restrict__ q,
                float* __restrict__ score, int M)
{
    __shared__ int4 AS[64 * 5];
    __shared__ int4 BS[256 * 5];
    __shared__ float red[4][2];
    const int row0 = blockIdx.x * 64;
    const int tid = threadIdx.x, lane = tid & 63, w = tid >> 6;

    f32x4 acc[4][4];
    const f32x4 zero4 = {0.f, 0.f, 0.f, 0.f};
    #pragma unroll
    for (int i = 0; i < 4; i++)
        #pragma unroll
        for (int j = 0; j < 4; j++) acc[i][j] = zero4;

    for (int k0 = 0; k0 < 256; k0 += 32) {
        {   // stage A: bf16 copy + relu bit-trick
            int r = tid >> 2, f = tid & 3;
            union { int4 v; unsigned short u[8]; } t;
            t.v = *(const int4*)&Ab[(size_t)(row0 + r) * DHID + k0 + f * 8];
            #pragma unroll
            for (int j = 0; j < 8; j++) if (t.u[j] & 0x8000) t.u[j] = 0;
            AS[r * 5 + f] = t.v;
        }
        {   // stage B: k-tile [256][32] hi
            size_t bbase = (size_t)(k0 >> 5) * (256 * 32);
            #pragma unroll
            for (int it = 0; it < 4; it++) {
                int id = tid + it * 256;
                BS[(id >> 2) * 5 + (id & 3)] = *(const int4*)&BgH[bbase + (size_t)id * 8];
            }
        }
        __syncthreads();

        const bf16x8* ASv = (const bf16x8*)AS;
        const bf16x8* BSv = (const bf16x8*)BS;
        const int slot = lane >> 4;
        bf16x8 ah[4];
        #pragma unroll
        for (int mt = 0; mt < 4; mt++) ah[mt] = ASv[(mt * 16 + (lane & 15)) * 5 + slot];
        #pragma unroll
        for (int nt = 0; nt < 4; nt++) {
            bf16x8 bh = BSv[((w * 4 + nt) * 16 + (lane & 15)) * 5 + slot];
            #pragma unroll
            for (int mt = 0; mt < 4; mt++)
                acc[mt][nt] = __builtin_amdgcn_mfma_f32_16x16x32_bf16(ah[mt], bh, acc[mt][nt], 0, 0, 0);
        }
        __syncthreads();
    }

    const int pbase = row0 / N_NODES;
    const int rowSplit = (pbase + 1) * N_NODES;
    float l0 = 0.f, l1 = 0.f;
    #pragma unroll
    for (int nt = 0; nt < 4; nt++) {
        int col = (w * 4 + nt) * 16 + (lane & 15);
        float qc = q[col], bc = bias[col];
        #pragma unroll
        for (int mt = 0; mt < 4; mt++)
            #pragma unroll
            for (int rg = 0; rg < 4; rg++) {
                int row = row0 + mt * 16 + (lane >> 4) * 4 + rg;
                float v = qc * fast_tanh(acc[mt][nt][rg] + bc);
                if (row >= rowSplit) l1 += v; else l0 += v;
            }
    }
    #pragma unroll
    for (int off = 32; off > 0; off >>= 1) {
        l0 += __shfl_down(l0, off, 64);
        l1 += __shfl_down(l1, off, 64);
    }
    if (lane == 0) { red[w][0] = l0; red[w][1] = l1; }
    __syncthreads();
    if (tid == 0)
        atomicAdd(score + pbase, red[0][0] + red[1][0] + red[2][0] + red[3][0]);
    if (tid == 1 && pbase + 1 < P_TYPES)
        atomicAdd(score + pbase + 1, red[0][1] + red[1][1] + red[2][1] + red[3][1]);
}

// ---- fused convert: all 4 weights -> k-tiled bf16; zero cursor + score ----
__global__ __launch_bounds__(256)
void convert_weights(const float* __restrict__ Wp1, const float* __restrict__ Wp2,
                     const float* __restrict__ Wk1, const float* __restrict__ Wk2,
                     unsigned short* __restrict__ Wp1h, unsigned short* __restrict__ Wp1l,
                     unsigned short* __restrict__ Wp2h, unsigned short* __restrict__ Wp2l,
                     unsigned short* __restrict__ Wk1h, unsigned short* __restrict__ Wk2h,
                     int* __restrict__ cursor, float* __restrict__ score)
{
    int id = blockIdx.x * 256 + threadIdx.x;
    if (id < 80000) cursor[id] = 0;
    if (id < 8) score[id] = 0.f;
    if (id < 131072) {                                  // Wp1, K=512
        int n = id & 255, k = id >> 8;
        float v = Wp1[id];
        unsigned short h = f2bf(v);
        size_t dst = ((size_t)(k >> 5) * 256 + n) * 32 + (k & 31);
        Wp1h[dst] = h; Wp1l[dst] = f2bf(v - bf2f(h));
    } else if (id < 196608) {                           // Wp2, K=256
        int i2 = id - 131072;
        int n = i2 & 255, k = i2 >> 8;
        float v = Wp2[i2];
        unsigned short h = f2bf(v);
        size_t dst = ((size_t)(k >> 5) * 256 + n) * 32 + (k & 31);
        Wp2h[dst] = h; Wp2l[dst] = f2bf(v - bf2f(h));
    } else if (id < 262144) {                           // Wk1 hi
        int i2 = id - 196608;
        int n = i2 & 255, k = i2 >> 8;
        size_t dst = ((size_t)(k >> 5) * 256 + n) * 32 + (k & 31);
        Wk1h[dst] = f2bf(Wk1[i2]);
    } else if (id < 327680) {                           // Wk2 hi
        int i2 = id - 262144;
        int n = i2 & 255, k = i2 >> 8;
        size_t dst = ((size_t)(k >> 5) * 256 + n) * 32 + (k & 31);
        Wk2h[dst] = f2bf(Wk2[i2]);
    }
}

// ---- x f32 -> x_hi/x_lo bf16 (row-major), float4/thread ----
__global__ __launch_bounds__(256)
void convert_x(const float* __restrict__ x, unsigned short* __restrict__ xh,
               unsigned short* __restrict__ xl)
{
    int idx = blockIdx.x * 256 + threadIdx.x;
    if (idx >= N_NODES * 512 / 4) return;
    float4 v = ((const float4*)x)[idx];
    ushort4 h, l;
    h.x = f2bf(v.x); h.y = f2bf(v.y); h.z = f2bf(v.z); h.w = f2bf(v.w);
    l.x = f2bf(v.x - bf2f(h.x)); l.y = f2bf(v.y - bf2f(h.y));
    l.z = f2bf(v.z - bf2f(h.z)); l.w = f2bf(v.w - bf2f(h.w));
    ((ushort4*)xh)[idx] = h;
    ((ushort4*)xl)[idx] = l;
}

// ================= CSR build =================
__global__ __launch_bounds__(256)
void hist_kernel(const int* __restrict__ edst, int* __restrict__ counts)
{
    int idx = blockIdx.x * 256 + threadIdx.x;
    if (idx >= P_TYPES * E_EDGES) return;
    int p = idx / E_EDGES;
    atomicAdd(&counts[p * N_NODES + edst[idx]], 1);
}

__global__ __launch_bounds__(1024)
void scan_block(const int* __restrict__ counts, int* __restrict__ out,
                int* __restrict__ blockSum, int total)
{
    __shared__ int wsum[16];
    int tid = threadIdx.x, lane = tid & 63, w = tid >> 6;
    int i = blockIdx.x * 1024 + tid;
    int v = (i < total) ? counts[i] : 0;
    int incl = v;
    #pragma unroll
    for (int off = 1; off < 64; off <<= 1) {
        int t = __shfl_up(incl, off, 64);
        if (lane >= off) incl += t;
    }
    if (lane == 63) wsum[w] = incl;
    __syncthreads();
    if (w == 0) {
        int s = (lane < 16) ? wsum[lane] : 0;
        #pragma unroll
        for (int off = 1; off < 16; off <<= 1) {
            int t = __shfl_up(s, off, 64);
            if (lane >= off) s += t;
        }
        if (lane < 16) wsum[lane] = s;
    }
    __syncthreads();
    int waveoff = w ? wsum[w - 1] : 0;
    if (i < total) out[i] = waveoff + incl - v;
    if (tid == 1023 && blockSum) blockSum[blockIdx.x] = wsum[15];
}

__global__ __launch_bounds__(1024)
void scan_add(int* __restrict__ row_start, int* __restrict__ cursor,
              const int* __restrict__ blockOff, int total)
{
    int i = blockIdx.x * 1024 + threadIdx.x;
    if (i == 0) row_start[total] = P_TYPES * E_EDGES;
    if (i < total) {
        int v = row_start[i] + blockOff[blockIdx.x];
        row_start[i] = v;
        cursor[i] = v;
    }
}

__global__ __launch_bounds__(256)
void fill_kernel(const int* __restrict__ esrc, const int* __restrict__ edst,
                 int* __restrict__ cursor, int* __restrict__ csr_src)
{
    int idx = blockIdx.x * 256 + threadIdx.x;
    if (idx >= P_TYPES * E_EDGES) return;
    int p = idx / E_EDGES;
    int pos = atomicAdd(&cursor[p * N_NODES + edst[idx]], 1);
    csr_src[pos] = esrc[idx];
}

// ------- CSR gather: 1 wave/segment, 4 edges in flight (2 per half-wave) ----
__global__ __launch_bounds__(256)
void gather_kernel(const int* __restrict__ row_start, const int* __restrict__ csr_src,
                   const float* __restrict__ a_src, const float* __restrict__ a_dst,
                   const unsigned short* __restrict__ zb, unsigned short* __restrict__ outsb)
{
    int seg = blockIdx.x * 4 + (threadIdx.x >> 6);      // p*N + dst (grid exact)
    int lane = threadIdx.x & 63;
    int sub = lane >> 5, cl = lane & 31;
    int h = cl >> 2;
    int dst = seg % N_NODES;
    float ad = a_dst[dst * HEADS + h];
    int start = row_start[seg], end = row_start[seg + 1];

    float acc[8] = {};
    float den = 0.f;
    int i = start + sub;
    // 2x unrolled: batch loads for edges i and i+2 -> 4 edges in flight per wave
    for (; i + 2 < end; i += 4) {
        int s0 = csr_src[i];
        int s1 = csr_src[i + 2];
        float g0 = a_src[s0 * HEADS + h];
        float g1 = a_src[s1 * HEADS + h];
        ushort8 z0 = *(const ushort8*)(zb + (size_t)s0 * DHID + cl * 8);
        ushort8 z1 = *(const ushort8*)(zb + (size_t)s1 * DHID + cl * 8);
        float e0 = g0 + ad; e0 = e0 > 0.f ? e0 : NEG_SLOPE * e0;
        float e1 = g1 + ad; e1 = e1 > 0.f ? e1 : NEG_SLOPE * e1;
        float w0 = __expf(e0), w1 = __expf(e1);
        #pragma unroll
        for (int j = 0; j < 8; j++) acc[j] += w0 * bf2f(z0[j]);
        #pragma unroll
        for (int j = 0; j < 8; j++) acc[j] += w1 * bf2f(z1[j]);
        den += w0 + w1;
    }
    if (i < end) {
        int s0 = csr_src[i];
        float g0 = a_src[s0 * HEADS + h];
        ushort8 z0 = *(const ushort8*)(zb + (size_t)s0 * DHID + cl * 8);
        float e0 = g0 + ad; e0 = e0 > 0.f ? e0 : NEG_SLOPE * e0;
        float w0 = __expf(e0);
        #pragma unroll
        for (int j = 0; j < 8; j++) acc[j] += w0 * bf2f(z0[j]);
        den += w0;
    }
    den += __shfl_xor(den, 32, 64);
    #pragma unroll
    for (int j = 0; j < 8; j++) acc[j] += __shfl_xor(acc[j], 32, 64);
    if (sub == 0) {
        float inv = den > 0.f ? 1.0f / den : 0.f;
        ushort8 o;
        #pragma unroll
        for (int j = 0; j < 8; j++) o[j] = f2bf(acc[j] * inv);
        *(ushort8*)(outsb + (size_t)seg * DHID + cl * 8) = o;
    }
}

// -------- weighted sum over types, fused beta softmax (+relu, opt elu) ------
// OUTMODE 0: fused final classifier -> out f32 [N,16] (block owns 8 rows).
// OUTMODE 1: write bf16 hi/lo (input for proj2).
template<int OUTMODE, bool ELU>
__global__ __launch_bounds__(256)
void wsum_kernel(const unsigned short* __restrict__ outsb, const float* __restrict__ score,
                 unsigned short* __restrict__ hh, unsigned short* __restrict__ hl,
                 const float* __restrict__ Wo, const float* __restrict__ bo,
                 float* __restrict__ out)
{
    __shared__ float hblk[8][256];                      // only used by OUTMODE 0
    int idx = blockIdx.x * 256 + threadIdx.x;           // ushort8 index into [N,256]
    float s0 = score[0], s1 = score[1], s2 = score[2], s3 = score[3];
    float m = fmaxf(fmaxf(s0, s1), fmaxf(s2, s3));
    float b[4];
    b[0] = __expf((s0 - m) * (1.f / N_NODES));
    b[1] = __expf((s1 - m) * (1.f / N_NODES));
    b[2] = __expf((s2 - m) * (1.f / N_NODES));
    b[3] = __expf((s3 - m) * (1.f / N_NODES));
    float dinv = 1.f / (b[0] + b[1] + b[2] + b[3]);
    b[0] *= dinv; b[1] *= dinv; b[2] *= dinv; b[3] *= dinv;

    const size_t stride = (size_t)N_NODES * DHID / 8;
    const ushort8* o = (const ushort8*)outsb;
    float r[8] = {};
    #pragma unroll
    for (int p = 0; p < 4; p++) {
        ushort8 v = o[idx + p * stride];
        #pragma unroll
        for (int j = 0; j < 8; j++) r[j] += b[p] * fmaxf(bf2f(v[j]), 0.f);
    }
    if (ELU) {
        #pragma unroll
        for (int j = 0; j < 8; j++) r[j] = r[j] > 0.f ? r[j] : expm1f(r[j]);
    }
    if (OUTMODE == 1) {
        ushort8 vh, vl;
        #pragma unroll
        for (int j = 0; j < 8; j++) {
            vh[j] = f2bf(r[j]);
            vl[j] = f2bf(r[j] - bf2f(vh[j]));
        }
        ((ushort8*)hh)[idx] = vh;
        ((ushort8*)hl)[idx] = vl;
    } else {
        // stage this block's 8 rows, then 128 threads do [8x256]@[256x16]+bo
        int row_l = threadIdx.x >> 5, u = threadIdx.x & 31;
        #pragma unroll
        for (int j = 0; j < 8; j++) hblk[row_l][u * 8 + j] = r[j];
        __syncthreads();
        int j = threadIdx.x;
        if (j < 8 * NCLASSES) {
            int rl = j >> 4, c = j & 15;
            float accv = bo[c];
            const float* hr = hblk[rl];
            #pragma unroll 8
            for (int k = 0; k < DHID; k++) accv = fmaf(hr[k], Wo[k * NCLASSES + c], accv);
            out[(size_t)(blockIdx.x * 8 + rl) * NCLASSES + c] = accv;
        }
    }
}

extern "C" void kernel_launch(void* const* d_in, const int* in_sizes, int n_in,
                              void* d_out, int out_size, void* d_ws, size_t ws_size,
                              hipStream_t stream)
{
    const float* x   = (const float*)d_in[0];
    const int*  esrc = (const int*)d_in[1];
    const int*  edst = (const int*)d_in[2];
    const float* Wp1 = (const float*)d_in[3];
    const float* bp1 = (const float*)d_in[4];
    const float* as1 = (const float*)d_in[5];
    const float* ad1 = (const float*)d_in[6];
    const float* Wk1 = (const float*)d_in[7];
    const float* bk1 = (const float*)d_in[8];
    const float* q1  = (const float*)d_in[9];
    const float* Wp2 = (const float*)d_in[10];
    const float* bp2 = (const float*)d_in[11];
    const float* as2 = (const float*)d_in[12];
    const float* ad2 = (const float*)d_in[13];
    const float* Wk2 = (const float*)d_in[14];
    const float* bk2 = (const float*)d_in[15];
    const float* q2  = (const float*)d_in[16];
    const float* Wo  = (const float*)d_in[17];
    const float* bo  = (const float*)d_in[18];
    float* out = (float*)d_out;

    // workspace layout (byte offsets, all 16B-aligned)
    char* wsb = (char*)d_ws;
    float* a_s   = (float*)(wsb + 20480000);                      //    640,000
    float* a_d   = (float*)(wsb + 21120000);                      //    640,000
    float* score = (float*)(wsb + 21760000);                      //         32
    unsigned short* zb      = (unsigned short*)(wsb + 21760032);  // 10,240,000
    unsigned short* outsb   = (unsigned short*)(wsb + 32000032);  // 40,960,000
    unsigned short* x_hi    = (unsigned short*)(wsb + 72960032);  // 20,480,000
    unsigned short* x_lo    = (unsigned short*)(wsb + 93440032);  // 20,480,000
    unsigned short* h_hi    = (unsigned short*)(wsb + 113920032); // 10,240,000
    unsigned short* h_lo    = (unsigned short*)(wsb + 124160032); // 10,240,000
    unsigned short* Wp1t_hi = (unsigned short*)(wsb + 134400032); //    262,144
    unsigned short* Wp1t_lo = (unsigned short*)(wsb + 134662176);
    unsigned short* Wp2t_hi = (unsigned short*)(wsb + 134924320); //    131,072
    unsigned short* Wp2t_lo = (unsigned short*)(wsb + 135055392);
    unsigned short* Wk1t_hi = (unsigned short*)(wsb + 135186464);
    unsigned short* Wk2t_hi = (unsigned short*)(wsb + 135317536);
    int* row_start = (int*)(wsb + 135448608);                     //    320,016
    int* cursor    = (int*)(wsb + 135768624);                     //    320,000
    int* blockSum  = (int*)(wsb + 136088624);                     //        512
    int* blockOff  = (int*)(wsb + 136089136);                     //        512
    int* csr_src   = (int*)(wsb + 136089648);                     //  5,120,000

    const int PN = P_TYPES * N_NODES;            // 80,000
    const int PE = P_TYPES * E_EDGES;            // 1,280,000
    const int NBS = (PN + 1023) / 1024;          // 79

    // ---- converts + zeroing (1 dispatch) + x split (1 dispatch) ----
    convert_weights<<<1280, 256, 0, stream>>>(Wp1, Wp2, Wk1, Wk2,
        Wp1t_hi, Wp1t_lo, Wp2t_hi, Wp2t_lo, Wk1t_hi, Wk2t_hi, cursor, score);
    convert_x<<<(N_NODES * 512 / 4 + 255) / 256, 256, 0, stream>>>(x, x_hi, x_lo);

    // ---- CSR build (edge structure shared by both layers) ----
    hist_kernel<<<(PE + 255) / 256, 256, 0, stream>>>(edst, cursor);
    scan_block<<<NBS, 1024, 0, stream>>>(cursor, row_start, blockSum, PN);
    scan_block<<<1, 1024, 0, stream>>>(blockSum, blockOff, nullptr, NBS);
    scan_add<<<NBS, 1024, 0, stream>>>(row_start, cursor, blockOff, PN);
    fill_kernel<<<(PE + 255) / 256, 256, 0, stream>>>(esrc, edst, cursor, csr_src);

    dim3 gp((N_NODES + 63) / 64, 2);
    const int gw = (N_NODES * DHID / 8 + 255) / 256;   // 2500 blocks, 8 rows each

    // ---- layer 1 ----
    proj_gemm<<<gp, 256, 0, stream>>>(x_hi, x_lo, Wp1t_hi, Wp1t_lo, bp1, as1, ad1,
                                      zb, a_s, a_d, N_NODES, 512);
    gather_kernel<<<PN / 4, 256, 0, stream>>>(row_start, csr_src, a_s, a_d, zb, outsb);
    score_gemm<<<PN / 64, 256, 0, stream>>>(outsb, Wk1t_hi, bk1, q1, score, PN);
    wsum_kernel<1, true><<<gw, 256, 0, stream>>>(outsb, score, h_hi, h_lo,
                                                 nullptr, nullptr, nullptr);

    // ---- layer 2 ----
    proj_gemm<<<gp, 256, 0, stream>>>(h_hi, h_lo, Wp2t_hi, Wp2t_lo, bp2, as2, ad2,
                                      zb, a_s, a_d, N_NODES, 256);
    gather_kernel<<<PN / 4, 256, 0, stream>>>(row_start, csr_src, a_s, a_d, zb, outsb);
    score_gemm<<<PN / 64, 256, 0, stream>>>(outsb, Wk2t_hi, bk2, q2, score + 4, PN);
    wsum_kernel<0, false><<<gw, 256, 0, stream>>>(outsb, score + 4, nullptr, nullptr,
                                                  Wo, bo, out);
}

// Round 9
// 451.002 us; speedup vs baseline: 20.2343x; 1.1141x over previous
//
#include <hip/hip_runtime.h>
#include <hip/hip_bf16.h>
#include <cstdint>

#define N_NODES 20000
#define E_EDGES 320000
#define P_TYPES 4
#define HEADS   8
#define DHID    256
#define NCLASSES 16
#define NEG_SLOPE 0.2f
#define PE_TOT (P_TYPES * E_EDGES)
#define PN_TOT (P_TYPES * N_NODES)

typedef __attribute__((ext_vector_type(8))) short bf16x8;
typedef __attribute__((ext_vector_type(8))) unsigned short ushort8;
typedef __attribute__((ext_vector_type(4))) float f32x4;

static __device__ __forceinline__ unsigned short f2bf(float v) {
    __hip_bfloat16 h = __float2bfloat16(v);
    return *(unsigned short*)&h;
}
static __device__ __forceinline__ float bf2f(unsigned short u) {
    __hip_bfloat16 h = *(__hip_bfloat16*)&u;
    return __bfloat162float(h);
}
static __device__ __forceinline__ float fast_tanh(float x) {
    x = fminf(fmaxf(x, -10.f), 10.f);
    float t = __expf(2.f * x);
    return (t - 1.f) * __builtin_amdgcn_rcpf(t + 1.f);   // ~1e-6 rel, plenty
}

// ===== prep: convert_x || convert_weights(+score zero) || hist_rank =========
// block ranges: [0,10000) x->hi/lo; [10000,11280) weights; [11280,16280) hist.
// hist_rank: rank[e] = old count of (p,dst) segment -- the ONLY atomic pass.
__global__ __launch_bounds__(256)
void prep_kernel(const float* __restrict__ x, unsigned short* __restrict__ xh,
                 unsigned short* __restrict__ xl,
                 const float* __restrict__ Wp1, const float* __restrict__ Wp2,
                 const float* __restrict__ Wk1, const float* __restrict__ Wk2,
                 unsigned short* __restrict__ Wp1h, unsigned short* __restrict__ Wp1l,
                 unsigned short* __restrict__ Wp2h, unsigned short* __restrict__ Wp2l,
                 unsigned short* __restrict__ Wk1h, unsigned short* __restrict__ Wk2h,
                 float* __restrict__ score,
                 const int* __restrict__ edst, int* __restrict__ count,
                 int* __restrict__ rank)
{
    int b = blockIdx.x;
    if (b < 10000) {                                    // x -> hi/lo bf16 (exact grid)
        int idx = b * 256 + threadIdx.x;
        float4 v = ((const float4*)x)[idx];
        ushort4 h, l;
        h.x = f2bf(v.x); h.y = f2bf(v.y); h.z = f2bf(v.z); h.w = f2bf(v.w);
        l.x = f2bf(v.x - bf2f(h.x)); l.y = f2bf(v.y - bf2f(h.y));
        l.z = f2bf(v.z - bf2f(h.z)); l.w = f2bf(v.w - bf2f(h.w));
        ((ushort4*)xh)[idx] = h;
        ((ushort4*)xl)[idx] = l;
    } else if (b < 11280) {                             // weights -> k-tiled bf16
        int id = (b - 10000) * 256 + threadIdx.x;
        if (id < 8) score[id] = 0.f;
        if (id < 131072) {                              // Wp1, K=512
            int n = id & 255, k = id >> 8;
            float v = Wp1[id];
            unsigned short h = f2bf(v);
            size_t dst = ((size_t)(k >> 5) * 256 + n) * 32 + (k & 31);
            Wp1h[dst] = h; Wp1l[dst] = f2bf(v - bf2f(h));
        } else if (id < 196608) {                       // Wp2, K=256
            int i2 = id - 131072;
            int n = i2 & 255, k = i2 >> 8;
            float v = Wp2[i2];
            unsigned short h = f2bf(v);
            size_t dst = ((size_t)(k >> 5) * 256 + n) * 32 + (k & 31);
            Wp2h[dst] = h; Wp2l[dst] = f2bf(v - bf2f(h));
        } else if (id < 262144) {                       // Wk1 hi
            int i2 = id - 196608;
            int n = i2 & 255, k = i2 >> 8;
            size_t dst = ((size_t)(k >> 5) * 256 + n) * 32 + (k & 31);
            Wk1h[dst] = f2bf(Wk1[i2]);
        } else if (id < 327680) {                       // Wk2 hi
            int i2 = id - 262144;
            int n = i2 & 255, k = i2 >> 8;
            size_t dst = ((size_t)(k >> 5) * 256 + n) * 32 + (k & 31);
            Wk2h[dst] = f2bf(Wk2[i2]);
        }
    } else {                                            // hist_rank (exact grid)
        int idx = (b - 11280) * 256 + threadIdx.x;
        int p = idx / E_EDGES;
        int seg = p * N_NODES + edst[idx];
        rank[idx] = atomicAdd(&count[seg], 1);
    }
}

// ========== proj GEMM + (optional) CSR fill riding along =====================
// blocks < projBlocks: zb = A(hi/lo bf16)@Wp + bp with fused att epilogue
//   (linearized: bx=blk>>1 in [0,313), by=blk&1; wave w = head by*4+w).
// blocks >= projBlocks: atomic-free CSR fill, 2 edges/thread.
__global__ __launch_bounds__(256)
void proj_fill(const unsigned short* __restrict__ Ah, const unsigned short* __restrict__ Al,
               const unsigned short* __restrict__ BgH, const unsigned short* __restrict__ BgL,
               const float* __restrict__ bias, const float* __restrict__ att_s,
               const float* __restrict__ att_d, unsigned short* __restrict__ zb,
               float* __restrict__ a_s, float* __restrict__ a_d, int M, int K,
               int projBlocks, const int* __restrict__ row_start,
               const int* __restrict__ rank, const int* __restrict__ edst,
               const int* __restrict__ esrc, int* __restrict__ csr_src)
{
    __shared__ int4 AS[2 * 64 * 5];
    __shared__ int4 BS[2 * 128 * 5];

    if ((int)blockIdx.x >= projBlocks) {                // ---- CSR fill path ----
        int base = (blockIdx.x - projBlocks) * 512 + threadIdx.x;
        #pragma unroll
        for (int t = 0; t < 2; t++) {
            int idx = base + t * 256;                   // exact: 2500*512 == PE_TOT
            int p = idx / E_EDGES;
            int seg = p * N_NODES + edst[idx];
            csr_src[row_start[seg] + rank[idx]] = esrc[idx];
        }
        return;
    }

    const int bx = blockIdx.x >> 1, by = blockIdx.x & 1;
    const int row0 = bx * 64;
    const int tid = threadIdx.x, lane = tid & 63, w = tid >> 6;

    f32x4 acc[4][2];
    const f32x4 zero4 = {0.f, 0.f, 0.f, 0.f};
    #pragma unroll
    for (int i = 0; i < 4; i++) { acc[i][0] = zero4; acc[i][1] = zero4; }

    for (int k0 = 0; k0 < K; k0 += 32) {
        {   // stage A: 64 rows x 32 k hi+lo (pure copies)
            int r = tid >> 2, f = tid & 3;
            int rg_ = row0 + r;
            int4 vh = make_int4(0, 0, 0, 0), vl = make_int4(0, 0, 0, 0);
            if (rg_ < M) {
                size_t a = (size_t)rg_ * K + k0 + f * 8;
                vh = *(const int4*)&Ah[a];
                vl = *(const int4*)&Al[a];
            }
            AS[r * 5 + f] = vh;
            AS[64 * 5 + r * 5 + f] = vl;
        }
        {   // stage B: 128 n-rows x 32 k hi+lo from k-tiled layout (coalesced)
            size_t bbase = (size_t)(k0 >> 5) * (256 * 32) + (size_t)(by * 128) * 32;
            #pragma unroll
            for (int it = 0; it < 2; it++) {
                int id = tid + it * 256;
                int r = id >> 2, f = id & 3;
                size_t a = bbase + (size_t)r * 32 + f * 8;
                BS[r * 5 + f] = *(const int4*)&BgH[a];
                BS[128 * 5 + r * 5 + f] = *(const int4*)&BgL[a];
            }
        }
        __syncthreads();

        const bf16x8* ASv = (const bf16x8*)AS;
        const bf16x8* BSv = (const bf16x8*)BS;
        const int slot = lane >> 4;
        bf16x8 ah[4], al[4];
        #pragma unroll
        for (int mt = 0; mt < 4; mt++) {
            int r = mt * 16 + (lane & 15);
            ah[mt] = ASv[r * 5 + slot];
            al[mt] = ASv[64 * 5 + r * 5 + slot];
        }
        #pragma unroll
        for (int nt = 0; nt < 2; nt++) {
            int rb = (w * 2 + nt) * 16 + (lane & 15);
            bf16x8 bh = BSv[rb * 5 + slot];
            bf16x8 bl = BSv[128 * 5 + rb * 5 + slot];
            #pragma unroll
            for (int mt = 0; mt < 4; mt++) {
                acc[mt][nt] = __builtin_amdgcn_mfma_f32_16x16x32_bf16(ah[mt], bh, acc[mt][nt], 0, 0, 0);
                acc[mt][nt] = __builtin_amdgcn_mfma_f32_16x16x32_bf16(ah[mt], bl, acc[mt][nt], 0, 0, 0);
                acc[mt][nt] = __builtin_amdgcn_mfma_f32_16x16x32_bf16(al[mt], bh, acc[mt][nt], 0, 0, 0);
            }
        }
        __syncthreads();
    }

    // Epilogue. C/D: col=lane&15 within 16-tile, row=(lane>>4)*4+reg.
    const int c15 = lane & 15, lhi = lane >> 4;
    const int hd = by * 4 + w;
    float asw[2], adw[2], bw[2];
    #pragma unroll
    for (int nt = 0; nt < 2; nt++) {
        int col = by * 128 + w * 32 + nt * 16 + c15;
        asw[nt] = att_s[col]; adw[nt] = att_d[col]; bw[nt] = bias[col];
    }
    #pragma unroll
    for (int mt = 0; mt < 4; mt++) {
        #pragma unroll
        for (int rg = 0; rg < 4; rg++) {
            int row = row0 + mt * 16 + lhi * 4 + rg;
            bool ok = row < M;
            float v0 = acc[mt][0][rg] + bw[0], v1 = acc[mt][1][rg] + bw[1];
            if (ok) {
                unsigned short* zp = zb + (size_t)row * DHID + by * 128 + w * 32 + c15;
                zp[0] = f2bf(v0); zp[16] = f2bf(v1);
            }
            float hs = v0 * asw[0] + v1 * asw[1];
            float hdd = v0 * adw[0] + v1 * adw[1];
            #pragma unroll
            for (int off = 1; off < 16; off <<= 1) {
                hs += __shfl_xor(hs, off, 64); hdd += __shfl_xor(hdd, off, 64);
            }
            if (ok && c15 == 0) {
                a_s[row * HEADS + hd] = hs;
                a_d[row * HEADS + hd] = hdd;
            }
        }
    }
}

// ========== score GEMM: bf16 A (relu'd), K=256, score-reduce epilogue =======
__global__ __launch_bounds__(256)
void score_gemm(const unsigned short* __restrict__ Ab, const unsigned short* __restrict__ BgH,
                const float* __restrict__ bias, const float* __restrict__ q,
                float* __restrict__ score, int M)
{
    __shared__ int4 AS[64 * 5];
    __shared__ int4 BS[256 * 5];
    __shared__ float red[4][2];
    const int row0 = blockIdx.x * 64;
    const int tid = threadIdx.x, lane = tid & 63, w = tid >> 6;

    f32x4 acc[4][4];
    const f32x4 zero4 = {0.f, 0.f, 0.f, 0.f};
    #pragma unroll
    for (int i = 0; i < 4; i++)
        #pragma unroll
        for (int j = 0; j < 4; j++) acc[i][j] = zero4;

    for (int k0 = 0; k0 < 256; k0 += 32) {
        {   // stage A: bf16 copy + relu bit-trick
            int r = tid >> 2, f = tid & 3;
            union { int4 v; unsigned short u[8]; } t;
            t.v = *(const int4*)&Ab[(size_t)(row0 + r) * DHID + k0 + f * 8];
            #pragma unroll
            for (int j = 0; j < 8; j++) if (t.u[j] & 0x8000) t.u[j] = 0;
            AS[r * 5 + f] = t.v;
        }
        {   // stage B: k-tile [256][32] hi
            size_t bbase = (size_t)(k0 >> 5) * (256 * 32);
            #pragma unroll
            for (int it = 0; it < 4; it++) {
                int id = tid + it * 256;
                BS[(id >> 2) * 5 + (id & 3)] = *(const int4*)&BgH[bbase + (size_t)id * 8];
            }
        }
        __syncthreads();

        const bf16x8* ASv = (const bf16x8*)AS;
        const bf16x8* BSv = (const bf16x8*)BS;
        const int slot = lane >> 4;
        bf16x8 ah[4];
        #pragma unroll
        for (int mt = 0; mt < 4; mt++) ah[mt] = ASv[(mt * 16 + (lane & 15)) * 5 + slot];
        #pragma unroll
        for (int nt = 0; nt < 4; nt++) {
            bf16x8 bh = BSv[((w * 4 + nt) * 16 + (lane & 15)) * 5 + slot];
            #pragma unroll
            for (int mt = 0; mt < 4; mt++)
                acc[mt][nt] = __builtin_amdgcn_mfma_f32_16x16x32_bf16(ah[mt], bh, acc[mt][nt], 0, 0, 0);
        }
        __syncthreads();
    }

    const int pbase = row0 / N_NODES;
    const int rowSplit = (pbase + 1) * N_NODES;
    float l0 = 0.f, l1 = 0.f;
    #pragma unroll
    for (int nt = 0; nt < 4; nt++) {
        int col = (w * 4 + nt) * 16 + (lane & 15);
        float qc = q[col], bc = bias[col];
        #pragma unroll
        for (int mt = 0; mt < 4; mt++)
            #pragma unroll
            for (int rg = 0; rg < 4; rg++) {
                int row = row0 + mt * 16 + (lane >> 4) * 4 + rg;
                float v = qc * fast_tanh(acc[mt][nt][rg] + bc);
                if (row >= rowSplit) l1 += v; else l0 += v;
            }
    }
    #pragma unroll
    for (int off = 32; off > 0; off >>= 1) {
        l0 += __shfl_down(l0, off, 64);
        l1 += __shfl_down(l1, off, 64);
    }
    if (lane == 0) { red[w][0] = l0; red[w][1] = l1; }
    __syncthreads();
    if (tid == 0)
        atomicAdd(score + pbase, red[0][0] + red[1][0] + red[2][0] + red[3][0]);
    if (tid == 1 && pbase + 1 < P_TYPES)
        atomicAdd(score + pbase + 1, red[0][1] + red[1][1] + red[2][1] + red[3][1]);
}

// ================= scan (hierarchical, over count -> row_start) =============
__global__ __launch_bounds__(1024)
void scan_block(const int* __restrict__ counts, int* __restrict__ out,
                int* __restrict__ blockSum, int total)
{
    __shared__ int wsum[16];
    int tid = threadIdx.x, lane = tid & 63, w = tid >> 6;
    int i = blockIdx.x * 1024 + tid;
    int v = (i < total) ? counts[i] : 0;
    int incl = v;
    #pragma unroll
    for (int off = 1; off < 64; off <<= 1) {
        int t = __shfl_up(incl, off, 64);
        if (lane >= off) incl += t;
    }
    if (lane == 63) wsum[w] = incl;
    __syncthreads();
    if (w == 0) {
        int s = (lane < 16) ? wsum[lane] : 0;
        #pragma unroll
        for (int off = 1; off < 16; off <<= 1) {
            int t = __shfl_up(s, off, 64);
            if (lane >= off) s += t;
        }
        if (lane < 16) wsum[lane] = s;
    }
    __syncthreads();
    int waveoff = w ? wsum[w - 1] : 0;
    if (i < total) out[i] = waveoff + incl - v;
    if (tid == 1023 && blockSum) blockSum[blockIdx.x] = wsum[15];
}

__global__ __launch_bounds__(1024)
void scan_add(int* __restrict__ row_start, const int* __restrict__ blockOff, int total)
{
    int i = blockIdx.x * 1024 + threadIdx.x;
    if (i == 0) row_start[total] = PE_TOT;
    if (i < total) row_start[i] += blockOff[blockIdx.x];
}

// ------- CSR gather: 1 wave/segment, 8 edges in flight (4 per half-wave) ----
__global__ __launch_bounds__(256)
void gather_kernel(const int* __restrict__ row_start, const int* __restrict__ csr_src,
                   const float* __restrict__ a_src, const float* __restrict__ a_dst,
                   const unsigned short* __restrict__ zb, unsigned short* __restrict__ outsb)
{
    int seg = blockIdx.x * 4 + (threadIdx.x >> 6);      // p*N + dst (grid exact)
    int lane = threadIdx.x & 63;
    int sub = lane >> 5, cl = lane & 31;
    int h = cl >> 2;
    int dst = seg % N_NODES;
    float ad = a_dst[dst * HEADS + h];
    int start = row_start[seg], end = row_start[seg + 1];

    float acc[8] = {};
    float den = 0.f;
    int i = start + sub;
    for (; i + 6 < end; i += 8) {                       // 4 edges per half-wave in flight
        int s0 = csr_src[i];
        int s1 = csr_src[i + 2];
        int s2 = csr_src[i + 4];
        int s3 = csr_src[i + 6];
        float g0 = a_src[s0 * HEADS + h];
        float g1 = a_src[s1 * HEADS + h];
        float g2 = a_src[s2 * HEADS + h];
        float g3 = a_src[s3 * HEADS + h];
        ushort8 z0 = *(const ushort8*)(zb + (size_t)s0 * DHID + cl * 8);
        ushort8 z1 = *(const ushort8*)(zb + (size_t)s1 * DHID + cl * 8);
        ushort8 z2 = *(const ushort8*)(zb + (size_t)s2 * DHID + cl * 8);
        ushort8 z3 = *(const ushort8*)(zb + (size_t)s3 * DHID + cl * 8);
        float e0 = g0 + ad; e0 = e0 > 0.f ? e0 : NEG_SLOPE * e0;
        float e1 = g1 + ad; e1 = e1 > 0.f ? e1 : NEG_SLOPE * e1;
        float e2 = g2 + ad; e2 = e2 > 0.f ? e2 : NEG_SLOPE * e2;
        float e3 = g3 + ad; e3 = e3 > 0.f ? e3 : NEG_SLOPE * e3;
        float w0 = __expf(e0), w1 = __expf(e1), w2 = __expf(e2), w3 = __expf(e3);
        #pragma unroll
        for (int j = 0; j < 8; j++) acc[j] += w0 * bf2f(z0[j]);
        #pragma unroll
        for (int j = 0; j < 8; j++) acc[j] += w1 * bf2f(z1[j]);
        #pragma unroll
        for (int j = 0; j < 8; j++) acc[j] += w2 * bf2f(z2[j]);
        #pragma unroll
        for (int j = 0; j < 8; j++) acc[j] += w3 * bf2f(z3[j]);
        den += (w0 + w1) + (w2 + w3);
    }
    for (; i < end; i += 2) {
        int s0 = csr_src[i];
        float g0 = a_src[s0 * HEADS + h];
        ushort8 z0 = *(const ushort8*)(zb + (size_t)s0 * DHID + cl * 8);
        float e0 = g0 + ad; e0 = e0 > 0.f ? e0 : NEG_SLOPE * e0;
        float w0 = __expf(e0);
        #pragma unroll
        for (int j = 0; j < 8; j++) acc[j] += w0 * bf2f(z0[j]);
        den += w0;
    }
    den += __shfl_xor(den, 32, 64);
    #pragma unroll
    for (int j = 0; j < 8; j++) acc[j] += __shfl_xor(acc[j], 32, 64);
    if (sub == 0) {
        float inv = den > 0.f ? 1.0f / den : 0.f;
        ushort8 o;
        #pragma unroll
        for (int j = 0; j < 8; j++) o[j] = f2bf(acc[j] * inv);
        *(ushort8*)(outsb + (size_t)seg * DHID + cl * 8) = o;
    }
}

// -------- weighted sum over types, fused beta softmax (+relu, opt elu) ------
// OUTMODE 0: fused final classifier -> out f32 [N,16] (block owns 8 rows).
// OUTMODE 1: write bf16 hi/lo (input for proj2).
template<int OUTMODE, bool ELU>
__global__ __launch_bounds__(256)
void wsum_kernel(const unsigned short* __restrict__ outsb, const float* __restrict__ score,
                 unsigned short* __restrict__ hh, unsigned short* __restrict__ hl,
                 const float* __restrict__ Wo, const float* __restrict__ bo,
                 float* __restrict__ out)
{
    __shared__ float hblk[8][256];                      // only used by OUTMODE 0
    int idx = blockIdx.x * 256 + threadIdx.x;           // ushort8 index into [N,256]
    float s0 = score[0], s1 = score[1], s2 = score[2], s3 = score[3];
    float m = fmaxf(fmaxf(s0, s1), fmaxf(s2, s3));
    float b[4];
    b[0] = __expf((s0 - m) * (1.f / N_NODES));
    b[1] = __expf((s1 - m) * (1.f / N_NODES));
    b[2] = __expf((s2 - m) * (1.f / N_NODES));
    b[3] = __expf((s3 - m) * (1.f / N_NODES));
    float dinv = 1.f / (b[0] + b[1] + b[2] + b[3]);
    b[0] *= dinv; b[1] *= dinv; b[2] *= dinv; b[3] *= dinv;

    const size_t stride = (size_t)N_NODES * DHID / 8;
    const ushort8* o = (const ushort8*)outsb;
    float r[8] = {};
    #pragma unroll
    for (int p = 0; p < 4; p++) {
        ushort8 v = o[idx + p * stride];
        #pragma unroll
        for (int j = 0; j < 8; j++) r[j] += b[p] * fmaxf(bf2f(v[j]), 0.f);
    }
    if (ELU) {
        #pragma unroll
        for (int j = 0; j < 8; j++) r[j] = r[j] > 0.f ? r[j] : expm1f(r[j]);
    }
    if (OUTMODE == 1) {
        ushort8 vh, vl;
        #pragma unroll
        for (int j = 0; j < 8; j++) {
            vh[j] = f2bf(r[j]);
            vl[j] = f2bf(r[j] - bf2f(vh[j]));
        }
        ((ushort8*)hh)[idx] = vh;
        ((ushort8*)hl)[idx] = vl;
    } else {
        // stage this block's 8 rows, then 128 threads do [8x256]@[256x16]+bo
        int row_l = threadIdx.x >> 5, u = threadIdx.x & 31;
        #pragma unroll
        for (int j = 0; j < 8; j++) hblk[row_l][u * 8 + j] = r[j];
        __syncthreads();
        int j = threadIdx.x;
        if (j < 8 * NCLASSES) {
            int rl = j >> 4, c = j & 15;
            float accv = bo[c];
            const float* hr = hblk[rl];
            #pragma unroll 8
            for (int k = 0; k < DHID; k++) accv = fmaf(hr[k], Wo[k * NCLASSES + c], accv);
            out[(size_t)(blockIdx.x * 8 + rl) * NCLASSES + c] = accv;
        }
    }
}

extern "C" void kernel_launch(void* const* d_in, const int* in_sizes, int n_in,
                              void* d_out, int out_size, void* d_ws, size_t ws_size,
                              hipStream_t stream)
{
    const float* x   = (const float*)d_in[0];
    const int*  esrc = (const int*)d_in[1];
    const int*  edst = (const int*)d_in[2];
    const float* Wp1 = (const float*)d_in[3];
    const float* bp1 = (const float*)d_in[4];
    const float* as1 = (const float*)d_in[5];
    const float* ad1 = (const float*)d_in[6];
    const float* Wk1 = (const float*)d_in[7];
    const float* bk1 = (const float*)d_in[8];
    const float* q1  = (const float*)d_in[9];
    const float* Wp2 = (const float*)d_in[10];
    const float* bp2 = (const float*)d_in[11];
    const float* as2 = (const float*)d_in[12];
    const float* ad2 = (const float*)d_in[13];
    const float* Wk2 = (const float*)d_in[14];
    const float* bk2 = (const float*)d_in[15];
    const float* q2  = (const float*)d_in[16];
    const float* Wo  = (const float*)d_in[17];
    const float* bo  = (const float*)d_in[18];
    float* out = (float*)d_out;

    // workspace layout (byte offsets, all 16B-aligned). rank reuses old hbuf slot.
    char* wsb = (char*)d_ws;
    int* rank    = (int*)wsb;                                     //  5,120,000
    float* a_s   = (float*)(wsb + 20480000);                      //    640,000
    float* a_d   = (float*)(wsb + 21120000);                      //    640,000
    float* score = (float*)(wsb + 21760000);                      //         32
    unsigned short* zb      = (unsigned short*)(wsb + 21760032);  // 10,240,000
    unsigned short* outsb   = (unsigned short*)(wsb + 32000032);  // 40,960,000
    unsigned short* x_hi    = (unsigned short*)(wsb + 72960032);  // 20,480,000
    unsigned short* x_lo    = (unsigned short*)(wsb + 93440032);  // 20,480,000
    unsigned short* h_hi    = (unsigned short*)(wsb + 113920032); // 10,240,000
    unsigned short* h_lo    = (unsigned short*)(wsb + 124160032); // 10,240,000
    unsigned short* Wp1t_hi = (unsigned short*)(wsb + 134400032); //    262,144
    unsigned short* Wp1t_lo = (unsigned short*)(wsb + 134662176);
    unsigned short* Wp2t_hi = (unsigned short*)(wsb + 134924320); //    131,072
    unsigned short* Wp2t_lo = (unsigned short*)(wsb + 135055392);
    unsigned short* Wk1t_hi = (unsigned short*)(wsb + 135186464);
    unsigned short* Wk2t_hi = (unsigned short*)(wsb + 135317536);
    int* row_start = (int*)(wsb + 135448608);                     //    320,016
    int* count     = (int*)(wsb + 135768624);                     //    320,000
    int* blockSum  = (int*)(wsb + 136088624);                     //        512
    int* blockOff  = (int*)(wsb + 136089136);                     //        512
    int* csr_src   = (int*)(wsb + 136089648);                     //  5,120,000

    const int NBS = (PN_TOT + 1023) / 1024;      // 79

    // ---- prep: count zero, then {convert_x || convert_weights || hist_rank} ----
    hipMemsetAsync(count, 0, PN_TOT * sizeof(int), stream);
    prep_kernel<<<16280, 256, 0, stream>>>(x, x_hi, x_lo, Wp1, Wp2, Wk1, Wk2,
        Wp1t_hi, Wp1t_lo, Wp2t_hi, Wp2t_lo, Wk1t_hi, Wk2t_hi, score,
        edst, count, rank);

    // ---- scan: count -> row_start (exclusive) + sentinel ----
    scan_block<<<NBS, 1024, 0, stream>>>(count, row_start, blockSum, PN_TOT);
    scan_block<<<1, 1024, 0, stream>>>(blockSum, blockOff, nullptr, NBS);
    scan_add<<<NBS, 1024, 0, stream>>>(row_start, blockOff, PN_TOT);

    const int PROJ_BLOCKS = 626;                 // 313 x 2
    const int FILL_BLOCKS = PE_TOT / 512;        // 2500 (exact)
    const int gw = N_NODES * DHID / 8 / 256;     // 2500 blocks, 8 rows each

    // ---- layer 1 (CSR fill rides along with proj1) ----
    proj_fill<<<PROJ_BLOCKS + FILL_BLOCKS, 256, 0, stream>>>(
        x_hi, x_lo, Wp1t_hi, Wp1t_lo, bp1, as1, ad1, zb, a_s, a_d, N_NODES, 512,
        PROJ_BLOCKS, row_start, rank, edst, esrc, csr_src);
    gather_kernel<<<PN_TOT / 4, 256, 0, stream>>>(row_start, csr_src, a_s, a_d, zb, outsb);
    score_gemm<<<PN_TOT / 64, 256, 0, stream>>>(outsb, Wk1t_hi, bk1, q1, score, PN_TOT);
    wsum_kernel<1, true><<<gw, 256, 0, stream>>>(outsb, score, h_hi, h_lo,
                                                 nullptr, nullptr, nullptr);

    // ---- layer 2 ----
    proj_fill<<<PROJ_BLOCKS, 256, 0, stream>>>(
        h_hi, h_lo, Wp2t_hi, Wp2t_lo, bp2, as2, ad2, zb, a_s, a_d, N_NODES, 256,
        PROJ_BLOCKS, row_start, rank, edst, esrc, csr_src);
    gather_kernel<<<PN_TOT / 4, 256, 0, stream>>>(row_start, csr_src, a_s, a_d, zb, outsb);
    score_gemm<<<PN_TOT / 64, 256, 0, stream>>>(outsb, Wk2t_hi, bk2, q2, score + 4, PN_TOT);
    wsum_kernel<0, false><<<gw, 256, 0, stream>>>(outsb, score + 4, nullptr, nullptr,
                                                  Wo, bo, out);
}